// Round 12
// baseline (252.400 us; speedup 1.0000x reference)
//
#include <hip/hip_runtime.h>
#include <hip/hip_bf16.h>
#include <stdint.h>

// Problem constants: b=1, s=2048, hidden=2048, H=16, d=128
#define SEQ   2048
#define HIDN  2048
#define NHEAD 16
#define HDIM  128
#define HEAVY 204   // int(0.1*2048)
#define RECENT 204

typedef __attribute__((ext_vector_type(4))) float f32x4;
typedef __attribute__((ext_vector_type(8))) short bf16x8;
typedef unsigned short u16;
typedef unsigned int   u32;

static __device__ __forceinline__ u16 f2bf(float f){
  union { float f; u32 u; } v; v.f = f;
  u32 r = (v.u + 0x7FFFu + ((v.u >> 16) & 1u)) >> 16;
  return (u16)r;
}
static __device__ __forceinline__ float bf2f(u16 u){
  union { u32 u; float f; } v; v.u = ((u32)u) << 16;
  return v.f;
}

// global -> LDS direct 16B load (dest is wave-uniform base + lane*16)
static __device__ __forceinline__ void gload16(const void* g, void* l){
  __builtin_amdgcn_global_load_lds((const __attribute__((address_space(1))) u32*)g,
                                   (__attribute__((address_space(3))) u32*)l, 16, 0, 0);
}

#define WAITVM(N) asm volatile("s_waitcnt vmcnt(" #N ")" ::: "memory")
#define BARRAW    __builtin_amdgcn_s_barrier()
#define PRIO1     __builtin_amdgcn_s_setprio(1)
#define PRIO0     __builtin_amdgcn_s_setprio(0)

// stage a 64x128 bf16 tile with 256 threads, runtime row stride (XOR-swizzled source)
static __device__ __forceinline__ void stage_tile(const u16* __restrict__ base, size_t stride,
                                                  int row0, u16* __restrict__ lds, int tid){
  const int wbase = tid & ~63;
#pragma unroll
  for (int it = 0; it < 4; ++it){
    int m = it * 256 + tid;
    int row = m >> 4, cp = m & 15;
    gload16(base + (size_t)(row0 + row) * stride + ((cp ^ (row & 7)) * 8),
            lds + (it * 256 + wbase) * 8);
  }
}

// stage 64x128 tile with 512 threads, runtime stride
static __device__ __forceinline__ void stageK512(const u16* __restrict__ base, size_t stride,
                                                 int row0, u16* __restrict__ lds, int tid){
#pragma unroll
  for (int it = 0; it < 2; ++it){
    int m = it * 512 + tid;
    int row = m >> 4, cp = m & 15;
    gload16(base + (size_t)(row0 + row) * stride + ((cp ^ (row & 7)) * 8),
            lds + (it * 512 + (tid & ~63)) * 8);
  }
}
// stage 128-row x 64-col tile (col offset c0) with 512 threads, runtime stride
static __device__ __forceinline__ void stageV512(const u16* __restrict__ base, size_t stride,
                                                 int c0, u16* __restrict__ lds, int tid){
#pragma unroll
  for (int it = 0; it < 2; ++it){
    int m = it * 512 + tid;
    int row = m >> 3, cp = m & 7;
    gload16(base + (size_t)row * stride + c0 + ((cp ^ (row & 7)) * 8),
            lds + (it * 512 + (tid & ~63)) * 8);
  }
}

// ---------------- prep: cvt5 + rope tables + zero colsum/rowsum (fused) ----------------
__global__ void k_prep(const float* __restrict__ A0, const float* __restrict__ A1,
                       const float* __restrict__ A2, const float* __restrict__ A3,
                       const float* __restrict__ A4, u16* __restrict__ out,
                       float* __restrict__ cosT, float* __restrict__ sinT,
                       float* __restrict__ colsum){
  int b = blockIdx.x, tid = threadIdx.x;
  if (b < 20480){
    int id = b * 256 + tid;
    int sel = id >> 20, off = (id & 1048575) * 4;
    const float* src = sel == 0 ? A0 : sel == 1 ? A1 : sel == 2 ? A2 : sel == 3 ? A3 : A4;
    float4 v = *(const float4*)(src + off);
    ushort4 o;
    o.x = f2bf(v.x); o.y = f2bf(v.y); o.z = f2bf(v.z); o.w = f2bf(v.w);
    *(ushort4*)(out + (size_t)sel * 4194304 + off) = o;
  } else if (b < 20992){
    int i = (b - 20480) * 256 + tid;           // 2048*64
    int pos = i >> 6, j = i & 63;
    float invf = powf(10000.0f, -(float)j * (1.0f / 64.0f));
    float a = (float)pos * invf;
    cosT[i] = cosf(a);
    sinT[i] = sinf(a);
  } else {
    int i = (b - 20992) * 256 + tid;           // 16384 float4 = colsum+rowsum (contiguous)
    if (i < 16384) ((float4*)colsum)[i] = (float4){0.f, 0.f, 0.f, 0.f};
  }
}

// ---------------- post: rope on Q,K + transpose V (fused) ----------------
__global__ void k_post(u16* __restrict__ Qm, u16* __restrict__ Km,
                       const float* __restrict__ cosT, const float* __restrict__ sinT,
                       const u16* __restrict__ V, u16* __restrict__ Vt){
  __shared__ u16 t[32][33];
  int b = blockIdx.x, tid = threadIdx.x;
  if (b < 4096){
    int gid = b * 256 + tid;                   // 2 * 524288
    u16* M = (gid < 524288) ? Qm : Km;
    int id = gid & 524287;
    int pos = id >> 8, rem = id & 255;
    int h = rem >> 4, j4 = (rem & 15) * 4;
    u16* p = M + (size_t)pos * HIDN + h * HDIM + j4;
    ushort4 lo = *(ushort4*)p;
    ushort4 hi = *(ushort4*)(p + 64);
    float4 c = *(const float4*)(cosT + pos * 64 + j4);
    float4 s = *(const float4*)(sinT + pos * 64 + j4);
    float l0 = bf2f(lo.x), l1 = bf2f(lo.y), l2 = bf2f(lo.z), l3 = bf2f(lo.w);
    float h0 = bf2f(hi.x), h1 = bf2f(hi.y), h2 = bf2f(hi.z), h3 = bf2f(hi.w);
    ushort4 nlo, nhi;
    nlo.x = f2bf(l0 * c.x - h0 * s.x);  nhi.x = f2bf(h0 * c.x + l0 * s.x);
    nlo.y = f2bf(l1 * c.y - h1 * s.y);  nhi.y = f2bf(h1 * c.y + l1 * s.y);
    nlo.z = f2bf(l2 * c.z - h2 * s.z);  nhi.z = f2bf(h2 * c.z + l2 * s.z);
    nlo.w = f2bf(l3 * c.w - h3 * s.w);  nhi.w = f2bf(h3 * c.w + l3 * s.w);
    *(ushort4*)p = nlo;
    *(ushort4*)(p + 64) = nhi;
  } else {
    int b2 = b - 4096;
    int s0 = (b2 & 63) * 32, c0 = (b2 >> 6) * 32;
    int r = tid >> 3, cc = (tid & 7) * 4;
    ushort4 v = *(const ushort4*)(V + (size_t)(s0 + r) * 2048 + c0 + cc);
    t[r][cc] = v.x; t[r][cc + 1] = v.y; t[r][cc + 2] = v.z; t[r][cc + 3] = v.w;
    __syncthreads();
    int co = tid >> 3, ro = (tid & 7) * 4;
    ushort4 o;
    o.x = t[ro][co]; o.y = t[ro + 1][co]; o.z = t[ro + 2][co]; o.w = t[ro + 3][co];
    *(ushort4*)(Vt + (size_t)(c0 + co) * 2048 + s0 + ro) = o;
  }
}

// ---------------- fused projection GEMM: C[2048][6144] = X @ [Wq;Wk;Wv]^T ----------------
// 128x192 tile, BK=32, 8 waves (2M x 4N), 40 KB LDS, <=128 VGPR -> 2 blocks/CU
// (4 waves/SIMD: cross-block barrier overlap). Counted vmcnt 2-buffer.
// grid (32, 16) = 512 blocks = exactly 2 per CU.
__global__ __launch_bounds__(512, 4)
void k_g256(const u16* __restrict__ X, const u16* __restrict__ Wq, const u16* __restrict__ Wk,
            const u16* __restrict__ Wv, u16* __restrict__ C0, u16* __restrict__ C1,
            u16* __restrict__ C2){
  __shared__ __align__(16) u16 LA[2][128 * 32];
  __shared__ __align__(16) u16 LB[2][192 * 32];
  const int tid = threadIdx.x;
  const int lane = tid & 63, wvi = tid >> 6;
  const int wm = wvi >> 2, wn = wvi & 3;
  const int g = lane >> 4, c15 = lane & 15;
  const int brow = blockIdx.y * 128;       // [0,2048)
  const int bcol = blockIdx.x * 192;       // [0,6144)
  const int NT = 64;                       // K tiles of 32
  const int cc = (g ^ (c15 & 3)) * 8;      // 4-chunk XOR swizzle (bijective per wave)

  f32x4 acc[4][3];
#pragma unroll
  for (int m = 0; m < 4; m++)
#pragma unroll
    for (int n = 0; n < 3; n++) acc[m][n] = (f32x4){0.f, 0.f, 0.f, 0.f};

#define BPTR(rB_) (rB_ < 2048 ? Wq + (size_t)(rB_) * 2048 \
                 : rB_ < 4096 ? Wk + (size_t)((rB_) - 2048) * 2048 \
                              : Wv + (size_t)((rB_) - 4096) * 2048)
// one stage = 3 uniform loads/thread: A (128x32), B rows 0-127, B rows 128-191
// (last staged twice by wave-halves to identical LDS bytes -- benign, keeps vmcnt uniform)
#define STG(kt, buf) do { \
    const int k0_ = (kt) * 32; \
    { int row_ = tid >> 2, cp_ = tid & 3; \
      gload16(X + (size_t)(brow + row_) * 2048 + k0_ + ((cp_ ^ (row_ & 3)) * 8), \
              &LA[buf][0] + (tid & ~63) * 8); } \
    { int row_ = tid >> 2, cp_ = tid & 3; int rB_ = bcol + row_; \
      const u16* bp_ = BPTR(rB_); \
      gload16(bp_ + k0_ + ((cp_ ^ (row_ & 3)) * 8), \
              &LB[buf][0] + (tid & ~63) * 8); } \
    { int c2_ = 512 + (tid & 255); int row_ = c2_ >> 2, cp_ = c2_ & 3; int rB_ = bcol + row_; \
      const u16* bp_ = BPTR(rB_); \
      gload16(bp_ + k0_ + ((cp_ ^ (row_ & 3)) * 8), \
              &LB[buf][0] + (512 + (tid & 192)) * 8); } \
  } while(0)

  STG(0, 0);
  for (int t = 0; t < NT; ++t){
    const int buf = t & 1;
    if (t + 1 < NT){ STG(t + 1, buf ^ 1); WAITVM(3); }
    else           { WAITVM(0); }
    BARRAW;
    bf16x8 af[4], bfv[3];
#pragma unroll
    for (int mi = 0; mi < 4; ++mi)
      af[mi] = *(const bf16x8*)(&LA[buf][0] + (size_t)(wm * 64 + mi * 16 + c15) * 32 + cc);
#pragma unroll
    for (int ni = 0; ni < 3; ++ni)
      bfv[ni] = *(const bf16x8*)(&LB[buf][0] + (size_t)(wn * 48 + ni * 16 + c15) * 32 + cc);
    PRIO1;
#pragma unroll
    for (int mi = 0; mi < 4; ++mi)
#pragma unroll
      for (int ni = 0; ni < 3; ++ni)
        acc[mi][ni] = __builtin_amdgcn_mfma_f32_16x16x32_bf16(af[mi], bfv[ni], acc[mi][ni], 0, 0, 0);
    PRIO0;
    BARRAW;
  }
#undef STG
#undef BPTR

#pragma unroll
  for (int mi = 0; mi < 4; ++mi)
#pragma unroll
    for (int ni = 0; ni < 3; ++ni){
      int colbase = bcol + wn * 48 + ni * 16;      // 2048-boundary is 16-aligned
      int proj = colbase >> 11;
      u16* Cb = proj == 0 ? C0 : proj == 1 ? C1 : C2;
      int lc = (colbase & 2047) + c15;
#pragma unroll
      for (int r = 0; r < 4; ++r){
        int row = brow + wm * 64 + mi * 16 + g * 4 + r;
        Cb[(size_t)row * 2048 + lc] = f2bf(acc[mi][ni][r]);
      }
    }
}

// ---------------- output GEMM: 128x128 tile, BK=64, 8 waves, counted vmcnt ----------------
// grid (16,16) = 256 blocks, 512 thr = 2 waves/SIMD
__global__ __launch_bounds__(512)
void k_gemm_out(const u16* __restrict__ A, const u16* __restrict__ B, float* __restrict__ C){
  __shared__ __align__(16) u16 As[2][128 * 64];
  __shared__ __align__(16) u16 Bs[2][128 * 64];
  const int tid = threadIdx.x;
  const int w = tid >> 6, lane = tid & 63;
  const int wm = w >> 1, wn = w & 1;
  const int g = lane >> 4, c15 = lane & 15;
  const int brow = blockIdx.y * 128, bcol = blockIdx.x * 128;
  const int cc0 = ((g ^ (c15 & 7)) * 8);

  f32x4 acc[2][4];
#pragma unroll
  for (int m = 0; m < 2; m++)
#pragma unroll
    for (int n = 0; n < 4; n++) acc[m][n] = (f32x4){0.f, 0.f, 0.f, 0.f};

#define STG_O(k0, buf) do { \
  _Pragma("unroll") for (int it = 0; it < 2; ++it){ \
    int m_ = it * 512 + tid; \
    int row_ = m_ >> 3, cp_ = m_ & 7; \
    gload16(A + (size_t)(brow + row_) * 2048 + (k0) + ((cp_ ^ (row_ & 7)) * 8), \
            As[buf] + (it * 512 + (tid & ~63)) * 8); \
    gload16(B + (size_t)(bcol + row_) * 2048 + (k0) + ((cp_ ^ (row_ & 7)) * 8), \
            Bs[buf] + (it * 512 + (tid & ~63)) * 8); \
  } } while(0)

  STG_O(0, 0);
  int cur = 0;
  for (int kt = 0; kt < 32; ++kt){
    if (kt + 1 < 32){ STG_O((kt + 1) * 64, cur ^ 1); WAITVM(4); }
    else            { WAITVM(0); }
    BARRAW;
    bf16x8 af[2][2], bfr[4][2];
#pragma unroll
    for (int mi = 0; mi < 2; ++mi){
      const u16* pr = As[cur] + (size_t)(wm * 32 + mi * 16 + c15) * 64;
      af[mi][0] = *(const bf16x8*)(pr + cc0);
      af[mi][1] = *(const bf16x8*)(pr + (cc0 ^ 32));
    }
#pragma unroll
    for (int ni = 0; ni < 4; ++ni){
      const u16* pr = Bs[cur] + (size_t)(wn * 64 + ni * 16 + c15) * 64;
      bfr[ni][0] = *(const bf16x8*)(pr + cc0);
      bfr[ni][1] = *(const bf16x8*)(pr + (cc0 ^ 32));
    }
    PRIO1;
#pragma unroll
    for (int mi = 0; mi < 2; ++mi)
#pragma unroll
      for (int ni = 0; ni < 4; ++ni)
#pragma unroll
        for (int kk = 0; kk < 2; ++kk)
          acc[mi][ni] = __builtin_amdgcn_mfma_f32_16x16x32_bf16(af[mi][kk], bfr[ni][kk],
                                                                acc[mi][ni], 0, 0, 0);
    PRIO0;
    BARRAW;
    cur ^= 1;
  }
#undef STG_O
#pragma unroll
  for (int mi = 0; mi < 2; ++mi)
#pragma unroll
    for (int ni = 0; ni < 4; ++ni)
#pragma unroll
      for (int r = 0; r < 4; ++r){
        int row = brow + wm * 32 + mi * 16 + g * 4 + r;
        int col = bcol + wn * 64 + ni * 16 + c15;
        C[(size_t)row * 2048 + col] = acc[mi][ni][r];
      }
}

// ---------------- pass 1a: rowsum of exp (causal), Q-in-registers ----------------
// grid (40, 16), 256 thr; K triple-buffered LDS stream, 1 barrier/iter.
__global__ __launch_bounds__(256)
void k_pass1a(const u16* __restrict__ Q, const u16* __restrict__ K, float* __restrict__ rowsum){
  __shared__ __align__(16) u16 Ks[3][64 * 128];
  const int tid = threadIdx.x;
  const int wv = tid >> 6, lane = tid & 63;
  const int g = lane >> 4, c15 = lane & 15;
  const int h = blockIdx.y;
  int qb = 0, c = 0;
  { int rem = blockIdx.x; int q = 0;
    while (rem >= ((2 * q + 9) >> 3)){ rem -= (2 * q + 9) >> 3; q++; }
    qb = q; c = rem; }
  const int i0 = qb * 128;
  const int ktend = 2 * qb + 2;
  const int kt0 = c * 8;
  const int kt1 = (ktend < kt0 + 8) ? ktend : (kt0 + 8);
  const u16* Qh = Q + h * HDIM;
  const u16* Kh = K + h * HDIM;
  const float scale = 0.08838834764831845f;   // 1/sqrt(128)
  const int wb = wv * 32;

  bf16x8 qfr[2][4];
#pragma unroll
  for (int m = 0; m < 2; m++)
#pragma unroll
    for (int ks = 0; ks < 4; ks++)
      qfr[m][ks] = *(const bf16x8*)(Qh + (size_t)(i0 + wb + m * 16 + c15) * 2048 + ks * 32 + g * 8);

  stage_tile(Kh, 2048, kt0 * 64, Ks[0], tid);
  if (kt0 + 1 < kt1) stage_tile(Kh, 2048, (kt0 + 1) * 64, Ks[1], tid);

  float rs[2][4] = {{0.f,0.f,0.f,0.f},{0.f,0.f,0.f,0.f}};
  for (int kt = kt0; kt < kt1; ++kt){
    const int bi = (kt - kt0) % 3;
    if (kt + 1 < kt1){ WAITVM(4); } else { WAITVM(0); }
    BARRAW;
    if (kt + 2 < kt1) stage_tile(Kh, 2048, (kt + 2) * 64, Ks[(kt - kt0 + 2) % 3], tid);
    const int k0 = kt * 64;
    f32x4 sacc[2][4];
#pragma unroll
    for (int m = 0; m < 2; m++)
#pragma unroll
      for (int n = 0; n < 4; n++) sacc[m][n] = (f32x4){0.f, 0.f, 0.f, 0.f};
#pragma unroll
    for (int ks = 0; ks < 4; ++ks){
#pragma unroll
      for (int n = 0; n < 4; n++){
        int brw = n * 16 + c15;
        bf16x8 b = *(const bf16x8*)(Ks[bi] + brw * 128 + ((ks * 32 + g * 8) ^ ((brw & 7) << 3)));
#pragma unroll
        for (int m = 0; m < 2; m++)
          sacc[m][n] = __builtin_amdgcn_mfma_f32_16x16x32_bf16(qfr[m][ks], b, sacc[m][n], 0, 0, 0);
      }
    }
    if (kt < 2 * qb){            // fully causal tile: no mask compare
#pragma unroll
      for (int m = 0; m < 2; m++)
#pragma unroll
        for (int n = 0; n < 4; n++)
#pragma unroll
          for (int r = 0; r < 4; r++)
            rs[m][r] += __expf(sacc[m][n][r] * scale);
    } else {
#pragma unroll
      for (int n = 0; n < 4; n++){
        int col = k0 + n * 16 + c15;
#pragma unroll
        for (int m = 0; m < 2; m++)
#pragma unroll
          for (int r = 0; r < 4; r++){
            int rowg = i0 + wb + m * 16 + g * 4 + r;
            rs[m][r] += (col <= rowg) ? __expf(sacc[m][n][r] * scale) : 0.f;
          }
      }
    }
  }
#pragma unroll
  for (int m = 0; m < 2; m++)
#pragma unroll
    for (int r = 0; r < 4; r++){
      float v = rs[m][r];
      v += __shfl_xor(v, 1); v += __shfl_xor(v, 2);
      v += __shfl_xor(v, 4); v += __shfl_xor(v, 8);
      if (c15 == 0)
        atomicAdd(&rowsum[h * 2048 + i0 + wb + m * 16 + g * 4 + r], v);
    }
}

// ---------------- pass 1b: colsum of normalized exp, K-in-registers ----------------
// grid (40, 16), 256 thr; Q triple-buffered LDS stream, 1 barrier/iter.
__global__ __launch_bounds__(256)
void k_pass1b(const u16* __restrict__ Q, const u16* __restrict__ K,
              const float* __restrict__ rowsum, float* __restrict__ colsum){
  __shared__ __align__(16) u16 Qs[3][64 * 128];
  const int tid = threadIdx.x;
  const int wv = tid >> 6, lane = tid & 63;
  const int g = lane >> 4, c15 = lane & 15;
  const int h = blockIdx.y;
  int kb = 0, c = 0;
  { int rem = blockIdx.x; int q = 0;
    while (rem >= ((39 - 2 * q) >> 3)){ rem -= (39 - 2 * q) >> 3; q++; }
    kb = q; c = rem; }
  const int k0 = kb * 128;
  const int qt0 = 2 * kb + c * 8;
  const int qt1 = (2 * kb + c * 8 + 8 < 32) ? (2 * kb + c * 8 + 8) : 32;
  const u16* Qh = Q + h * HDIM;
  const u16* Kh = K + h * HDIM;
  const float scale = 0.08838834764831845f;
  const int wb = wv * 32;
  const float* rsrow = rowsum + h * 2048;

  bf16x8 kfr[2][4];
#pragma unroll
  for (int m = 0; m < 2; m++)
#pragma unroll
    for (int ks = 0; ks < 4; ks++)
      kfr[m][ks] = *(const bf16x8*)(Kh + (size_t)(k0 + wb + m * 16 + c15) * 2048 + ks * 32 + g * 8);

  stage_tile(Qh, 2048, qt0 * 64, Qs[0], tid);
  if (qt0 + 1 < qt1) stage_tile(Qh, 2048, (qt0 + 1) * 64, Qs[1], tid);

  float racc[2][4] = {{0.f,0.f,0.f,0.f},{0.f,0.f,0.f,0.f}};
  for (int qt = qt0; qt < qt1; ++qt){
    const int bi = (qt - qt0) % 3;
    if (qt + 1 < qt1){ WAITVM(4); } else { WAITVM(0); }
    BARRAW;
    if (qt + 2 < qt1) stage_tile(Qh, 2048, (qt + 2) * 64, Qs[(qt - qt0 + 2) % 3], tid);
    const int i0q = qt * 64;
    float rw[4];
#pragma unroll
    for (int n = 0; n < 4; n++)
      rw[n] = 1.0f / rsrow[i0q + n * 16 + c15];
    f32x4 sacc[2][4];
#pragma unroll
    for (int m = 0; m < 2; m++)
#pragma unroll
      for (int n = 0; n < 4; n++) sacc[m][n] = (f32x4){0.f, 0.f, 0.f, 0.f};
#pragma unroll
    for (int ks = 0; ks < 4; ++ks){
#pragma unroll
      for (int n = 0; n < 4; n++){
        int brw = n * 16 + c15;
        bf16x8 b = *(const bf16x8*)(Qs[bi] + brw * 128 + ((ks * 32 + g * 8) ^ ((brw & 7) << 3)));
#pragma unroll
        for (int m = 0; m < 2; m++)
          sacc[m][n] = __builtin_amdgcn_mfma_f32_16x16x32_bf16(kfr[m][ks], b, sacc[m][n], 0, 0, 0);
      }
    }
    if (qt >= 2 * kb + 2){       // fully causal: no mask compare
#pragma unroll
      for (int m = 0; m < 2; m++)
#pragma unroll
        for (int n = 0; n < 4; n++)
#pragma unroll
          for (int r = 0; r < 4; r++)
            racc[m][r] += __expf(sacc[m][n][r] * scale) * rw[n];
    } else {
#pragma unroll
      for (int n = 0; n < 4; n++){
        int colq = i0q + n * 16 + c15;
#pragma unroll
        for (int m = 0; m < 2; m++)
#pragma unroll
          for (int r = 0; r < 4; r++){
            int rowk = k0 + wb + m * 16 + g * 4 + r;
            racc[m][r] += (rowk <= colq) ? __expf(sacc[m][n][r] * scale) * rw[n] : 0.f;
          }
      }
    }
  }
#pragma unroll
  for (int m = 0; m < 2; m++)
#pragma unroll
    for (int r = 0; r < 4; r++){
      float v = racc[m][r];
      v += __shfl_xor(v, 1); v += __shfl_xor(v, 2);
      v += __shfl_xor(v, 4); v += __shfl_xor(v, 8);
      if (c15 == 0)
        atomicAdd(&colsum[h * 2048 + k0 + wb + m * 16 + g * 4 + r], v);
    }
}

// ---------------- top-k via exact radix-select (select only, 16 blocks) ----------------
__global__ __launch_bounds__(1024)
void k_topk(const float* __restrict__ colsum, short* __restrict__ cidx){
  __shared__ u32 keys[2048];
  __shared__ int hist[256];
  __shared__ int chunkCnt[32];
  __shared__ short cidL[256];
  __shared__ u32 Tacc_s;
  __shared__ int rem_s;
  const int tid = threadIdx.x;
  const int h = blockIdx.x;
  const int w = tid >> 6, lane = tid & 63;

  for (int i = tid; i < 2048; i += 1024) keys[i] = ((const u32*)colsum)[h * 2048 + i];
  if (tid == 0){ Tacc_s = 0; rem_s = HEAVY; }
  __syncthreads();

  for (int s = 24; s >= 0; s -= 8){
    if (tid < 256) hist[tid] = 0;
    __syncthreads();
    u32 T = Tacc_s;
    for (int i = tid; i < 2048; i += 1024){
      u32 k = keys[i];
      bool match = (s == 24) ? true : (((k ^ T) >> (s + 8)) == 0);
      if (match) atomicAdd(&hist[(k >> s) & 255], 1);
    }
    __syncthreads();
    if (tid == 0){
      int rem = rem_s, acc = 0, b = 255;
      for (; b > 0; --b){
        int c2 = hist[b];
        if (acc + c2 >= rem) break;
        acc += c2;
      }
      Tacc_s = T | ((u32)b << s);
      rem_s = rem - acc;
    }
    __syncthreads();
  }
  const u32 T = Tacc_s;
  const int need = rem_s;                 // smallest-index ties among == T
  const u32 kA = keys[tid], kB = keys[tid + 1024];
  const bool eqA = (kA == T), eqB = (kB == T);
  unsigned long long ebA = __ballot(eqA);
  unsigned long long ebB = __ballot(eqB);
  if (lane == 0){ chunkCnt[w] = __popcll(ebA); chunkCnt[16 + w] = __popcll(ebB); }
  __syncthreads();
  if (tid == 0){
    int s2 = 0;
    for (int i2 = 0; i2 < 32; ++i2){ int c2 = chunkCnt[i2]; chunkCnt[i2] = s2; s2 += c2; }
  }
  __syncthreads();
  const unsigned long long below = (1ull << lane) - 1ull;
  const int eqrA = chunkCnt[w] + __popcll(ebA & below);
  const int eqrB = chunkCnt[16 + w] + __popcll(ebB & below);
  const bool hvA = (kA > T) || (eqA && eqrA < need);
  const bool hvB = (kB > T) || (eqB && eqrB < need);
  __syncthreads();                        // before reusing chunkCnt
  unsigned long long hbA = __ballot(hvA);
  unsigned long long hbB = __ballot(hvB);
  if (lane == 0){ chunkCnt[w] = __popcll(hbA); chunkCnt[16 + w] = __popcll(hbB); }
  if (tid >= HEAVY && tid < 256) cidL[tid] = 32767;
  __syncthreads();
  if (tid == 0){
    int s2 = 0;
    for (int i2 = 0; i2 < 32; ++i2){ int c2 = chunkCnt[i2]; chunkCnt[i2] = s2; s2 += c2; }
  }
  __syncthreads();
  if (hvA) cidL[chunkCnt[w] + __popcll(hbA & below)] = (short)tid;
  if (hvB) cidL[chunkCnt[16 + w] + __popcll(hbB & below)] = (short)(tid + 1024);
  __syncthreads();
  if (tid < 256) cidx[h * 256 + tid] = cidL[tid];
}

// ---------------- gather heavy K rows + V cols (full-grid, 384 blocks) ----------------
__global__ void k_gath(const u16* __restrict__ Kb, const u16* __restrict__ Vb,
                       const short* __restrict__ cidx,
                       u16* __restrict__ Kg, u16* __restrict__ Vg){
  __shared__ __align__(16) u16 t[32][136];
  int b = blockIdx.x, tid = threadIdx.x;
  if (b < 256){
    int gid = b * 256 + tid;                   // 16h * 256slot * 16chunk = 65536
    int h = gid >> 12, rem = gid & 4095;
    int slot = rem >> 4, cp = rem & 15;
    int cid = cidx[h * 256 + slot];
    bf16x8 z = (bf16x8){0,0,0,0,0,0,0,0};
    bf16x8 val = (cid < 2048) ? *(const bf16x8*)(Kb + (size_t)cid * 2048 + h * 128 + cp * 8) : z;
    *(bf16x8*)(Kg + ((size_t)h * 256 + slot) * 128 + cp * 8) = val;
  } else {
    int b2 = b - 256;
    int h = b2 >> 3, s0 = (b2 & 7) * 32;
#pragma unroll
    for (int it = 0; it < 2; ++it){
      int m = it * 256 + tid;                  // 512 chunks = 32 slots x 16 chunks
      int s = m >> 4, cp = m & 15;
      int cid = cidx[h * 256 + s0 + s];
      bf16x8 z = (bf16x8){0,0,0,0,0,0,0,0};
      bf16x8 val = (cid < 2048) ? *(const bf16x8*)(Vb + (size_t)cid * 2048 + h * 128 + cp * 8) : z;
      *(bf16x8*)(&t[s][cp * 8]) = val;
    }
    __syncthreads();
#pragma unroll
    for (int i = 0; i < 16; ++i){
      int idx = i * 256 + tid;                 // 4096 = 128 d x 32 s
      int d = idx >> 5, s = idx & 31;
      Vg[((size_t)h * 128 + d) * 256 + s0 + s] = t[s][d];
    }
  }
}

// ---------------- pass 2: QBLK=128, Q-in-reg, K+V LDS dbuf, 2 barriers/iter ----------------
// grid (16, 16) = 256 blocks, 512 thr (8 waves: 2 q-halves x 4 strips)
__global__ __launch_bounds__(512)
void k_pass2(const u16* __restrict__ Q, const u16* __restrict__ K, const u16* __restrict__ Vt,
             const u16* __restrict__ Kg, const u16* __restrict__ Vg,
             const short* __restrict__ cidx, u16* __restrict__ attn){
  __shared__ __align__(16) u16 Ks[2][64 * 128];
  __shared__ __align__(16) u16 Vs[2][128 * 64];
  __shared__ __align__(16) u16 Ps[8][16 * 64];
  __shared__ short cids[256];
  __shared__ int lists[12];
  __shared__ int nact_s;
  const int tid = threadIdx.x;
  const int w = tid >> 6, lane = tid & 63;
  const int g = lane >> 4, c15 = lane & 15;
  const int qb = blockIdx.x, h = blockIdx.y;
  const int i0 = qb * 128;
  const int wq = w >> 2, w4 = w & 3;
  const int rowbase = i0 + wq * 64 + w4 * 16;
  const u16* Qh = Q + h * HDIM;
  const u16* Kh = K + h * HDIM;
  const u16* Kgh = Kg + (size_t)h * 256 * 128;
  const u16* Vth = Vt + (size_t)h * 128 * 2048;
  const u16* Vgh = Vg + (size_t)h * 128 * 256;
  const float scale = 0.08838834764831845f;

  if (tid < 256) cids[tid] = cidx[h * 256 + tid];
  // Q fragments in registers (rows rowbase + c15)
  bf16x8 qfr[4];
#pragma unroll
  for (int ks = 0; ks < 4; ks++)
    qfr[ks] = *(const bf16x8*)(Qh + (size_t)(rowbase + c15) * 2048 + ks * 32 + g * 8);
  __syncthreads();
  if (tid == 0){
    int n = 0;
    int ktb0 = (i0 > RECENT) ? ((i0 - RECENT) >> 6) : 0;
    int ktmax = (i0 + 127) >> 6;
    for (int kt = ktb0; kt <= ktmax; ++kt) lists[n++] = kt;
    for (int gt = 0; gt < 4; ++gt)
      if ((int)cids[gt * 64] <= i0 + 127 - RECENT - 1) lists[n++] = 100 + gt;
    nact_s = n;
  }
  __syncthreads();
  const int nact = nact_s;

  // prologue: stage K0 (2) + V0 (2) only
  { int e = lists[0];
    if (e < 100){ stageK512(Kh, 2048, e * 64, Ks[0], tid);
                  stageV512(Vth, 2048, e * 64, Vs[0], tid); }
    else        { stageK512(Kgh, 128, (e - 100) * 64, Ks[0], tid);
                  stageV512(Vgh, 256, (e - 100) * 64, Vs[0], tid); } }

  f32x4 oacc[8];
#pragma unroll
  for (int f = 0; f < 8; f++) oacc[f] = (f32x4){0.f, 0.f, 0.f, 0.f};
  float lsum[4] = {0.f, 0.f, 0.f, 0.f};

  int cur = 0;
  for (int i = 0; i < nact; ++i){
    const int e = lists[i];
    const bool isg = (e >= 100);
    const bool nxt = (i + 1 < nact);
    WAITVM(2);                 // retire K(i); keep V(i)
    BARRAW;
    if (nxt){                  // stage K/V(i+1) AFTER barrier (no race vs iter i-1 reads)
      int e2 = lists[i + 1];
      if (e2 < 100){ stageK512(Kh, 2048, e2 * 64, Ks[cur ^ 1], tid);
                     stageV512(Vth, 2048, e2 * 64, Vs[cur ^ 1], tid); }
      else         { stageK512(Kgh, 128, (e2 - 100) * 64, Ks[cur ^ 1], tid);
                     stageV512(Vgh, 256, (e2 - 100) * 64, Vs[cur ^ 1], tid); }
    }
    // QK^T
    f32x4 sacc[4];
#pragma unroll
    for (int n = 0; n < 4; n++) sacc[n] = (f32x4){0.f, 0.f, 0.f, 0.f};
#pragma unroll
    for (int ks = 0; ks < 4; ++ks){
#pragma unroll
      for (int n = 0; n < 4; n++){
        int brw = n * 16 + c15;
        bf16x8 b = *(const bf16x8*)(Ks[cur] + brw * 128 + ((ks * 32 + g * 8) ^ ((brw & 7) << 3)));
        sacc[n] = __builtin_amdgcn_mfma_f32_16x16x32_bf16(qfr[ks], b, sacc[n], 0, 0, 0);
      }
    }
    // masked exp -> P (LDS, wave-private), row sums
#pragma unroll
    for (int n = 0; n < 4; n++){
      int cid = isg ? (int)cids[(e - 100) * 64 + n * 16 + c15] : (e * 64 + n * 16 + c15);
#pragma unroll
      for (int r = 0; r < 4; r++){
        int rowg = rowbase + g * 4 + r;
        int dist = rowg - cid;
        bool valid = (cid <= rowg) && (isg ? (dist > RECENT) : (dist <= RECENT));
        float ev = valid ? __expf(sacc[n][r] * scale) : 0.f;
        lsum[r] += ev;
        int prow = g * 4 + r;
        Ps[w][prow * 64 + ((n * 16 + c15) ^ ((prow & 7) << 3))] = f2bf(ev);
      }
    }
    // retire V(i) (keep K/V(i+1)), then PV from LDS
    if (nxt) WAITVM(4); else WAITVM(0);
    BARRAW;
    PRIO1;
#pragma unroll
    for (int ks2 = 0; ks2 < 2; ++ks2){
      bf16x8 pa = *(const bf16x8*)(&Ps[w][c15 * 64 + ((ks2 * 32 + g * 8) ^ ((c15 & 7) << 3))]);
#pragma unroll
      for (int f = 0; f < 8; ++f){
        int vrow = f * 16 + c15;
        bf16x8 vb = *(const bf16x8*)(Vs[cur] + vrow * 64 + ((ks2 * 32 + g * 8) ^ ((vrow & 7) << 3)));
        oacc[f] = __builtin_amdgcn_mfma_f32_16x16x32_bf16(pa, vb, oacc[f], 0, 0, 0);
      }
    }
    PRIO0;
    cur ^= 1;
  }
  float rinv[4];
#pragma unroll
  for (int r = 0; r < 4; r++){
    float v = lsum[r];
    v += __shfl_xor(v, 1); v += __shfl_xor(v, 2);
    v += __shfl_xor(v, 4); v += __shfl_xor(v, 8);
    rinv[r] = 1.0f / v;
  }
#pragma unroll
  for (int f = 0; f < 8; f++)
#pragma unroll
    for (int r = 0; r < 4; r++){
      int rowg = rowbase + g * 4 + r;
      attn[(size_t)rowg * 2048 + h * HDIM + f * 16 + c15] = f2bf(oacc[f][r] * rinv[r]);
    }
}

// ---------------- host launcher ----------------
extern "C" void kernel_launch(void* const* d_in, const int* in_sizes, int n_in,
                              void* d_out, int out_size, void* d_ws, size_t ws_size,
                              hipStream_t stream){
  const float* X  = (const float*)d_in[0];
  const float* Wq = (const float*)d_in[1];
  const float* Wk = (const float*)d_in[2];
  const float* Wv = (const float*)d_in[3];
  const float* Wo = (const float*)d_in[4];

  char* w = (char*)d_ws;
  const size_t MB8 = (size_t)2048 * 2048 * 2;   // one bf16 matrix = 8 MiB
  u16* Xb  = (u16*)(w);
  u16* Wqb = (u16*)(w + 1 * MB8);
  u16* Wkb = (u16*)(w + 2 * MB8);
  u16* Wvb = (u16*)(w + 3 * MB8);
  u16* Wob = (u16*)(w + 4 * MB8);
  u16* Qb  = (u16*)(w + 5 * MB8);
  u16* Kb  = (u16*)(w + 6 * MB8);
  u16* Vb  = (u16*)(w + 7 * MB8);
  u16* Vtb   = Wqb;   // Wq dead after projections
  u16* attnb = Xb;    // X dead after projections
  char* p = w + 8 * MB8;
  float* cosT = (float*)p;              p += 524288;
  float* sinT = (float*)p;              p += 524288;
  float* colsum = (float*)p;            p += 131072;   // zeroed in k_prep (with rowsum)
  float* rowsum = (float*)p;            p += 131072;
  short* cidx  = (short*)p;             p += 16 * 256 * 2;
  u16*   Kg    = (u16*)p;               p += (size_t)16 * 256 * 128 * 2;
  u16*   Vg    = (u16*)p;

  dim3 b256(256);

  k_prep<<<21056, b256, 0, stream>>>(X, Wq, Wk, Wv, Wo, Xb, cosT, sinT, colsum);

  k_g256<<<dim3(32, 16), dim3(512), 0, stream>>>(Xb, Wqb, Wkb, Wvb, Qb, Kb, Vb);
  k_post<<<8192, b256, 0, stream>>>(Qb, Kb, cosT, sinT, Vb, Vtb);

  k_pass1a<<<dim3(40, 16), b256, 0, stream>>>(Qb, Kb, rowsum);
  k_pass1b<<<dim3(40, 16), b256, 0, stream>>>(Qb, Kb, rowsum, colsum);
  k_topk<<<16, dim3(1024), 0, stream>>>(colsum, cidx);
  k_gath<<<384, b256, 0, stream>>>(Kb, Vb, cidx, Kg, Vg);
  k_pass2<<<dim3(16, 16), dim3(512), 0, stream>>>(Qb, Kb, Vtb, Kg, Vg, cidx, attnb);

  k_gemm_out<<<dim3(16, 16), dim3(512), 0, stream>>>(attnb, Wob, (float*)d_out);
}

// Round 13
// 251.857 us; speedup vs baseline: 1.0022x; 1.0022x over previous
//
#include <hip/hip_runtime.h>
#include <hip/hip_bf16.h>
#include <stdint.h>

// Problem constants: b=1, s=2048, hidden=2048, H=16, d=128
#define SEQ   2048
#define HIDN  2048
#define NHEAD 16
#define HDIM  128
#define HEAVY 204   // int(0.1*2048)
#define RECENT 204

typedef __attribute__((ext_vector_type(4))) float f32x4;
typedef __attribute__((ext_vector_type(8))) short bf16x8;
typedef unsigned short u16;
typedef unsigned int   u32;

static __device__ __forceinline__ u16 f2bf(float f){
  union { float f; u32 u; } v; v.f = f;
  u32 r = (v.u + 0x7FFFu + ((v.u >> 16) & 1u)) >> 16;
  return (u16)r;
}
static __device__ __forceinline__ float bf2f(u16 u){
  union { u32 u; float f; } v; v.u = ((u32)u) << 16;
  return v.f;
}

// global -> LDS direct 16B load (dest is wave-uniform base + lane*16)
static __device__ __forceinline__ void gload16(const void* g, void* l){
  __builtin_amdgcn_global_load_lds((const __attribute__((address_space(1))) u32*)g,
                                   (__attribute__((address_space(3))) u32*)l, 16, 0, 0);
}

#define WAITVM(N) asm volatile("s_waitcnt vmcnt(" #N ")" ::: "memory")
#define BARRAW    __builtin_amdgcn_s_barrier()
#define PRIO1     __builtin_amdgcn_s_setprio(1)
#define PRIO0     __builtin_amdgcn_s_setprio(0)

// stage a 64x128 bf16 tile with 256 threads, runtime row stride (XOR-swizzled source)
static __device__ __forceinline__ void stage_tile(const u16* __restrict__ base, size_t stride,
                                                  int row0, u16* __restrict__ lds, int tid){
  const int wbase = tid & ~63;
#pragma unroll
  for (int it = 0; it < 4; ++it){
    int m = it * 256 + tid;
    int row = m >> 4, cp = m & 15;
    gload16(base + (size_t)(row0 + row) * stride + ((cp ^ (row & 7)) * 8),
            lds + (it * 256 + wbase) * 8);
  }
}

// stage 64x128 tile with 512 threads, runtime stride
static __device__ __forceinline__ void stageK512(const u16* __restrict__ base, size_t stride,
                                                 int row0, u16* __restrict__ lds, int tid){
#pragma unroll
  for (int it = 0; it < 2; ++it){
    int m = it * 512 + tid;
    int row = m >> 4, cp = m & 15;
    gload16(base + (size_t)(row0 + row) * stride + ((cp ^ (row & 7)) * 8),
            lds + (it * 512 + (tid & ~63)) * 8);
  }
}
// stage 128-row x 64-col tile (col offset c0) with 512 threads, runtime stride
static __device__ __forceinline__ void stageV512(const u16* __restrict__ base, size_t stride,
                                                 int c0, u16* __restrict__ lds, int tid){
#pragma unroll
  for (int it = 0; it < 2; ++it){
    int m = it * 512 + tid;
    int row = m >> 3, cp = m & 7;
    gload16(base + (size_t)row * stride + c0 + ((cp ^ (row & 7)) * 8),
            lds + (it * 512 + (tid & ~63)) * 8);
  }
}

// ---------------- prep: cvt5 + rope tables + zero colsum/rowsum (fused) ----------------
__global__ void k_prep(const float* __restrict__ A0, const float* __restrict__ A1,
                       const float* __restrict__ A2, const float* __restrict__ A3,
                       const float* __restrict__ A4, u16* __restrict__ out,
                       float* __restrict__ cosT, float* __restrict__ sinT,
                       float* __restrict__ colsum){
  int b = blockIdx.x, tid = threadIdx.x;
  if (b < 20480){
    int id = b * 256 + tid;
    int sel = id >> 20, off = (id & 1048575) * 4;
    const float* src = sel == 0 ? A0 : sel == 1 ? A1 : sel == 2 ? A2 : sel == 3 ? A3 : A4;
    float4 v = *(const float4*)(src + off);
    ushort4 o;
    o.x = f2bf(v.x); o.y = f2bf(v.y); o.z = f2bf(v.z); o.w = f2bf(v.w);
    *(ushort4*)(out + (size_t)sel * 4194304 + off) = o;
  } else if (b < 20992){
    int i = (b - 20480) * 256 + tid;           // 2048*64
    int pos = i >> 6, j = i & 63;
    float invf = powf(10000.0f, -(float)j * (1.0f / 64.0f));
    float a = (float)pos * invf;
    cosT[i] = cosf(a);
    sinT[i] = sinf(a);
  } else {
    int i = (b - 20992) * 256 + tid;           // 16384 float4 = colsum+rowsum (contiguous)
    if (i < 16384) ((float4*)colsum)[i] = (float4){0.f, 0.f, 0.f, 0.f};
  }
}

// ---------------- post: rope on Q,K + transpose V (fused) ----------------
__global__ void k_post(u16* __restrict__ Qm, u16* __restrict__ Km,
                       const float* __restrict__ cosT, const float* __restrict__ sinT,
                       const u16* __restrict__ V, u16* __restrict__ Vt){
  __shared__ u16 t[32][33];
  int b = blockIdx.x, tid = threadIdx.x;
  if (b < 4096){
    int gid = b * 256 + tid;                   // 2 * 524288
    u16* M = (gid < 524288) ? Qm : Km;
    int id = gid & 524287;
    int pos = id >> 8, rem = id & 255;
    int h = rem >> 4, j4 = (rem & 15) * 4;
    u16* p = M + (size_t)pos * HIDN + h * HDIM + j4;
    ushort4 lo = *(ushort4*)p;
    ushort4 hi = *(ushort4*)(p + 64);
    float4 c = *(const float4*)(cosT + pos * 64 + j4);
    float4 s = *(const float4*)(sinT + pos * 64 + j4);
    float l0 = bf2f(lo.x), l1 = bf2f(lo.y), l2 = bf2f(lo.z), l3 = bf2f(lo.w);
    float h0 = bf2f(hi.x), h1 = bf2f(hi.y), h2 = bf2f(hi.z), h3 = bf2f(hi.w);
    ushort4 nlo, nhi;
    nlo.x = f2bf(l0 * c.x - h0 * s.x);  nhi.x = f2bf(h0 * c.x + l0 * s.x);
    nlo.y = f2bf(l1 * c.y - h1 * s.y);  nhi.y = f2bf(h1 * c.y + l1 * s.y);
    nlo.z = f2bf(l2 * c.z - h2 * s.z);  nhi.z = f2bf(h2 * c.z + l2 * s.z);
    nlo.w = f2bf(l3 * c.w - h3 * s.w);  nhi.w = f2bf(h3 * c.w + l3 * s.w);
    *(ushort4*)p = nlo;
    *(ushort4*)(p + 64) = nhi;
  } else {
    int b2 = b - 4096;
    int s0 = (b2 & 63) * 32, c0 = (b2 >> 6) * 32;
    int r = tid >> 3, cc = (tid & 7) * 4;
    ushort4 v = *(const ushort4*)(V + (size_t)(s0 + r) * 2048 + c0 + cc);
    t[r][cc] = v.x; t[r][cc + 1] = v.y; t[r][cc + 2] = v.z; t[r][cc + 3] = v.w;
    __syncthreads();
    int co = tid >> 3, ro = (tid & 7) * 4;
    ushort4 o;
    o.x = t[ro][co]; o.y = t[ro + 1][co]; o.z = t[ro + 2][co]; o.w = t[ro + 3][co];
    *(ushort4*)(Vt + (size_t)(c0 + co) * 2048 + s0 + ro) = o;
  }
}

// ---------------- fused projection GEMM: C[2048][6144] = X @ [Wq;Wk;Wv]^T ----------------
// 128x192 tile, BK=32, 8 waves (2M x 4N), 40 KB LDS, 2 blocks/CU (4 waves/SIMD).
// Counted vmcnt 2-buffer. Swizzle fixed for 64B rows: chunk = g ^ ((row>>1)&3)
// (even rows cycle all 4 chunks -> exactly 2-way bank aliasing = free).
// grid (32, 16) = 512 blocks = exactly 2 per CU.
__global__ __launch_bounds__(512, 4)
void k_g256(const u16* __restrict__ X, const u16* __restrict__ Wq, const u16* __restrict__ Wk,
            const u16* __restrict__ Wv, u16* __restrict__ C0, u16* __restrict__ C1,
            u16* __restrict__ C2){
  __shared__ __align__(16) u16 LA[2][128 * 32];
  __shared__ __align__(16) u16 LB[2][192 * 32];
  const int tid = threadIdx.x;
  const int lane = tid & 63, wvi = tid >> 6;
  const int wm = wvi >> 2, wn = wvi & 3;
  const int g = lane >> 4, c15 = lane & 15;
  const int brow = blockIdx.y * 128;       // [0,2048)
  const int bcol = blockIdx.x * 192;       // [0,6144)
  const int NT = 64;                       // K tiles of 32
  const int cc = (g ^ ((c15 >> 1) & 3)) * 8;   // fixed swizzle (row>>1)&3 == (c15>>1)&3

  f32x4 acc[4][3];
#pragma unroll
  for (int m = 0; m < 4; m++)
#pragma unroll
    for (int n = 0; n < 3; n++) acc[m][n] = (f32x4){0.f, 0.f, 0.f, 0.f};

#define BPTR(rB_) (rB_ < 2048 ? Wq + (size_t)(rB_) * 2048 \
                 : rB_ < 4096 ? Wk + (size_t)((rB_) - 2048) * 2048 \
                              : Wv + (size_t)((rB_) - 4096) * 2048)
// one stage = 3 uniform loads/thread: A (128x32), B rows 0-127, B rows 128-191
// (last staged twice by wave-halves to identical LDS bytes -- benign, keeps vmcnt uniform)
#define STG(kt, buf) do { \
    const int k0_ = (kt) * 32; \
    { int row_ = tid >> 2, cp_ = tid & 3; \
      gload16(X + (size_t)(brow + row_) * 2048 + k0_ + ((cp_ ^ ((row_ >> 1) & 3)) * 8), \
              &LA[buf][0] + (tid & ~63) * 8); } \
    { int row_ = tid >> 2, cp_ = tid & 3; int rB_ = bcol + row_; \
      const u16* bp_ = BPTR(rB_); \
      gload16(bp_ + k0_ + ((cp_ ^ ((row_ >> 1) & 3)) * 8), \
              &LB[buf][0] + (tid & ~63) * 8); } \
    { int c2_ = 512 + (tid & 255); int row_ = c2_ >> 2, cp_ = c2_ & 3; int rB_ = bcol + row_; \
      const u16* bp_ = BPTR(rB_); \
      gload16(bp_ + k0_ + ((cp_ ^ ((row_ >> 1) & 3)) * 8), \
              &LB[buf][0] + (512 + (tid & 192)) * 8); } \
  } while(0)

  STG(0, 0);
  for (int t = 0; t < NT; ++t){
    const int buf = t & 1;
    if (t + 1 < NT){ STG(t + 1, buf ^ 1); WAITVM(3); }
    else           { WAITVM(0); }
    BARRAW;
    bf16x8 af[4], bfv[3];
#pragma unroll
    for (int mi = 0; mi < 4; ++mi)
      af[mi] = *(const bf16x8*)(&LA[buf][0] + (size_t)(wm * 64 + mi * 16 + c15) * 32 + cc);
#pragma unroll
    for (int ni = 0; ni < 3; ++ni)
      bfv[ni] = *(const bf16x8*)(&LB[buf][0] + (size_t)(wn * 48 + ni * 16 + c15) * 32 + cc);
    PRIO1;
#pragma unroll
    for (int mi = 0; mi < 4; ++mi)
#pragma unroll
      for (int ni = 0; ni < 3; ++ni)
        acc[mi][ni] = __builtin_amdgcn_mfma_f32_16x16x32_bf16(af[mi], bfv[ni], acc[mi][ni], 0, 0, 0);
    PRIO0;
    BARRAW;
  }
#undef STG
#undef BPTR

#pragma unroll
  for (int mi = 0; mi < 4; ++mi)
#pragma unroll
    for (int ni = 0; ni < 3; ++ni){
      int colbase = bcol + wn * 48 + ni * 16;      // 2048-boundary is 16-aligned
      int proj = colbase >> 11;
      u16* Cb = proj == 0 ? C0 : proj == 1 ? C1 : C2;
      int lc = (colbase & 2047) + c15;
#pragma unroll
      for (int r = 0; r < 4; ++r){
        int row = brow + wm * 64 + mi * 16 + g * 4 + r;
        Cb[(size_t)row * 2048 + lc] = f2bf(acc[mi][ni][r]);
      }
    }
}

// ---------------- output GEMM: 128x128 tile, BK=64, 8 waves, counted vmcnt ----------------
// grid (16,16) = 256 blocks, 512 thr = 2 waves/SIMD
__global__ __launch_bounds__(512)
void k_gemm_out(const u16* __restrict__ A, const u16* __restrict__ B, float* __restrict__ C){
  __shared__ __align__(16) u16 As[2][128 * 64];
  __shared__ __align__(16) u16 Bs[2][128 * 64];
  const int tid = threadIdx.x;
  const int w = tid >> 6, lane = tid & 63;
  const int wm = w >> 1, wn = w & 1;
  const int g = lane >> 4, c15 = lane & 15;
  const int brow = blockIdx.y * 128, bcol = blockIdx.x * 128;
  const int cc0 = ((g ^ (c15 & 7)) * 8);

  f32x4 acc[2][4];
#pragma unroll
  for (int m = 0; m < 2; m++)
#pragma unroll
    for (int n = 0; n < 4; n++) acc[m][n] = (f32x4){0.f, 0.f, 0.f, 0.f};

#define STG_O(k0, buf) do { \
  _Pragma("unroll") for (int it = 0; it < 2; ++it){ \
    int m_ = it * 512 + tid; \
    int row_ = m_ >> 3, cp_ = m_ & 7; \
    gload16(A + (size_t)(brow + row_) * 2048 + (k0) + ((cp_ ^ (row_ & 7)) * 8), \
            As[buf] + (it * 512 + (tid & ~63)) * 8); \
    gload16(B + (size_t)(bcol + row_) * 2048 + (k0) + ((cp_ ^ (row_ & 7)) * 8), \
            Bs[buf] + (it * 512 + (tid & ~63)) * 8); \
  } } while(0)

  STG_O(0, 0);
  int cur = 0;
  for (int kt = 0; kt < 32; ++kt){
    if (kt + 1 < 32){ STG_O((kt + 1) * 64, cur ^ 1); WAITVM(4); }
    else            { WAITVM(0); }
    BARRAW;
    bf16x8 af[2][2], bfr[4][2];
#pragma unroll
    for (int mi = 0; mi < 2; ++mi){
      const u16* pr = As[cur] + (size_t)(wm * 32 + mi * 16 + c15) * 64;
      af[mi][0] = *(const bf16x8*)(pr + cc0);
      af[mi][1] = *(const bf16x8*)(pr + (cc0 ^ 32));
    }
#pragma unroll
    for (int ni = 0; ni < 4; ++ni){
      const u16* pr = Bs[cur] + (size_t)(wn * 64 + ni * 16 + c15) * 64;
      bfr[ni][0] = *(const bf16x8*)(pr + cc0);
      bfr[ni][1] = *(const bf16x8*)(pr + (cc0 ^ 32));
    }
    PRIO1;
#pragma unroll
    for (int mi = 0; mi < 2; ++mi)
#pragma unroll
      for (int ni = 0; ni < 4; ++ni)
#pragma unroll
        for (int kk = 0; kk < 2; ++kk)
          acc[mi][ni] = __builtin_amdgcn_mfma_f32_16x16x32_bf16(af[mi][kk], bfr[ni][kk],
                                                                acc[mi][ni], 0, 0, 0);
    PRIO0;
    BARRAW;
    cur ^= 1;
  }
#undef STG_O
#pragma unroll
  for (int mi = 0; mi < 2; ++mi)
#pragma unroll
    for (int ni = 0; ni < 4; ++ni)
#pragma unroll
      for (int r = 0; r < 4; ++r){
        int row = brow + wm * 32 + mi * 16 + g * 4 + r;
        int col = bcol + wn * 64 + ni * 16 + c15;
        C[(size_t)row * 2048 + col] = acc[mi][ni][r];
      }
}

// ---------------- pass 1a: rowsum of exp (causal), Q-in-registers ----------------
// grid (40, 16), 256 thr; K triple-buffered LDS stream, 1 barrier/iter.
__global__ __launch_bounds__(256)
void k_pass1a(const u16* __restrict__ Q, const u16* __restrict__ K, float* __restrict__ rowsum){
  __shared__ __align__(16) u16 Ks[3][64 * 128];
  const int tid = threadIdx.x;
  const int wv = tid >> 6, lane = tid & 63;
  const int g = lane >> 4, c15 = lane & 15;
  const int h = blockIdx.y;
  int qb = 0, c = 0;
  { int rem = blockIdx.x; int q = 0;
    while (rem >= ((2 * q + 9) >> 3)){ rem -= (2 * q + 9) >> 3; q++; }
    qb = q; c = rem; }
  const int i0 = qb * 128;
  const int ktend = 2 * qb + 2;
  const int kt0 = c * 8;
  const int kt1 = (ktend < kt0 + 8) ? ktend : (kt0 + 8);
  const u16* Qh = Q + h * HDIM;
  const u16* Kh = K + h * HDIM;
  const float scale = 0.08838834764831845f;   // 1/sqrt(128)
  const int wb = wv * 32;

  bf16x8 qfr[2][4];
#pragma unroll
  for (int m = 0; m < 2; m++)
#pragma unroll
    for (int ks = 0; ks < 4; ks++)
      qfr[m][ks] = *(const bf16x8*)(Qh + (size_t)(i0 + wb + m * 16 + c15) * 2048 + ks * 32 + g * 8);

  stage_tile(Kh, 2048, kt0 * 64, Ks[0], tid);
  if (kt0 + 1 < kt1) stage_tile(Kh, 2048, (kt0 + 1) * 64, Ks[1], tid);

  float rs[2][4] = {{0.f,0.f,0.f,0.f},{0.f,0.f,0.f,0.f}};
  for (int kt = kt0; kt < kt1; ++kt){
    const int bi = (kt - kt0) % 3;
    if (kt + 1 < kt1){ WAITVM(4); } else { WAITVM(0); }
    BARRAW;
    if (kt + 2 < kt1) stage_tile(Kh, 2048, (kt + 2) * 64, Ks[(kt - kt0 + 2) % 3], tid);
    const int k0 = kt * 64;
    f32x4 sacc[2][4];
#pragma unroll
    for (int m = 0; m < 2; m++)
#pragma unroll
      for (int n = 0; n < 4; n++) sacc[m][n] = (f32x4){0.f, 0.f, 0.f, 0.f};
#pragma unroll
    for (int ks = 0; ks < 4; ++ks){
#pragma unroll
      for (int n = 0; n < 4; n++){
        int brw = n * 16 + c15;
        bf16x8 b = *(const bf16x8*)(Ks[bi] + brw * 128 + ((ks * 32 + g * 8) ^ ((brw & 7) << 3)));
#pragma unroll
        for (int m = 0; m < 2; m++)
          sacc[m][n] = __builtin_amdgcn_mfma_f32_16x16x32_bf16(qfr[m][ks], b, sacc[m][n], 0, 0, 0);
      }
    }
    if (kt < 2 * qb){            // fully causal tile: no mask compare
#pragma unroll
      for (int m = 0; m < 2; m++)
#pragma unroll
        for (int n = 0; n < 4; n++)
#pragma unroll
          for (int r = 0; r < 4; r++)
            rs[m][r] += __expf(sacc[m][n][r] * scale);
    } else {
#pragma unroll
      for (int n = 0; n < 4; n++){
        int col = k0 + n * 16 + c15;
#pragma unroll
        for (int m = 0; m < 2; m++)
#pragma unroll
          for (int r = 0; r < 4; r++){
            int rowg = i0 + wb + m * 16 + g * 4 + r;
            rs[m][r] += (col <= rowg) ? __expf(sacc[m][n][r] * scale) : 0.f;
          }
      }
    }
  }
#pragma unroll
  for (int m = 0; m < 2; m++)
#pragma unroll
    for (int r = 0; r < 4; r++){
      float v = rs[m][r];
      v += __shfl_xor(v, 1); v += __shfl_xor(v, 2);
      v += __shfl_xor(v, 4); v += __shfl_xor(v, 8);
      if (c15 == 0)
        atomicAdd(&rowsum[h * 2048 + i0 + wb + m * 16 + g * 4 + r], v);
    }
}

// ---------------- pass 1b: colsum of normalized exp, K-in-registers ----------------
// grid (40, 16), 256 thr; Q triple-buffered LDS stream, 1 barrier/iter.
__global__ __launch_bounds__(256)
void k_pass1b(const u16* __restrict__ Q, const u16* __restrict__ K,
              const float* __restrict__ rowsum, float* __restrict__ colsum){
  __shared__ __align__(16) u16 Qs[3][64 * 128];
  const int tid = threadIdx.x;
  const int wv = tid >> 6, lane = tid & 63;
  const int g = lane >> 4, c15 = lane & 15;
  const int h = blockIdx.y;
  int kb = 0, c = 0;
  { int rem = blockIdx.x; int q = 0;
    while (rem >= ((39 - 2 * q) >> 3)){ rem -= (39 - 2 * q) >> 3; q++; }
    kb = q; c = rem; }
  const int k0 = kb * 128;
  const int qt0 = 2 * kb + c * 8;
  const int qt1 = (2 * kb + c * 8 + 8 < 32) ? (2 * kb + c * 8 + 8) : 32;
  const u16* Qh = Q + h * HDIM;
  const u16* Kh = K + h * HDIM;
  const float scale = 0.08838834764831845f;
  const int wb = wv * 32;
  const float* rsrow = rowsum + h * 2048;

  bf16x8 kfr[2][4];
#pragma unroll
  for (int m = 0; m < 2; m++)
#pragma unroll
    for (int ks = 0; ks < 4; ks++)
      kfr[m][ks] = *(const bf16x8*)(Kh + (size_t)(k0 + wb + m * 16 + c15) * 2048 + ks * 32 + g * 8);

  stage_tile(Qh, 2048, qt0 * 64, Qs[0], tid);
  if (qt0 + 1 < qt1) stage_tile(Qh, 2048, (qt0 + 1) * 64, Qs[1], tid);

  float racc[2][4] = {{0.f,0.f,0.f,0.f},{0.f,0.f,0.f,0.f}};
  for (int qt = qt0; qt < qt1; ++qt){
    const int bi = (qt - qt0) % 3;
    if (qt + 1 < qt1){ WAITVM(4); } else { WAITVM(0); }
    BARRAW;
    if (qt + 2 < qt1) stage_tile(Qh, 2048, (qt + 2) * 64, Qs[(qt - qt0 + 2) % 3], tid);
    const int i0q = qt * 64;
    float rw[4];
#pragma unroll
    for (int n = 0; n < 4; n++)
      rw[n] = 1.0f / rsrow[i0q + n * 16 + c15];
    f32x4 sacc[2][4];
#pragma unroll
    for (int m = 0; m < 2; m++)
#pragma unroll
      for (int n = 0; n < 4; n++) sacc[m][n] = (f32x4){0.f, 0.f, 0.f, 0.f};
#pragma unroll
    for (int ks = 0; ks < 4; ++ks){
#pragma unroll
      for (int n = 0; n < 4; n++){
        int brw = n * 16 + c15;
        bf16x8 b = *(const bf16x8*)(Qs[bi] + brw * 128 + ((ks * 32 + g * 8) ^ ((brw & 7) << 3)));
#pragma unroll
        for (int m = 0; m < 2; m++)
          sacc[m][n] = __builtin_amdgcn_mfma_f32_16x16x32_bf16(kfr[m][ks], b, sacc[m][n], 0, 0, 0);
      }
    }
    if (qt >= 2 * kb + 2){       // fully causal: no mask compare
#pragma unroll
      for (int m = 0; m < 2; m++)
#pragma unroll
        for (int n = 0; n < 4; n++)
#pragma unroll
          for (int r = 0; r < 4; r++)
            racc[m][r] += __expf(sacc[m][n][r] * scale) * rw[n];
    } else {
#pragma unroll
      for (int n = 0; n < 4; n++){
        int colq = i0q + n * 16 + c15;
#pragma unroll
        for (int m = 0; m < 2; m++)
#pragma unroll
          for (int r = 0; r < 4; r++){
            int rowk = k0 + wb + m * 16 + g * 4 + r;
            racc[m][r] += (rowk <= colq) ? __expf(sacc[m][n][r] * scale) * rw[n] : 0.f;
          }
      }
    }
  }
#pragma unroll
  for (int m = 0; m < 2; m++)
#pragma unroll
    for (int r = 0; r < 4; r++){
      float v = racc[m][r];
      v += __shfl_xor(v, 1); v += __shfl_xor(v, 2);
      v += __shfl_xor(v, 4); v += __shfl_xor(v, 8);
      if (c15 == 0)
        atomicAdd(&colsum[h * 2048 + k0 + wb + m * 16 + g * 4 + r], v);
    }
}

// ---------------- top-k via exact radix-select (select only, 16 blocks) ----------------
__global__ __launch_bounds__(1024)
void k_topk(const float* __restrict__ colsum, short* __restrict__ cidx){
  __shared__ u32 keys[2048];
  __shared__ int hist[256];
  __shared__ int chunkCnt[32];
  __shared__ short cidL[256];
  __shared__ u32 Tacc_s;
  __shared__ int rem_s;
  const int tid = threadIdx.x;
  const int h = blockIdx.x;
  const int w = tid >> 6, lane = tid & 63;

  for (int i = tid; i < 2048; i += 1024) keys[i] = ((const u32*)colsum)[h * 2048 + i];
  if (tid == 0){ Tacc_s = 0; rem_s = HEAVY; }
  __syncthreads();

  for (int s = 24; s >= 0; s -= 8){
    if (tid < 256) hist[tid] = 0;
    __syncthreads();
    u32 T = Tacc_s;
    for (int i = tid; i < 2048; i += 1024){
      u32 k = keys[i];
      bool match = (s == 24) ? true : (((k ^ T) >> (s + 8)) == 0);
      if (match) atomicAdd(&hist[(k >> s) & 255], 1);
    }
    __syncthreads();
    if (tid == 0){
      int rem = rem_s, acc = 0, b = 255;
      for (; b > 0; --b){
        int c2 = hist[b];
        if (acc + c2 >= rem) break;
        acc += c2;
      }
      Tacc_s = T | ((u32)b << s);
      rem_s = rem - acc;
    }
    __syncthreads();
  }
  const u32 T = Tacc_s;
  const int need = rem_s;                 // smallest-index ties among == T
  const u32 kA = keys[tid], kB = keys[tid + 1024];
  const bool eqA = (kA == T), eqB = (kB == T);
  unsigned long long ebA = __ballot(eqA);
  unsigned long long ebB = __ballot(eqB);
  if (lane == 0){ chunkCnt[w] = __popcll(ebA); chunkCnt[16 + w] = __popcll(ebB); }
  __syncthreads();
  if (tid == 0){
    int s2 = 0;
    for (int i2 = 0; i2 < 32; ++i2){ int c2 = chunkCnt[i2]; chunkCnt[i2] = s2; s2 += c2; }
  }
  __syncthreads();
  const unsigned long long below = (1ull << lane) - 1ull;
  const int eqrA = chunkCnt[w] + __popcll(ebA & below);
  const int eqrB = chunkCnt[16 + w] + __popcll(ebB & below);
  const bool hvA = (kA > T) || (eqA && eqrA < need);
  const bool hvB = (kB > T) || (eqB && eqrB < need);
  __syncthreads();                        // before reusing chunkCnt
  unsigned long long hbA = __ballot(hvA);
  unsigned long long hbB = __ballot(hvB);
  if (lane == 0){ chunkCnt[w] = __popcll(hbA); chunkCnt[16 + w] = __popcll(hbB); }
  if (tid >= HEAVY && tid < 256) cidL[tid] = 32767;
  __syncthreads();
  if (tid == 0){
    int s2 = 0;
    for (int i2 = 0; i2 < 32; ++i2){ int c2 = chunkCnt[i2]; chunkCnt[i2] = s2; s2 += c2; }
  }
  __syncthreads();
  if (hvA) cidL[chunkCnt[w] + __popcll(hbA & below)] = (short)tid;
  if (hvB) cidL[chunkCnt[16 + w] + __popcll(hbB & below)] = (short)(tid + 1024);
  __syncthreads();
  if (tid < 256) cidx[h * 256 + tid] = cidL[tid];
}

// ---------------- gather heavy K rows + V cols (full-grid, 384 blocks) ----------------
__global__ void k_gath(const u16* __restrict__ Kb, const u16* __restrict__ Vb,
                       const short* __restrict__ cidx,
                       u16* __restrict__ Kg, u16* __restrict__ Vg){
  __shared__ __align__(16) u16 t[32][136];
  int b = blockIdx.x, tid = threadIdx.x;
  if (b < 256){
    int gid = b * 256 + tid;                   // 16h * 256slot * 16chunk = 65536
    int h = gid >> 12, rem = gid & 4095;
    int slot = rem >> 4, cp = rem & 15;
    int cid = cidx[h * 256 + slot];
    bf16x8 z = (bf16x8){0,0,0,0,0,0,0,0};
    bf16x8 val = (cid < 2048) ? *(const bf16x8*)(Kb + (size_t)cid * 2048 + h * 128 + cp * 8) : z;
    *(bf16x8*)(Kg + ((size_t)h * 256 + slot) * 128 + cp * 8) = val;
  } else {
    int b2 = b - 256;
    int h = b2 >> 3, s0 = (b2 & 7) * 32;
#pragma unroll
    for (int it = 0; it < 2; ++it){
      int m = it * 256 + tid;                  // 512 chunks = 32 slots x 16 chunks
      int s = m >> 4, cp = m & 15;
      int cid = cidx[h * 256 + s0 + s];
      bf16x8 z = (bf16x8){0,0,0,0,0,0,0,0};
      bf16x8 val = (cid < 2048) ? *(const bf16x8*)(Vb + (size_t)cid * 2048 + h * 128 + cp * 8) : z;
      *(bf16x8*)(&t[s][cp * 8]) = val;
    }
    __syncthreads();
#pragma unroll
    for (int i = 0; i < 16; ++i){
      int idx = i * 256 + tid;                 // 4096 = 128 d x 32 s
      int d = idx >> 5, s = idx & 31;
      Vg[((size_t)h * 128 + d) * 256 + s0 + s] = t[s][d];
    }
  }
}

// ---------------- pass 2: QBLK=128, Q-in-reg, K+V LDS dbuf, 2 barriers/iter ----------------
// grid (16, 16) = 256 blocks, 512 thr (8 waves: 2 q-halves x 4 strips)
__global__ __launch_bounds__(512)
void k_pass2(const u16* __restrict__ Q, const u16* __restrict__ K, const u16* __restrict__ Vt,
             const u16* __restrict__ Kg, const u16* __restrict__ Vg,
             const short* __restrict__ cidx, u16* __restrict__ attn){
  __shared__ __align__(16) u16 Ks[2][64 * 128];
  __shared__ __align__(16) u16 Vs[2][128 * 64];
  __shared__ __align__(16) u16 Ps[8][16 * 64];
  __shared__ short cids[256];
  __shared__ int lists[12];
  __shared__ int nact_s;
  const int tid = threadIdx.x;
  const int w = tid >> 6, lane = tid & 63;
  const int g = lane >> 4, c15 = lane & 15;
  const int qb = blockIdx.x, h = blockIdx.y;
  const int i0 = qb * 128;
  const int wq = w >> 2, w4 = w & 3;
  const int rowbase = i0 + wq * 64 + w4 * 16;
  const u16* Qh = Q + h * HDIM;
  const u16* Kh = K + h * HDIM;
  const u16* Kgh = Kg + (size_t)h * 256 * 128;
  const u16* Vth = Vt + (size_t)h * 128 * 2048;
  const u16* Vgh = Vg + (size_t)h * 128 * 256;
  const float scale = 0.08838834764831845f;

  if (tid < 256) cids[tid] = cidx[h * 256 + tid];
  // Q fragments in registers (rows rowbase + c15)
  bf16x8 qfr[4];
#pragma unroll
  for (int ks = 0; ks < 4; ks++)
    qfr[ks] = *(const bf16x8*)(Qh + (size_t)(rowbase + c15) * 2048 + ks * 32 + g * 8);
  __syncthreads();
  if (tid == 0){
    int n = 0;
    int ktb0 = (i0 > RECENT) ? ((i0 - RECENT) >> 6) : 0;
    int ktmax = (i0 + 127) >> 6;
    for (int kt = ktb0; kt <= ktmax; ++kt) lists[n++] = kt;
    for (int gt = 0; gt < 4; ++gt)
      if ((int)cids[gt * 64] <= i0 + 127 - RECENT - 1) lists[n++] = 100 + gt;
    nact_s = n;
  }
  __syncthreads();
  const int nact = nact_s;

  // prologue: stage K0 (2) + V0 (2) only
  { int e = lists[0];
    if (e < 100){ stageK512(Kh, 2048, e * 64, Ks[0], tid);
                  stageV512(Vth, 2048, e * 64, Vs[0], tid); }
    else        { stageK512(Kgh, 128, (e - 100) * 64, Ks[0], tid);
                  stageV512(Vgh, 256, (e - 100) * 64, Vs[0], tid); } }

  f32x4 oacc[8];
#pragma unroll
  for (int f = 0; f < 8; f++) oacc[f] = (f32x4){0.f, 0.f, 0.f, 0.f};
  float lsum[4] = {0.f, 0.f, 0.f, 0.f};

  int cur = 0;
  for (int i = 0; i < nact; ++i){
    const int e = lists[i];
    const bool isg = (e >= 100);
    const bool nxt = (i + 1 < nact);
    WAITVM(2);                 // retire K(i); keep V(i)
    BARRAW;
    if (nxt){                  // stage K/V(i+1) AFTER barrier (no race vs iter i-1 reads)
      int e2 = lists[i + 1];
      if (e2 < 100){ stageK512(Kh, 2048, e2 * 64, Ks[cur ^ 1], tid);
                     stageV512(Vth, 2048, e2 * 64, Vs[cur ^ 1], tid); }
      else         { stageK512(Kgh, 128, (e2 - 100) * 64, Ks[cur ^ 1], tid);
                     stageV512(Vgh, 256, (e2 - 100) * 64, Vs[cur ^ 1], tid); }
    }
    // QK^T
    f32x4 sacc[4];
#pragma unroll
    for (int n = 0; n < 4; n++) sacc[n] = (f32x4){0.f, 0.f, 0.f, 0.f};
#pragma unroll
    for (int ks = 0; ks < 4; ++ks){
#pragma unroll
      for (int n = 0; n < 4; n++){
        int brw = n * 16 + c15;
        bf16x8 b = *(const bf16x8*)(Ks[cur] + brw * 128 + ((ks * 32 + g * 8) ^ ((brw & 7) << 3)));
        sacc[n] = __builtin_amdgcn_mfma_f32_16x16x32_bf16(qfr[ks], b, sacc[n], 0, 0, 0);
      }
    }
    // masked exp -> P (LDS, wave-private), row sums
#pragma unroll
    for (int n = 0; n < 4; n++){
      int cid = isg ? (int)cids[(e - 100) * 64 + n * 16 + c15] : (e * 64 + n * 16 + c15);
#pragma unroll
      for (int r = 0; r < 4; r++){
        int rowg = rowbase + g * 4 + r;
        int dist = rowg - cid;
        bool valid = (cid <= rowg) && (isg ? (dist > RECENT) : (dist <= RECENT));
        float ev = valid ? __expf(sacc[n][r] * scale) : 0.f;
        lsum[r] += ev;
        int prow = g * 4 + r;
        Ps[w][prow * 64 + ((n * 16 + c15) ^ ((prow & 7) << 3))] = f2bf(ev);
      }
    }
    // retire V(i) (keep K/V(i+1)), then PV from LDS
    if (nxt) WAITVM(4); else WAITVM(0);
    BARRAW;
    PRIO1;
#pragma unroll
    for (int ks2 = 0; ks2 < 2; ++ks2){
      bf16x8 pa = *(const bf16x8*)(&Ps[w][c15 * 64 + ((ks2 * 32 + g * 8) ^ ((c15 & 7) << 3))]);
#pragma unroll
      for (int f = 0; f < 8; ++f){
        int vrow = f * 16 + c15;
        bf16x8 vb = *(const bf16x8*)(Vs[cur] + vrow * 64 + ((ks2 * 32 + g * 8) ^ ((vrow & 7) << 3)));
        oacc[f] = __builtin_amdgcn_mfma_f32_16x16x32_bf16(pa, vb, oacc[f], 0, 0, 0);
      }
    }
    PRIO0;
    cur ^= 1;
  }
  float rinv[4];
#pragma unroll
  for (int r = 0; r < 4; r++){
    float v = lsum[r];
    v += __shfl_xor(v, 1); v += __shfl_xor(v, 2);
    v += __shfl_xor(v, 4); v += __shfl_xor(v, 8);
    rinv[r] = 1.0f / v;
  }
#pragma unroll
  for (int f = 0; f < 8; f++)
#pragma unroll
    for (int r = 0; r < 4; r++){
      int rowg = rowbase + g * 4 + r;
      attn[(size_t)rowg * 2048 + h * HDIM + f * 16 + c15] = f2bf(oacc[f][r] * rinv[r]);
    }
}

// ---------------- host launcher ----------------
extern "C" void kernel_launch(void* const* d_in, const int* in_sizes, int n_in,
                              void* d_out, int out_size, void* d_ws, size_t ws_size,
                              hipStream_t stream){
  const float* X  = (const float*)d_in[0];
  const float* Wq = (const float*)d_in[1];
  const float* Wk = (const float*)d_in[2];
  const float* Wv = (const float*)d_in[3];
  const float* Wo = (const float*)d_in[4];

  char* w = (char*)d_ws;
  const size_t MB8 = (size_t)2048 * 2048 * 2;   // one bf16 matrix = 8 MiB
  u16* Xb  = (u16*)(w);
  u16* Wqb = (u16*)(w + 1 * MB8);
  u16* Wkb = (u16*)(w + 2 * MB8);
  u16* Wvb = (u16*)(w + 3 * MB8);
  u16* Wob = (u16*)(w + 4 * MB8);
  u16* Qb  = (u16*)(w + 5 * MB8);
  u16* Kb  = (u16*)(w + 6 * MB8);
  u16* Vb  = (u16*)(w + 7 * MB8);
  u16* Vtb   = Wqb;   // Wq dead after projections
  u16* attnb = Xb;    // X dead after projections
  char* p = w + 8 * MB8;
  float* cosT = (float*)p;              p += 524288;
  float* sinT = (float*)p;              p += 524288;
  float* colsum = (float*)p;            p += 131072;   // zeroed in k_prep (with rowsum)
  float* rowsum = (float*)p;            p += 131072;
  short* cidx  = (short*)p;             p += 16 * 256 * 2;
  u16*   Kg    = (u16*)p;               p += (size_t)16 * 256 * 128 * 2;
  u16*   Vg    = (u16*)p;

  dim3 b256(256);

  k_prep<<<21056, b256, 0, stream>>>(X, Wq, Wk, Wv, Wo, Xb, cosT, sinT, colsum);

  k_g256<<<dim3(32, 16), dim3(512), 0, stream>>>(Xb, Wqb, Wkb, Wvb, Qb, Kb, Vb);
  k_post<<<8192, b256, 0, stream>>>(Qb, Kb, cosT, sinT, Vb, Vtb);

  k_pass1a<<<dim3(40, 16), b256, 0, stream>>>(Qb, Kb, rowsum);
  k_pass1b<<<dim3(40, 16), b256, 0, stream>>>(Qb, Kb, rowsum, colsum);
  k_topk<<<16, dim3(1024), 0, stream>>>(colsum, cidx);
  k_gath<<<384, b256, 0, stream>>>(Kb, Vb, cidx, Kg, Vg);
  k_pass2<<<dim3(16, 16), dim3(512), 0, stream>>>(Qb, Kb, Vtb, Kg, Vg, cidx, attnb);

  k_gemm_out<<<dim3(16, 16), dim3(512), 0, stream>>>(attnb, Wob, (float*)d_out);
}

// Round 14
// 238.903 us; speedup vs baseline: 1.0565x; 1.0542x over previous
//
#include <hip/hip_runtime.h>
#include <hip/hip_bf16.h>
#include <stdint.h>

// Problem constants: b=1, s=2048, hidden=2048, H=16, d=128
#define SEQ   2048
#define HIDN  2048
#define NHEAD 16
#define HDIM  128
#define HEAVY 204   // int(0.1*2048)
#define RECENT 204

typedef __attribute__((ext_vector_type(4))) float f32x4;
typedef __attribute__((ext_vector_type(8))) short bf16x8;
typedef unsigned short u16;
typedef unsigned int   u32;

static __device__ __forceinline__ u16 f2bf(float f){
  union { float f; u32 u; } v; v.f = f;
  u32 r = (v.u + 0x7FFFu + ((v.u >> 16) & 1u)) >> 16;
  return (u16)r;
}
static __device__ __forceinline__ float bf2f(u16 u){
  union { u32 u; float f; } v; v.u = ((u32)u) << 16;
  return v.f;
}

// global -> LDS direct 16B load (dest is wave-uniform base + lane*16)
static __device__ __forceinline__ void gload16(const void* g, void* l){
  __builtin_amdgcn_global_load_lds((const __attribute__((address_space(1))) u32*)g,
                                   (__attribute__((address_space(3))) u32*)l, 16, 0, 0);
}

#define WAITVM(N) asm volatile("s_waitcnt vmcnt(" #N ")" ::: "memory")
#define BARRAW    __builtin_amdgcn_s_barrier()
#define PRIO1     __builtin_amdgcn_s_setprio(1)
#define PRIO0     __builtin_amdgcn_s_setprio(0)

// stage a 64x128 bf16 tile with 256 threads, runtime row stride (XOR-swizzled source)
static __device__ __forceinline__ void stage_tile(const u16* __restrict__ base, size_t stride,
                                                  int row0, u16* __restrict__ lds, int tid){
  const int wbase = tid & ~63;
#pragma unroll
  for (int it = 0; it < 4; ++it){
    int m = it * 256 + tid;
    int row = m >> 4, cp = m & 15;
    gload16(base + (size_t)(row0 + row) * stride + ((cp ^ (row & 7)) * 8),
            lds + (it * 256 + wbase) * 8);
  }
}

// stage 64x128 tile with 512 threads, runtime stride
static __device__ __forceinline__ void stageK512(const u16* __restrict__ base, size_t stride,
                                                 int row0, u16* __restrict__ lds, int tid){
#pragma unroll
  for (int it = 0; it < 2; ++it){
    int m = it * 512 + tid;
    int row = m >> 4, cp = m & 15;
    gload16(base + (size_t)(row0 + row) * stride + ((cp ^ (row & 7)) * 8),
            lds + (it * 512 + (tid & ~63)) * 8);
  }
}
// stage 128-row x 64-col tile (col offset c0) with 512 threads, runtime stride
static __device__ __forceinline__ void stageV512(const u16* __restrict__ base, size_t stride,
                                                 int c0, u16* __restrict__ lds, int tid){
#pragma unroll
  for (int it = 0; it < 2; ++it){
    int m = it * 512 + tid;
    int row = m >> 3, cp = m & 7;
    gload16(base + (size_t)row * stride + c0 + ((cp ^ (row & 7)) * 8),
            lds + (it * 512 + (tid & ~63)) * 8);
  }
}

// ---------------- prep: cvt5 + rope tables + zero colsum/rowsum (fused) ----------------
__global__ void k_prep(const float* __restrict__ A0, const float* __restrict__ A1,
                       const float* __restrict__ A2, const float* __restrict__ A3,
                       const float* __restrict__ A4, u16* __restrict__ out,
                       float* __restrict__ cosT, float* __restrict__ sinT,
                       float* __restrict__ colsum){
  int b = blockIdx.x, tid = threadIdx.x;
  if (b < 20480){
    int id = b * 256 + tid;
    int sel = id >> 20, off = (id & 1048575) * 4;
    const float* src = sel == 0 ? A0 : sel == 1 ? A1 : sel == 2 ? A2 : sel == 3 ? A3 : A4;
    float4 v = *(const float4*)(src + off);
    ushort4 o;
    o.x = f2bf(v.x); o.y = f2bf(v.y); o.z = f2bf(v.z); o.w = f2bf(v.w);
    *(ushort4*)(out + (size_t)sel * 4194304 + off) = o;
  } else if (b < 20992){
    int i = (b - 20480) * 256 + tid;           // 2048*64
    int pos = i >> 6, j = i & 63;
    float invf = powf(10000.0f, -(float)j * (1.0f / 64.0f));
    float a = (float)pos * invf;
    cosT[i] = cosf(a);
    sinT[i] = sinf(a);
  } else {
    int i = (b - 20992) * 256 + tid;           // 16384 float4 = colsum+rowsum (contiguous)
    if (i < 16384) ((float4*)colsum)[i] = (float4){0.f, 0.f, 0.f, 0.f};
  }
}

// ---------------- post: rope on Q,K + transpose V (fused) ----------------
__global__ void k_post(u16* __restrict__ Qm, u16* __restrict__ Km,
                       const float* __restrict__ cosT, const float* __restrict__ sinT,
                       const u16* __restrict__ V, u16* __restrict__ Vt){
  __shared__ u16 t[32][33];
  int b = blockIdx.x, tid = threadIdx.x;
  if (b < 4096){
    int gid = b * 256 + tid;                   // 2 * 524288
    u16* M = (gid < 524288) ? Qm : Km;
    int id = gid & 524287;
    int pos = id >> 8, rem = id & 255;
    int h = rem >> 4, j4 = (rem & 15) * 4;
    u16* p = M + (size_t)pos * HIDN + h * HDIM + j4;
    ushort4 lo = *(ushort4*)p;
    ushort4 hi = *(ushort4*)(p + 64);
    float4 c = *(const float4*)(cosT + pos * 64 + j4);
    float4 s = *(const float4*)(sinT + pos * 64 + j4);
    float l0 = bf2f(lo.x), l1 = bf2f(lo.y), l2 = bf2f(lo.z), l3 = bf2f(lo.w);
    float h0 = bf2f(hi.x), h1 = bf2f(hi.y), h2 = bf2f(hi.z), h3 = bf2f(hi.w);
    ushort4 nlo, nhi;
    nlo.x = f2bf(l0 * c.x - h0 * s.x);  nhi.x = f2bf(h0 * c.x + l0 * s.x);
    nlo.y = f2bf(l1 * c.y - h1 * s.y);  nhi.y = f2bf(h1 * c.y + l1 * s.y);
    nlo.z = f2bf(l2 * c.z - h2 * s.z);  nhi.z = f2bf(h2 * c.z + l2 * s.z);
    nlo.w = f2bf(l3 * c.w - h3 * s.w);  nhi.w = f2bf(h3 * c.w + l3 * s.w);
    *(ushort4*)p = nlo;
    *(ushort4*)(p + 64) = nhi;
  } else {
    int b2 = b - 4096;
    int s0 = (b2 & 63) * 32, c0 = (b2 >> 6) * 32;
    int r = tid >> 3, cc = (tid & 7) * 4;
    ushort4 v = *(const ushort4*)(V + (size_t)(s0 + r) * 2048 + c0 + cc);
    t[r][cc] = v.x; t[r][cc + 1] = v.y; t[r][cc + 2] = v.z; t[r][cc + 3] = v.w;
    __syncthreads();
    int co = tid >> 3, ro = (tid & 7) * 4;
    ushort4 o;
    o.x = t[ro][co]; o.y = t[ro + 1][co]; o.z = t[ro + 2][co]; o.w = t[ro + 3][co];
    *(ushort4*)(Vt + (size_t)(c0 + co) * 2048 + s0 + ro) = o;
  }
}

// ---------------- fused projection GEMM: C[2048][6144] = X @ [Wq;Wk;Wv]^T ----------------
// 256x192 tile, BK=64, 8 waves, 2 barriers/tile (reads+MFMA overlap via compiler lgkmcnt),
// counted vmcnt. grid (32,8) = 256 blocks, full fill. [R11 proven: 53 us, MfmaUtil 40%]
__global__ __launch_bounds__(512, 1)
void k_g256(const u16* __restrict__ X, const u16* __restrict__ Wq, const u16* __restrict__ Wk,
            const u16* __restrict__ Wv, u16* __restrict__ C0, u16* __restrict__ C1,
            u16* __restrict__ C2){
  __shared__ __align__(16) u16 LA[2][256 * 64];
  __shared__ __align__(16) u16 LB[2][192 * 64];
  const int tid = threadIdx.x;
  const int lane = tid & 63, wvi = tid >> 6;
  const int wm = wvi >> 2, wn = wvi & 3;
  const int g = lane >> 4, c15 = lane & 15;
  const int brow = blockIdx.y * 256;       // [0,2048)
  const int bcol = blockIdx.x * 192;       // [0,6144)
  const int NT = 32;

  f32x4 acc[8][3];
#pragma unroll
  for (int m = 0; m < 8; m++)
#pragma unroll
    for (int n = 0; n < 3; n++) acc[m][n] = (f32x4){0.f, 0.f, 0.f, 0.f};

  const int cc0 = ((g ^ (c15 & 7)) * 8);
  bf16x8 af[4][2], af2[4][2], bf[3][2];

#define BPTR(rB_) (rB_ < 2048 ? Wq + (size_t)(rB_) * 2048 \
                 : rB_ < 4096 ? Wk + (size_t)((rB_) - 2048) * 2048 \
                              : Wv + (size_t)((rB_) - 4096) * 2048)
#define STGA(grow0, gcol0, ldsb) do { \
  _Pragma("unroll") for (int it = 0; it < 2; ++it){ \
    int m_ = it * 512 + tid; \
    int row_ = m_ >> 3, cp_ = m_ & 7; \
    gload16(X + (size_t)((grow0) + row_) * 2048 + (gcol0) + ((cp_ ^ (row_ & 7)) * 8), \
            (ldsb) + (it * 512 + (tid & ~63)) * 8); \
  } } while(0)
#define STGB128(gcol0, ldsb) do { \
  _Pragma("unroll") for (int it = 0; it < 2; ++it){ \
    int m_ = it * 512 + tid; \
    int row_ = m_ >> 3, cp_ = m_ & 7; \
    int rB_ = bcol + row_; \
    const u16* bp_ = BPTR(rB_); \
    gload16(bp_ + (gcol0) + ((cp_ ^ (row_ & 7)) * 8), \
            (ldsb) + (it * 512 + (tid & ~63)) * 8); \
  } } while(0)
#define STGB64(gcol0, ldsb) do { \
    int row_ = 128 + (tid >> 3), cp_ = tid & 7; \
    int rB_ = bcol + row_; \
    const u16* bp_ = BPTR(rB_); \
    gload16(bp_ + (gcol0) + ((cp_ ^ (row_ & 7)) * 8), \
            (ldsb) + (tid & ~63) * 8); \
  } while(0)
#define RDA(buf) \
  _Pragma("unroll") for (int mi2 = 0; mi2 < 4; ++mi2){ \
    const u16* pr = &LA[buf][0] + (size_t)(wm * 128 + mi2 * 16 + c15) * 64; \
    af[mi2][0] = *(const bf16x8*)(pr + cc0); \
    af[mi2][1] = *(const bf16x8*)(pr + (cc0 ^ 32)); \
  }
#define RDA2(buf) \
  _Pragma("unroll") for (int mi2 = 0; mi2 < 4; ++mi2){ \
    const u16* pr = &LA[buf][0] + (size_t)(wm * 128 + (4 + mi2) * 16 + c15) * 64; \
    af2[mi2][0] = *(const bf16x8*)(pr + cc0); \
    af2[mi2][1] = *(const bf16x8*)(pr + (cc0 ^ 32)); \
  }
#define RDB2(buf) \
  _Pragma("unroll") for (int ni2 = 0; ni2 < 2; ++ni2){ \
    const u16* pr = &LB[buf][0] + (size_t)(wn * 48 + ni2 * 16 + c15) * 64; \
    bf[ni2][0] = *(const bf16x8*)(pr + cc0); \
    bf[ni2][1] = *(const bf16x8*)(pr + (cc0 ^ 32)); \
  }
#define RDB1(buf) do { \
    const u16* pr = &LB[buf][0] + (size_t)(wn * 48 + 32 + c15) * 64; \
    bf[2][0] = *(const bf16x8*)(pr + cc0); \
    bf[2][1] = *(const bf16x8*)(pr + (cc0 ^ 32)); \
  } while(0)
// MFMA clusters
#define MM2A \
  _Pragma("unroll") for (int mi2 = 0; mi2 < 4; ++mi2) \
  _Pragma("unroll") for (int ni2 = 0; ni2 < 2; ++ni2) \
  _Pragma("unroll") for (int kk = 0; kk < 2; ++kk) \
    acc[mi2][ni2] = __builtin_amdgcn_mfma_f32_16x16x32_bf16( \
        af[mi2][kk], bf[ni2][kk], acc[mi2][ni2], 0, 0, 0);
#define MM1AB \
  _Pragma("unroll") for (int mi2 = 0; mi2 < 4; ++mi2) \
  _Pragma("unroll") for (int kk = 0; kk < 2; ++kk){ \
    acc[mi2][2] = __builtin_amdgcn_mfma_f32_16x16x32_bf16( \
        af[mi2][kk], bf[2][kk], acc[mi2][2], 0, 0, 0); \
    acc[4 + mi2][2] = __builtin_amdgcn_mfma_f32_16x16x32_bf16( \
        af2[mi2][kk], bf[2][kk], acc[4 + mi2][2], 0, 0, 0); \
  }
#define MM2B \
  _Pragma("unroll") for (int mi2 = 0; mi2 < 4; ++mi2) \
  _Pragma("unroll") for (int ni2 = 0; ni2 < 2; ++ni2) \
  _Pragma("unroll") for (int kk = 0; kk < 2; ++kk) \
    acc[4 + mi2][ni2] = __builtin_amdgcn_mfma_f32_16x16x32_bf16( \
        af2[mi2][kk], bf[ni2][kk], acc[4 + mi2][ni2], 0, 0, 0);

// one tile = 2 barriers. Reads+STGA up front; barrier #1 after the 32-MFMA block
// (all LDS reads consumed => serviced); STGB into freed LB[buf] overlaps reg-only MM2B;
// WAITVM(3) retires STGA(t+1), keeps STGB(t+2) in flight across barrier #2.
#define TILE(t, buf) do { \
    const int kn1 = ((t) + 1) * 64; \
    const int kn2 = ((t) + 2) * 64; \
    RDA(buf); RDB2(buf); RDA2(buf); RDB1(buf); \
    if ((t) + 1 < NT){ STGA(brow, kn1, &LA[buf ^ 1][0]); \
                       STGA(brow + 128, kn1, &LA[buf ^ 1][0] + 128 * 64); } \
    PRIO1; MM2A; MM1AB; PRIO0; \
    BARRAW; \
    if ((t) + 2 < NT){ STGB128(kn2, &LB[buf][0]); STGB64(kn2, &LB[buf][0] + 128 * 64); } \
    PRIO1; MM2B; PRIO0; \
    if ((t) + 2 < NT){ WAITVM(3); } \
    else if ((t) + 1 < NT){ WAITVM(0); } \
    BARRAW; \
  } while(0)

  // prologue: A(0) 4 loads, B(0) 3, B(1) 3; WAITVM(3) retires A0,B0, keeps B1
  STGA(brow,       0, &LA[0][0]);
  STGA(brow + 128, 0, &LA[0][0] + 128 * 64);
  STGB128(0,  &LB[0][0]);
  STGB64(0,   &LB[0][0] + 128 * 64);
  STGB128(64, &LB[1][0]);
  STGB64(64,  &LB[1][0] + 128 * 64);
  WAITVM(3);
  BARRAW;

  for (int t = 0; t < NT; t += 2){
    TILE(t, 0);
    TILE(t + 1, 1);
  }
#undef TILE
#undef BPTR
#undef STGA
#undef STGB128
#undef STGB64
#undef RDA
#undef RDA2
#undef RDB2
#undef RDB1
#undef MM2A
#undef MM1AB
#undef MM2B

#pragma unroll
  for (int mi = 0; mi < 8; ++mi)
#pragma unroll
    for (int ni = 0; ni < 3; ++ni){
      int colbase = bcol + wn * 48 + ni * 16;      // 2048-boundary is 16-aligned
      int proj = colbase >> 11;
      u16* Cb = proj == 0 ? C0 : proj == 1 ? C1 : C2;
      int lc = (colbase & 2047) + c15;
#pragma unroll
      for (int r = 0; r < 4; ++r){
        int row = brow + wm * 128 + mi * 16 + g * 4 + r;
        Cb[(size_t)row * 2048 + lc] = f2bf(acc[mi][ni][r]);
      }
    }
}

// ---------------- output GEMM: 128x128 tile, BK=64, 8 waves, counted vmcnt ----------------
// grid (16,16) = 256 blocks, 512 thr = 2 waves/SIMD
__global__ __launch_bounds__(512)
void k_gemm_out(const u16* __restrict__ A, const u16* __restrict__ B, float* __restrict__ C){
  __shared__ __align__(16) u16 As[2][128 * 64];
  __shared__ __align__(16) u16 Bs[2][128 * 64];
  const int tid = threadIdx.x;
  const int w = tid >> 6, lane = tid & 63;
  const int wm = w >> 1, wn = w & 1;
  const int g = lane >> 4, c15 = lane & 15;
  const int brow = blockIdx.y * 128, bcol = blockIdx.x * 128;
  const int cc0 = ((g ^ (c15 & 7)) * 8);

  f32x4 acc[2][4];
#pragma unroll
  for (int m = 0; m < 2; m++)
#pragma unroll
    for (int n = 0; n < 4; n++) acc[m][n] = (f32x4){0.f, 0.f, 0.f, 0.f};

#define STG_O(k0, buf) do { \
  _Pragma("unroll") for (int it = 0; it < 2; ++it){ \
    int m_ = it * 512 + tid; \
    int row_ = m_ >> 3, cp_ = m_ & 7; \
    gload16(A + (size_t)(brow + row_) * 2048 + (k0) + ((cp_ ^ (row_ & 7)) * 8), \
            As[buf] + (it * 512 + (tid & ~63)) * 8); \
    gload16(B + (size_t)(bcol + row_) * 2048 + (k0) + ((cp_ ^ (row_ & 7)) * 8), \
            Bs[buf] + (it * 512 + (tid & ~63)) * 8); \
  } } while(0)

  STG_O(0, 0);
  int cur = 0;
  for (int kt = 0; kt < 32; ++kt){
    if (kt + 1 < 32){ STG_O((kt + 1) * 64, cur ^ 1); WAITVM(4); }
    else            { WAITVM(0); }
    BARRAW;
    bf16x8 af[2][2], bfr[4][2];
#pragma unroll
    for (int mi = 0; mi < 2; ++mi){
      const u16* pr = As[cur] + (size_t)(wm * 32 + mi * 16 + c15) * 64;
      af[mi][0] = *(const bf16x8*)(pr + cc0);
      af[mi][1] = *(const bf16x8*)(pr + (cc0 ^ 32));
    }
#pragma unroll
    for (int ni = 0; ni < 4; ++ni){
      const u16* pr = Bs[cur] + (size_t)(wn * 64 + ni * 16 + c15) * 64;
      bfr[ni][0] = *(const bf16x8*)(pr + cc0);
      bfr[ni][1] = *(const bf16x8*)(pr + (cc0 ^ 32));
    }
    PRIO1;
#pragma unroll
    for (int mi = 0; mi < 2; ++mi)
#pragma unroll
      for (int ni = 0; ni < 4; ++ni)
#pragma unroll
        for (int kk = 0; kk < 2; ++kk)
          acc[mi][ni] = __builtin_amdgcn_mfma_f32_16x16x32_bf16(af[mi][kk], bfr[ni][kk],
                                                                acc[mi][ni], 0, 0, 0);
    PRIO0;
    BARRAW;
    cur ^= 1;
  }
#undef STG_O
#pragma unroll
  for (int mi = 0; mi < 2; ++mi)
#pragma unroll
    for (int ni = 0; ni < 4; ++ni)
#pragma unroll
      for (int r = 0; r < 4; ++r){
        int row = brow + wm * 32 + mi * 16 + g * 4 + r;
        int col = bcol + wn * 64 + ni * 16 + c15;
        C[(size_t)row * 2048 + col] = acc[mi][ni][r];
      }
}

// ---------------- pass 1a: rowsum of exp (causal), Q-in-registers ----------------
// grid (40, 16), 256 thr; K triple-buffered LDS stream, 1 barrier/iter.
__global__ __launch_bounds__(256)
void k_pass1a(const u16* __restrict__ Q, const u16* __restrict__ K, float* __restrict__ rowsum){
  __shared__ __align__(16) u16 Ks[3][64 * 128];
  const int tid = threadIdx.x;
  const int wv = tid >> 6, lane = tid & 63;
  const int g = lane >> 4, c15 = lane & 15;
  const int h = blockIdx.y;
  int qb = 0, c = 0;
  { int rem = blockIdx.x; int q = 0;
    while (rem >= ((2 * q + 9) >> 3)){ rem -= (2 * q + 9) >> 3; q++; }
    qb = q; c = rem; }
  const int i0 = qb * 128;
  const int ktend = 2 * qb + 2;
  const int kt0 = c * 8;
  const int kt1 = (ktend < kt0 + 8) ? ktend : (kt0 + 8);
  const u16* Qh = Q + h * HDIM;
  const u16* Kh = K + h * HDIM;
  const float scale = 0.08838834764831845f;   // 1/sqrt(128)
  const int wb = wv * 32;

  bf16x8 qfr[2][4];
#pragma unroll
  for (int m = 0; m < 2; m++)
#pragma unroll
    for (int ks = 0; ks < 4; ks++)
      qfr[m][ks] = *(const bf16x8*)(Qh + (size_t)(i0 + wb + m * 16 + c15) * 2048 + ks * 32 + g * 8);

  stage_tile(Kh, 2048, kt0 * 64, Ks[0], tid);
  if (kt0 + 1 < kt1) stage_tile(Kh, 2048, (kt0 + 1) * 64, Ks[1], tid);

  float rs[2][4] = {{0.f,0.f,0.f,0.f},{0.f,0.f,0.f,0.f}};
  for (int kt = kt0; kt < kt1; ++kt){
    const int bi = (kt - kt0) % 3;
    if (kt + 1 < kt1){ WAITVM(4); } else { WAITVM(0); }
    BARRAW;
    if (kt + 2 < kt1) stage_tile(Kh, 2048, (kt + 2) * 64, Ks[(kt - kt0 + 2) % 3], tid);
    const int k0 = kt * 64;
    f32x4 sacc[2][4];
#pragma unroll
    for (int m = 0; m < 2; m++)
#pragma unroll
      for (int n = 0; n < 4; n++) sacc[m][n] = (f32x4){0.f, 0.f, 0.f, 0.f};
#pragma unroll
    for (int ks = 0; ks < 4; ++ks){
#pragma unroll
      for (int n = 0; n < 4; n++){
        int brw = n * 16 + c15;
        bf16x8 b = *(const bf16x8*)(Ks[bi] + brw * 128 + ((ks * 32 + g * 8) ^ ((brw & 7) << 3)));
#pragma unroll
        for (int m = 0; m < 2; m++)
          sacc[m][n] = __builtin_amdgcn_mfma_f32_16x16x32_bf16(qfr[m][ks], b, sacc[m][n], 0, 0, 0);
      }
    }
    if (kt < 2 * qb){            // fully causal tile: no mask compare
#pragma unroll
      for (int m = 0; m < 2; m++)
#pragma unroll
        for (int n = 0; n < 4; n++)
#pragma unroll
          for (int r = 0; r < 4; r++)
            rs[m][r] += __expf(sacc[m][n][r] * scale);
    } else {
#pragma unroll
      for (int n = 0; n < 4; n++){
        int col = k0 + n * 16 + c15;
#pragma unroll
        for (int m = 0; m < 2; m++)
#pragma unroll
          for (int r = 0; r < 4; r++){
            int rowg = i0 + wb + m * 16 + g * 4 + r;
            rs[m][r] += (col <= rowg) ? __expf(sacc[m][n][r] * scale) : 0.f;
          }
      }
    }
  }
#pragma unroll
  for (int m = 0; m < 2; m++)
#pragma unroll
    for (int r = 0; r < 4; r++){
      float v = rs[m][r];
      v += __shfl_xor(v, 1); v += __shfl_xor(v, 2);
      v += __shfl_xor(v, 4); v += __shfl_xor(v, 8);
      if (c15 == 0)
        atomicAdd(&rowsum[h * 2048 + i0 + wb + m * 16 + g * 4 + r], v);
    }
}

// ---------------- pass 1b: colsum of normalized exp, K-in-registers ----------------
// grid (40, 16), 256 thr; Q triple-buffered LDS stream, 1 barrier/iter.
__global__ __launch_bounds__(256)
void k_pass1b(const u16* __restrict__ Q, const u16* __restrict__ K,
              const float* __restrict__ rowsum, float* __restrict__ colsum){
  __shared__ __align__(16) u16 Qs[3][64 * 128];
  const int tid = threadIdx.x;
  const int wv = tid >> 6, lane = tid & 63;
  const int g = lane >> 4, c15 = lane & 15;
  const int h = blockIdx.y;
  int kb = 0, c = 0;
  { int rem = blockIdx.x; int q = 0;
    while (rem >= ((39 - 2 * q) >> 3)){ rem -= (39 - 2 * q) >> 3; q++; }
    kb = q; c = rem; }
  const int k0 = kb * 128;
  const int qt0 = 2 * kb + c * 8;
  const int qt1 = (2 * kb + c * 8 + 8 < 32) ? (2 * kb + c * 8 + 8) : 32;
  const u16* Qh = Q + h * HDIM;
  const u16* Kh = K + h * HDIM;
  const float scale = 0.08838834764831845f;
  const int wb = wv * 32;
  const float* rsrow = rowsum + h * 2048;

  bf16x8 kfr[2][4];
#pragma unroll
  for (int m = 0; m < 2; m++)
#pragma unroll
    for (int ks = 0; ks < 4; ks++)
      kfr[m][ks] = *(const bf16x8*)(Kh + (size_t)(k0 + wb + m * 16 + c15) * 2048 + ks * 32 + g * 8);

  stage_tile(Qh, 2048, qt0 * 64, Qs[0], tid);
  if (qt0 + 1 < qt1) stage_tile(Qh, 2048, (qt0 + 1) * 64, Qs[1], tid);

  float racc[2][4] = {{0.f,0.f,0.f,0.f},{0.f,0.f,0.f,0.f}};
  for (int qt = qt0; qt < qt1; ++qt){
    const int bi = (qt - qt0) % 3;
    if (qt + 1 < qt1){ WAITVM(4); } else { WAITVM(0); }
    BARRAW;
    if (qt + 2 < qt1) stage_tile(Qh, 2048, (qt + 2) * 64, Qs[(qt - qt0 + 2) % 3], tid);
    const int i0q = qt * 64;
    float rw[4];
#pragma unroll
    for (int n = 0; n < 4; n++)
      rw[n] = 1.0f / rsrow[i0q + n * 16 + c15];
    f32x4 sacc[2][4];
#pragma unroll
    for (int m = 0; m < 2; m++)
#pragma unroll
      for (int n = 0; n < 4; n++) sacc[m][n] = (f32x4){0.f, 0.f, 0.f, 0.f};
#pragma unroll
    for (int ks = 0; ks < 4; ++ks){
#pragma unroll
      for (int n = 0; n < 4; n++){
        int brw = n * 16 + c15;
        bf16x8 b = *(const bf16x8*)(Qs[bi] + brw * 128 + ((ks * 32 + g * 8) ^ ((brw & 7) << 3)));
#pragma unroll
        for (int m = 0; m < 2; m++)
          sacc[m][n] = __builtin_amdgcn_mfma_f32_16x16x32_bf16(kfr[m][ks], b, sacc[m][n], 0, 0, 0);
      }
    }
    if (qt >= 2 * kb + 2){       // fully causal: no mask compare
#pragma unroll
      for (int m = 0; m < 2; m++)
#pragma unroll
        for (int n = 0; n < 4; n++)
#pragma unroll
          for (int r = 0; r < 4; r++)
            racc[m][r] += __expf(sacc[m][n][r] * scale) * rw[n];
    } else {
#pragma unroll
      for (int n = 0; n < 4; n++){
        int colq = i0q + n * 16 + c15;
#pragma unroll
        for (int m = 0; m < 2; m++)
#pragma unroll
          for (int r = 0; r < 4; r++){
            int rowk = k0 + wb + m * 16 + g * 4 + r;
            racc[m][r] += (rowk <= colq) ? __expf(sacc[m][n][r] * scale) * rw[n] : 0.f;
          }
      }
    }
  }
#pragma unroll
  for (int m = 0; m < 2; m++)
#pragma unroll
    for (int r = 0; r < 4; r++){
      float v = racc[m][r];
      v += __shfl_xor(v, 1); v += __shfl_xor(v, 2);
      v += __shfl_xor(v, 4); v += __shfl_xor(v, 8);
      if (c15 == 0)
        atomicAdd(&colsum[h * 2048 + k0 + wb + m * 16 + g * 4 + r], v);
    }
}

// ---------------- top-k via exact radix-select (select only, 16 blocks) ----------------
__global__ __launch_bounds__(1024)
void k_topk(const float* __restrict__ colsum, short* __restrict__ cidx){
  __shared__ u32 keys[2048];
  __shared__ int hist[256];
  __shared__ int chunkCnt[32];
  __shared__ short cidL[256];
  __shared__ u32 Tacc_s;
  __shared__ int rem_s;
  const int tid = threadIdx.x;
  const int h = blockIdx.x;
  const int w = tid >> 6, lane = tid & 63;

  for (int i = tid; i < 2048; i += 1024) keys[i] = ((const u32*)colsum)[h * 2048 + i];
  if (tid == 0){ Tacc_s = 0; rem_s = HEAVY; }
  __syncthreads();

  for (int s = 24; s >= 0; s -= 8){
    if (tid < 256) hist[tid] = 0;
    __syncthreads();
    u32 T = Tacc_s;
    for (int i = tid; i < 2048; i += 1024){
      u32 k = keys[i];
      bool match = (s == 24) ? true : (((k ^ T) >> (s + 8)) == 0);
      if (match) atomicAdd(&hist[(k >> s) & 255], 1);
    }
    __syncthreads();
    if (tid == 0){
      int rem = rem_s, acc = 0, b = 255;
      for (; b > 0; --b){
        int c2 = hist[b];
        if (acc + c2 >= rem) break;
        acc += c2;
      }
      Tacc_s = T | ((u32)b << s);
      rem_s = rem - acc;
    }
    __syncthreads();
  }
  const u32 T = Tacc_s;
  const int need = rem_s;                 // smallest-index ties among == T
  const u32 kA = keys[tid], kB = keys[tid + 1024];
  const bool eqA = (kA == T), eqB = (kB == T);
  unsigned long long ebA = __ballot(eqA);
  unsigned long long ebB = __ballot(eqB);
  if (lane == 0){ chunkCnt[w] = __popcll(ebA); chunkCnt[16 + w] = __popcll(ebB); }
  __syncthreads();
  if (tid == 0){
    int s2 = 0;
    for (int i2 = 0; i2 < 32; ++i2){ int c2 = chunkCnt[i2]; chunkCnt[i2] = s2; s2 += c2; }
  }
  __syncthreads();
  const unsigned long long below = (1ull << lane) - 1ull;
  const int eqrA = chunkCnt[w] + __popcll(ebA & below);
  const int eqrB = chunkCnt[16 + w] + __popcll(ebB & below);
  const bool hvA = (kA > T) || (eqA && eqrA < need);
  const bool hvB = (kB > T) || (eqB && eqrB < need);
  __syncthreads();                        // before reusing chunkCnt
  unsigned long long hbA = __ballot(hvA);
  unsigned long long hbB = __ballot(hvB);
  if (lane == 0){ chunkCnt[w] = __popcll(hbA); chunkCnt[16 + w] = __popcll(hbB); }
  if (tid >= HEAVY && tid < 256) cidL[tid] = 32767;
  __syncthreads();
  if (tid == 0){
    int s2 = 0;
    for (int i2 = 0; i2 < 32; ++i2){ int c2 = chunkCnt[i2]; chunkCnt[i2] = s2; s2 += c2; }
  }
  __syncthreads();
  if (hvA) cidL[chunkCnt[w] + __popcll(hbA & below)] = (short)tid;
  if (hvB) cidL[chunkCnt[16 + w] + __popcll(hbB & below)] = (short)(tid + 1024);
  __syncthreads();
  if (tid < 256) cidx[h * 256 + tid] = cidL[tid];
}

// ---------------- gather heavy K rows + V cols (full-grid, 384 blocks) ----------------
__global__ void k_gath(const u16* __restrict__ Kb, const u16* __restrict__ Vb,
                       const short* __restrict__ cidx,
                       u16* __restrict__ Kg, u16* __restrict__ Vg){
  __shared__ __align__(16) u16 t[32][136];
  int b = blockIdx.x, tid = threadIdx.x;
  if (b < 256){
    int gid = b * 256 + tid;                   // 16h * 256slot * 16chunk = 65536
    int h = gid >> 12, rem = gid & 4095;
    int slot = rem >> 4, cp = rem & 15;
    int cid = cidx[h * 256 + slot];
    bf16x8 z = (bf16x8){0,0,0,0,0,0,0,0};
    bf16x8 val = (cid < 2048) ? *(const bf16x8*)(Kb + (size_t)cid * 2048 + h * 128 + cp * 8) : z;
    *(bf16x8*)(Kg + ((size_t)h * 256 + slot) * 128 + cp * 8) = val;
  } else {
    int b2 = b - 256;
    int h = b2 >> 3, s0 = (b2 & 7) * 32;
#pragma unroll
    for (int it = 0; it < 2; ++it){
      int m = it * 256 + tid;                  // 512 chunks = 32 slots x 16 chunks
      int s = m >> 4, cp = m & 15;
      int cid = cidx[h * 256 + s0 + s];
      bf16x8 z = (bf16x8){0,0,0,0,0,0,0,0};
      bf16x8 val = (cid < 2048) ? *(const bf16x8*)(Vb + (size_t)cid * 2048 + h * 128 + cp * 8) : z;
      *(bf16x8*)(&t[s][cp * 8]) = val;
    }
    __syncthreads();
#pragma unroll
    for (int i = 0; i < 16; ++i){
      int idx = i * 256 + tid;                 // 4096 = 128 d x 32 s
      int d = idx >> 5, s = idx & 31;
      Vg[((size_t)h * 128 + d) * 256 + s0 + s] = t[s][d];
    }
  }
}

// ---------------- pass 2: QBLK=128, Q-in-reg, K+V LDS dbuf, 2 barriers/iter ----------------
// grid (16, 16) = 256 blocks, 512 thr (8 waves: 2 q-halves x 4 strips)
__global__ __launch_bounds__(512)
void k_pass2(const u16* __restrict__ Q, const u16* __restrict__ K, const u16* __restrict__ Vt,
             const u16* __restrict__ Kg, const u16* __restrict__ Vg,
             const short* __restrict__ cidx, u16* __restrict__ attn){
  __shared__ __align__(16) u16 Ks[2][64 * 128];
  __shared__ __align__(16) u16 Vs[2][128 * 64];
  __shared__ __align__(16) u16 Ps[8][16 * 64];
  __shared__ short cids[256];
  __shared__ int lists[12];
  __shared__ int nact_s;
  const int tid = threadIdx.x;
  const int w = tid >> 6, lane = tid & 63;
  const int g = lane >> 4, c15 = lane & 15;
  const int qb = blockIdx.x, h = blockIdx.y;
  const int i0 = qb * 128;
  const int wq = w >> 2, w4 = w & 3;
  const int rowbase = i0 + wq * 64 + w4 * 16;
  const u16* Qh = Q + h * HDIM;
  const u16* Kh = K + h * HDIM;
  const u16* Kgh = Kg + (size_t)h * 256 * 128;
  const u16* Vth = Vt + (size_t)h * 128 * 2048;
  const u16* Vgh = Vg + (size_t)h * 128 * 256;
  const float scale = 0.08838834764831845f;

  if (tid < 256) cids[tid] = cidx[h * 256 + tid];
  // Q fragments in registers (rows rowbase + c15)
  bf16x8 qfr[4];
#pragma unroll
  for (int ks = 0; ks < 4; ks++)
    qfr[ks] = *(const bf16x8*)(Qh + (size_t)(rowbase + c15) * 2048 + ks * 32 + g * 8);
  __syncthreads();
  if (tid == 0){
    int n = 0;
    int ktb0 = (i0 > RECENT) ? ((i0 - RECENT) >> 6) : 0;
    int ktmax = (i0 + 127) >> 6;
    for (int kt = ktb0; kt <= ktmax; ++kt) lists[n++] = kt;
    for (int gt = 0; gt < 4; ++gt)
      if ((int)cids[gt * 64] <= i0 + 127 - RECENT - 1) lists[n++] = 100 + gt;
    nact_s = n;
  }
  __syncthreads();
  const int nact = nact_s;

  // prologue: stage K0 (2) + V0 (2) only
  { int e = lists[0];
    if (e < 100){ stageK512(Kh, 2048, e * 64, Ks[0], tid);
                  stageV512(Vth, 2048, e * 64, Vs[0], tid); }
    else        { stageK512(Kgh, 128, (e - 100) * 64, Ks[0], tid);
                  stageV512(Vgh, 256, (e - 100) * 64, Vs[0], tid); } }

  f32x4 oacc[8];
#pragma unroll
  for (int f = 0; f < 8; f++) oacc[f] = (f32x4){0.f, 0.f, 0.f, 0.f};
  float lsum[4] = {0.f, 0.f, 0.f, 0.f};

  int cur = 0;
  for (int i = 0; i < nact; ++i){
    const int e = lists[i];
    const bool isg = (e >= 100);
    const bool nxt = (i + 1 < nact);
    WAITVM(2);                 // retire K(i); keep V(i)
    BARRAW;
    if (nxt){                  // stage K/V(i+1) AFTER barrier (no race vs iter i-1 reads)
      int e2 = lists[i + 1];
      if (e2 < 100){ stageK512(Kh, 2048, e2 * 64, Ks[cur ^ 1], tid);
                     stageV512(Vth, 2048, e2 * 64, Vs[cur ^ 1], tid); }
      else         { stageK512(Kgh, 128, (e2 - 100) * 64, Ks[cur ^ 1], tid);
                     stageV512(Vgh, 256, (e2 - 100) * 64, Vs[cur ^ 1], tid); }
    }
    // QK^T
    f32x4 sacc[4];
#pragma unroll
    for (int n = 0; n < 4; n++) sacc[n] = (f32x4){0.f, 0.f, 0.f, 0.f};
#pragma unroll
    for (int ks = 0; ks < 4; ++ks){
#pragma unroll
      for (int n = 0; n < 4; n++){
        int brw = n * 16 + c15;
        bf16x8 b = *(const bf16x8*)(Ks[cur] + brw * 128 + ((ks * 32 + g * 8) ^ ((brw & 7) << 3)));
        sacc[n] = __builtin_amdgcn_mfma_f32_16x16x32_bf16(qfr[ks], b, sacc[n], 0, 0, 0);
      }
    }
    // masked exp -> P (LDS, wave-private), row sums
#pragma unroll
    for (int n = 0; n < 4; n++){
      int cid = isg ? (int)cids[(e - 100) * 64 + n * 16 + c15] : (e * 64 + n * 16 + c15);
#pragma unroll
      for (int r = 0; r < 4; r++){
        int rowg = rowbase + g * 4 + r;
        int dist = rowg - cid;
        bool valid = (cid <= rowg) && (isg ? (dist > RECENT) : (dist <= RECENT));
        float ev = valid ? __expf(sacc[n][r] * scale) : 0.f;
        lsum[r] += ev;
        int prow = g * 4 + r;
        Ps[w][prow * 64 + ((n * 16 + c15) ^ ((prow & 7) << 3))] = f2bf(ev);
      }
    }
    // retire V(i) (keep K/V(i+1)), then PV from LDS
    if (nxt) WAITVM(4); else WAITVM(0);
    BARRAW;
    PRIO1;
#pragma unroll
    for (int ks2 = 0; ks2 < 2; ++ks2){
      bf16x8 pa = *(const bf16x8*)(&Ps[w][c15 * 64 + ((ks2 * 32 + g * 8) ^ ((c15 & 7) << 3))]);
#pragma unroll
      for (int f = 0; f < 8; ++f){
        int vrow = f * 16 + c15;
        bf16x8 vb = *(const bf16x8*)(Vs[cur] + vrow * 64 + ((ks2 * 32 + g * 8) ^ ((vrow & 7) << 3)));
        oacc[f] = __builtin_amdgcn_mfma_f32_16x16x32_bf16(pa, vb, oacc[f], 0, 0, 0);
      }
    }
    PRIO0;
    cur ^= 1;
  }
  float rinv[4];
#pragma unroll
  for (int r = 0; r < 4; r++){
    float v = lsum[r];
    v += __shfl_xor(v, 1); v += __shfl_xor(v, 2);
    v += __shfl_xor(v, 4); v += __shfl_xor(v, 8);
    rinv[r] = 1.0f / v;
  }
#pragma unroll
  for (int f = 0; f < 8; f++)
#pragma unroll
    for (int r = 0; r < 4; r++){
      int rowg = rowbase + g * 4 + r;
      attn[(size_t)rowg * 2048 + h * HDIM + f * 16 + c15] = f2bf(oacc[f][r] * rinv[r]);
    }
}

// ---------------- host launcher ----------------
extern "C" void kernel_launch(void* const* d_in, const int* in_sizes, int n_in,
                              void* d_out, int out_size, void* d_ws, size_t ws_size,
                              hipStream_t stream){
  const float* X  = (const float*)d_in[0];
  const float* Wq = (const float*)d_in[1];
  const float* Wk = (const float*)d_in[2];
  const float* Wv = (const float*)d_in[3];
  const float* Wo = (const float*)d_in[4];

  char* w = (char*)d_ws;
  const size_t MB8 = (size_t)2048 * 2048 * 2;   // one bf16 matrix = 8 MiB
  u16* Xb  = (u16*)(w);
  u16* Wqb = (u16*)(w + 1 * MB8);
  u16* Wkb = (u16*)(w + 2 * MB8);
  u16* Wvb = (u16*)(w + 3 * MB8);
  u16* Wob = (u16*)(w + 4 * MB8);
  u16* Qb  = (u16*)(w + 5 * MB8);
  u16* Kb  = (u16*)(w + 6 * MB8);
  u16* Vb  = (u16*)(w + 7 * MB8);
  u16* Vtb   = Wqb;   // Wq dead after projections
  u16* attnb = Xb;    // X dead after projections
  char* p = w + 8 * MB8;
  float* cosT = (float*)p;              p += 524288;
  float* sinT = (float*)p;              p += 524288;
  float* colsum = (float*)p;            p += 131072;   // zeroed in k_prep (with rowsum)
  float* rowsum = (float*)p;            p += 131072;
  short* cidx  = (short*)p;             p += 16 * 256 * 2;
  u16*   Kg    = (u16*)p;               p += (size_t)16 * 256 * 128 * 2;
  u16*   Vg    = (u16*)p;

  dim3 b256(256);

  k_prep<<<21056, b256, 0, stream>>>(X, Wq, Wk, Wv, Wo, Xb, cosT, sinT, colsum);

  k_g256<<<dim3(32, 8), dim3(512), 0, stream>>>(Xb, Wqb, Wkb, Wvb, Qb, Kb, Vb);
  k_post<<<8192, b256, 0, stream>>>(Qb, Kb, cosT, sinT, Vb, Vtb);

  k_pass1a<<<dim3(40, 16), b256, 0, stream>>>(Qb, Kb, rowsum);
  k_pass1b<<<dim3(40, 16), b256, 0, stream>>>(Qb, Kb, rowsum, colsum);
  k_topk<<<16, dim3(1024), 0, stream>>>(colsum, cidx);
  k_gath<<<384, b256, 0, stream>>>(Kb, Vb, cidx, Kg, Vg);
  k_pass2<<<dim3(16, 16), dim3(512), 0, stream>>>(Qb, Kb, Vtb, Kg, Vg, cidx, attnb);

  k_gemm_out<<<dim3(16, 16), dim3(512), 0, stream>>>(attnb, Wob, (float*)d_out);
}

// Round 15
// 226.935 us; speedup vs baseline: 1.1122x; 1.0527x over previous
//
#include <hip/hip_runtime.h>
#include <hip/hip_bf16.h>
#include <stdint.h>

// Problem constants: b=1, s=2048, hidden=2048, H=16, d=128
#define SEQ   2048
#define HIDN  2048
#define NHEAD 16
#define HDIM  128
#define HEAVY 204   // int(0.1*2048)
#define RECENT 204
// Q is pre-scaled by (1/sqrt(128)) * log2(e) in k_post, so softmax uses exp2 directly.
#define QPRESCALE 0.12751743342f

typedef __attribute__((ext_vector_type(4))) float f32x4;
typedef __attribute__((ext_vector_type(8))) short bf16x8;
typedef unsigned short u16;
typedef unsigned int   u32;

static __device__ __forceinline__ u16 f2bf(float f){
  union { float f; u32 u; } v; v.f = f;
  u32 r = (v.u + 0x7FFFu + ((v.u >> 16) & 1u)) >> 16;
  return (u16)r;
}
static __device__ __forceinline__ float bf2f(u16 u){
  union { u32 u; float f; } v; v.u = ((u32)u) << 16;
  return v.f;
}
static __device__ __forceinline__ float exp2g(float x){
  return __builtin_amdgcn_exp2f(x);
}

// global -> LDS direct 16B load (dest is wave-uniform base + lane*16)
static __device__ __forceinline__ void gload16(const void* g, void* l){
  __builtin_amdgcn_global_load_lds((const __attribute__((address_space(1))) u32*)g,
                                   (__attribute__((address_space(3))) u32*)l, 16, 0, 0);
}

#define WAITVM(N) asm volatile("s_waitcnt vmcnt(" #N ")" ::: "memory")
#define BARRAW    __builtin_amdgcn_s_barrier()
#define PRIO1     __builtin_amdgcn_s_setprio(1)
#define PRIO0     __builtin_amdgcn_s_setprio(0)

// stage a 64x128 bf16 tile with 256 threads, runtime row stride (XOR-swizzled source)
static __device__ __forceinline__ void stage_tile(const u16* __restrict__ base, size_t stride,
                                                  int row0, u16* __restrict__ lds, int tid){
  const int wbase = tid & ~63;
#pragma unroll
  for (int it = 0; it < 4; ++it){
    int m = it * 256 + tid;
    int row = m >> 4, cp = m & 15;
    gload16(base + (size_t)(row0 + row) * stride + ((cp ^ (row & 7)) * 8),
            lds + (it * 256 + wbase) * 8);
  }
}

// stage 64x128 tile with 512 threads, runtime stride
static __device__ __forceinline__ void stageK512(const u16* __restrict__ base, size_t stride,
                                                 int row0, u16* __restrict__ lds, int tid){
#pragma unroll
  for (int it = 0; it < 2; ++it){
    int m = it * 512 + tid;
    int row = m >> 4, cp = m & 15;
    gload16(base + (size_t)(row0 + row) * stride + ((cp ^ (row & 7)) * 8),
            lds + (it * 512 + (tid & ~63)) * 8);
  }
}
// stage 128-row x 64-col tile (col offset c0) with 512 threads, runtime stride
static __device__ __forceinline__ void stageV512(const u16* __restrict__ base, size_t stride,
                                                 int c0, u16* __restrict__ lds, int tid){
#pragma unroll
  for (int it = 0; it < 2; ++it){
    int m = it * 512 + tid;
    int row = m >> 3, cp = m & 7;
    gload16(base + (size_t)row * stride + c0 + ((cp ^ (row & 7)) * 8),
            lds + (it * 512 + (tid & ~63)) * 8);
  }
}

// ---------------- prep: cvt5 + rope tables + zero colsum/rowsum (fused) ----------------
__global__ void k_prep(const float* __restrict__ A0, const float* __restrict__ A1,
                       const float* __restrict__ A2, const float* __restrict__ A3,
                       const float* __restrict__ A4, u16* __restrict__ out,
                       float* __restrict__ cosT, float* __restrict__ sinT,
                       float* __restrict__ colsum){
  int b = blockIdx.x, tid = threadIdx.x;
  if (b < 20480){
    int id = b * 256 + tid;
    int sel = id >> 20, off = (id & 1048575) * 4;
    const float* src = sel == 0 ? A0 : sel == 1 ? A1 : sel == 2 ? A2 : sel == 3 ? A3 : A4;
    float4 v = *(const float4*)(src + off);
    ushort4 o;
    o.x = f2bf(v.x); o.y = f2bf(v.y); o.z = f2bf(v.z); o.w = f2bf(v.w);
    *(ushort4*)(out + (size_t)sel * 4194304 + off) = o;
  } else if (b < 20992){
    int i = (b - 20480) * 256 + tid;           // 2048*64
    int pos = i >> 6, j = i & 63;
    float invf = powf(10000.0f, -(float)j * (1.0f / 64.0f));
    float a = (float)pos * invf;
    cosT[i] = cosf(a);
    sinT[i] = sinf(a);
  } else {
    int i = (b - 20992) * 256 + tid;           // 16384 float4 = colsum+rowsum (contiguous)
    if (i < 16384) ((float4*)colsum)[i] = (float4){0.f, 0.f, 0.f, 0.f};
  }
}

// ---------------- post: rope on Q,K (Q pre-scaled) + transpose V (fused) ----------------
__global__ void k_post(u16* __restrict__ Qm, u16* __restrict__ Km,
                       const float* __restrict__ cosT, const float* __restrict__ sinT,
                       const u16* __restrict__ V, u16* __restrict__ Vt){
  __shared__ u16 t[32][33];
  int b = blockIdx.x, tid = threadIdx.x;
  if (b < 4096){
    int gid = b * 256 + tid;                   // 2 * 524288
    bool isQ = (gid < 524288);
    u16* M = isQ ? Qm : Km;
    const float ps = isQ ? QPRESCALE : 1.0f;
    int id = gid & 524287;
    int pos = id >> 8, rem = id & 255;
    int h = rem >> 4, j4 = (rem & 15) * 4;
    u16* p = M + (size_t)pos * HIDN + h * HDIM + j4;
    ushort4 lo = *(ushort4*)p;
    ushort4 hi = *(ushort4*)(p + 64);
    float4 c = *(const float4*)(cosT + pos * 64 + j4);
    float4 s = *(const float4*)(sinT + pos * 64 + j4);
    float l0 = bf2f(lo.x), l1 = bf2f(lo.y), l2 = bf2f(lo.z), l3 = bf2f(lo.w);
    float h0 = bf2f(hi.x), h1 = bf2f(hi.y), h2 = bf2f(hi.z), h3 = bf2f(hi.w);
    ushort4 nlo, nhi;
    nlo.x = f2bf((l0 * c.x - h0 * s.x) * ps);  nhi.x = f2bf((h0 * c.x + l0 * s.x) * ps);
    nlo.y = f2bf((l1 * c.y - h1 * s.y) * ps);  nhi.y = f2bf((h1 * c.y + l1 * s.y) * ps);
    nlo.z = f2bf((l2 * c.z - h2 * s.z) * ps);  nhi.z = f2bf((h2 * c.z + l2 * s.z) * ps);
    nlo.w = f2bf((l3 * c.w - h3 * s.w) * ps);  nhi.w = f2bf((h3 * c.w + l3 * s.w) * ps);
    *(ushort4*)p = nlo;
    *(ushort4*)(p + 64) = nhi;
  } else {
    int b2 = b - 4096;
    int s0 = (b2 & 63) * 32, c0 = (b2 >> 6) * 32;
    int r = tid >> 3, cc = (tid & 7) * 4;
    ushort4 v = *(const ushort4*)(V + (size_t)(s0 + r) * 2048 + c0 + cc);
    t[r][cc] = v.x; t[r][cc + 1] = v.y; t[r][cc + 2] = v.z; t[r][cc + 3] = v.w;
    __syncthreads();
    int co = tid >> 3, ro = (tid & 7) * 4;
    ushort4 o;
    o.x = t[ro][co]; o.y = t[ro + 1][co]; o.z = t[ro + 2][co]; o.w = t[ro + 3][co];
    *(ushort4*)(Vt + (size_t)(c0 + co) * 2048 + s0 + ro) = o;
  }
}

// ---------------- fused projection GEMM: C[2048][6144] = X @ [Wq;Wk;Wv]^T ----------------
// 256x192 tile, BK=64, 8 waves, 2 barriers/tile, counted vmcnt. grid (32,8) = 256 blocks.
__global__ __launch_bounds__(512, 1)
void k_g256(const u16* __restrict__ X, const u16* __restrict__ Wq, const u16* __restrict__ Wk,
            const u16* __restrict__ Wv, u16* __restrict__ C0, u16* __restrict__ C1,
            u16* __restrict__ C2){
  __shared__ __align__(16) u16 LA[2][256 * 64];
  __shared__ __align__(16) u16 LB[2][192 * 64];
  const int tid = threadIdx.x;
  const int lane = tid & 63, wvi = tid >> 6;
  const int wm = wvi >> 2, wn = wvi & 3;
  const int g = lane >> 4, c15 = lane & 15;
  const int brow = blockIdx.y * 256;       // [0,2048)
  const int bcol = blockIdx.x * 192;       // [0,6144)
  const int NT = 32;

  f32x4 acc[8][3];
#pragma unroll
  for (int m = 0; m < 8; m++)
#pragma unroll
    for (int n = 0; n < 3; n++) acc[m][n] = (f32x4){0.f, 0.f, 0.f, 0.f};

  const int cc0 = ((g ^ (c15 & 7)) * 8);
  bf16x8 af[4][2], af2[4][2], bf[3][2];

#define BPTR(rB_) (rB_ < 2048 ? Wq + (size_t)(rB_) * 2048 \
                 : rB_ < 4096 ? Wk + (size_t)((rB_) - 2048) * 2048 \
                              : Wv + (size_t)((rB_) - 4096) * 2048)
#define STGA(grow0, gcol0, ldsb) do { \
  _Pragma("unroll") for (int it = 0; it < 2; ++it){ \
    int m_ = it * 512 + tid; \
    int row_ = m_ >> 3, cp_ = m_ & 7; \
    gload16(X + (size_t)((grow0) + row_) * 2048 + (gcol0) + ((cp_ ^ (row_ & 7)) * 8), \
            (ldsb) + (it * 512 + (tid & ~63)) * 8); \
  } } while(0)
#define STGB128(gcol0, ldsb) do { \
  _Pragma("unroll") for (int it = 0; it < 2; ++it){ \
    int m_ = it * 512 + tid; \
    int row_ = m_ >> 3, cp_ = m_ & 7; \
    int rB_ = bcol + row_; \
    const u16* bp_ = BPTR(rB_); \
    gload16(bp_ + (gcol0) + ((cp_ ^ (row_ & 7)) * 8), \
            (ldsb) + (it * 512 + (tid & ~63)) * 8); \
  } } while(0)
#define STGB64(gcol0, ldsb) do { \
    int row_ = 128 + (tid >> 3), cp_ = tid & 7; \
    int rB_ = bcol + row_; \
    const u16* bp_ = BPTR(rB_); \
    gload16(bp_ + (gcol0) + ((cp_ ^ (row_ & 7)) * 8), \
            (ldsb) + (tid & ~63) * 8); \
  } while(0)
#define RDA(buf) \
  _Pragma("unroll") for (int mi2 = 0; mi2 < 4; ++mi2){ \
    const u16* pr = &LA[buf][0] + (size_t)(wm * 128 + mi2 * 16 + c15) * 64; \
    af[mi2][0] = *(const bf16x8*)(pr + cc0); \
    af[mi2][1] = *(const bf16x8*)(pr + (cc0 ^ 32)); \
  }
#define RDA2(buf) \
  _Pragma("unroll") for (int mi2 = 0; mi2 < 4; ++mi2){ \
    const u16* pr = &LA[buf][0] + (size_t)(wm * 128 + (4 + mi2) * 16 + c15) * 64; \
    af2[mi2][0] = *(const bf16x8*)(pr + cc0); \
    af2[mi2][1] = *(const bf16x8*)(pr + (cc0 ^ 32)); \
  }
#define RDB2(buf) \
  _Pragma("unroll") for (int ni2 = 0; ni2 < 2; ++ni2){ \
    const u16* pr = &LB[buf][0] + (size_t)(wn * 48 + ni2 * 16 + c15) * 64; \
    bf[ni2][0] = *(const bf16x8*)(pr + cc0); \
    bf[ni2][1] = *(const bf16x8*)(pr + (cc0 ^ 32)); \
  }
#define RDB1(buf) do { \
    const u16* pr = &LB[buf][0] + (size_t)(wn * 48 + 32 + c15) * 64; \
    bf[2][0] = *(const bf16x8*)(pr + cc0); \
    bf[2][1] = *(const bf16x8*)(pr + (cc0 ^ 32)); \
  } while(0)
#define MM2A \
  _Pragma("unroll") for (int mi2 = 0; mi2 < 4; ++mi2) \
  _Pragma("unroll") for (int ni2 = 0; ni2 < 2; ++ni2) \
  _Pragma("unroll") for (int kk = 0; kk < 2; ++kk) \
    acc[mi2][ni2] = __builtin_amdgcn_mfma_f32_16x16x32_bf16( \
        af[mi2][kk], bf[ni2][kk], acc[mi2][ni2], 0, 0, 0);
#define MM1AB \
  _Pragma("unroll") for (int mi2 = 0; mi2 < 4; ++mi2) \
  _Pragma("unroll") for (int kk = 0; kk < 2; ++kk){ \
    acc[mi2][2] = __builtin_amdgcn_mfma_f32_16x16x32_bf16( \
        af[mi2][kk], bf[2][kk], acc[mi2][2], 0, 0, 0); \
    acc[4 + mi2][2] = __builtin_amdgcn_mfma_f32_16x16x32_bf16( \
        af2[mi2][kk], bf[2][kk], acc[4 + mi2][2], 0, 0, 0); \
  }
#define MM2B \
  _Pragma("unroll") for (int mi2 = 0; mi2 < 4; ++mi2) \
  _Pragma("unroll") for (int ni2 = 0; ni2 < 2; ++ni2) \
  _Pragma("unroll") for (int kk = 0; kk < 2; ++kk) \
    acc[4 + mi2][ni2] = __builtin_amdgcn_mfma_f32_16x16x32_bf16( \
        af2[mi2][kk], bf[ni2][kk], acc[4 + mi2][ni2], 0, 0, 0);

#define TILE(t, buf) do { \
    const int kn1 = ((t) + 1) * 64; \
    const int kn2 = ((t) + 2) * 64; \
    RDA(buf); RDB2(buf); RDA2(buf); RDB1(buf); \
    if ((t) + 1 < NT){ STGA(brow, kn1, &LA[buf ^ 1][0]); \
                       STGA(brow + 128, kn1, &LA[buf ^ 1][0] + 128 * 64); } \
    PRIO1; MM2A; MM1AB; PRIO0; \
    BARRAW; \
    if ((t) + 2 < NT){ STGB128(kn2, &LB[buf][0]); STGB64(kn2, &LB[buf][0] + 128 * 64); } \
    PRIO1; MM2B; PRIO0; \
    if ((t) + 2 < NT){ WAITVM(3); } \
    else if ((t) + 1 < NT){ WAITVM(0); } \
    BARRAW; \
  } while(0)

  STGA(brow,       0, &LA[0][0]);
  STGA(brow + 128, 0, &LA[0][0] + 128 * 64);
  STGB128(0,  &LB[0][0]);
  STGB64(0,   &LB[0][0] + 128 * 64);
  STGB128(64, &LB[1][0]);
  STGB64(64,  &LB[1][0] + 128 * 64);
  WAITVM(3);
  BARRAW;

  for (int t = 0; t < NT; t += 2){
    TILE(t, 0);
    TILE(t + 1, 1);
  }
#undef TILE
#undef BPTR
#undef STGA
#undef STGB128
#undef STGB64
#undef RDA
#undef RDA2
#undef RDB2
#undef RDB1
#undef MM2A
#undef MM1AB
#undef MM2B

#pragma unroll
  for (int mi = 0; mi < 8; ++mi)
#pragma unroll
    for (int ni = 0; ni < 3; ++ni){
      int colbase = bcol + wn * 48 + ni * 16;      // 2048-boundary is 16-aligned
      int proj = colbase >> 11;
      u16* Cb = proj == 0 ? C0 : proj == 1 ? C1 : C2;
      int lc = (colbase & 2047) + c15;
#pragma unroll
      for (int r = 0; r < 4; ++r){
        int row = brow + wm * 128 + mi * 16 + g * 4 + r;
        Cb[(size_t)row * 2048 + lc] = f2bf(acc[mi][ni][r]);
      }
    }
}

// ---------------- output GEMM: 128x128 tile, BK=128, 8 waves, counted vmcnt ----------------
// grid (16,16) = 256 blocks, 512 thr; 32 MFMA per barrier-pair (2x density vs BK=64).
__global__ __launch_bounds__(512)
void k_gemm_out(const u16* __restrict__ A, const u16* __restrict__ B, float* __restrict__ C){
  __shared__ __align__(16) u16 As[2][128 * 128];
  __shared__ __align__(16) u16 Bs[2][128 * 128];
  const int tid = threadIdx.x;
  const int w = tid >> 6, lane = tid & 63;
  const int wm = w >> 1, wn = w & 1;
  const int g = lane >> 4, c15 = lane & 15;
  const int brow = blockIdx.y * 128, bcol = blockIdx.x * 128;

  f32x4 acc[2][4];
#pragma unroll
  for (int m = 0; m < 2; m++)
#pragma unroll
    for (int n = 0; n < 4; n++) acc[m][n] = (f32x4){0.f, 0.f, 0.f, 0.f};

// stage 128x128 tile for A and B: 4+4 loads/thread
#define STG_O(k0, buf) do { \
  _Pragma("unroll") for (int it = 0; it < 4; ++it){ \
    int m_ = it * 512 + tid; \
    int row_ = m_ >> 4, cp_ = m_ & 15; \
    gload16(A + (size_t)(brow + row_) * 2048 + (k0) + ((cp_ ^ (row_ & 7)) * 8), \
            As[buf] + (it * 512 + (tid & ~63)) * 8); \
    gload16(B + (size_t)(bcol + row_) * 2048 + (k0) + ((cp_ ^ (row_ & 7)) * 8), \
            Bs[buf] + (it * 512 + (tid & ~63)) * 8); \
  } } while(0)

  STG_O(0, 0);
  int cur = 0;
  for (int kt = 0; kt < 16; ++kt){
    if (kt + 1 < 16){ STG_O((kt + 1) * 128, cur ^ 1); WAITVM(8); }
    else            { WAITVM(0); }
    BARRAW;
    bf16x8 af[2][4], bfr[4][4];
#pragma unroll
    for (int mi = 0; mi < 2; ++mi){
      int row = wm * 32 + mi * 16 + c15;
#pragma unroll
      for (int ks = 0; ks < 4; ++ks)
        af[mi][ks] = *(const bf16x8*)(As[cur] + (size_t)row * 128 + ((ks * 32 + g * 8) ^ ((row & 7) << 3)));
    }
#pragma unroll
    for (int ni = 0; ni < 4; ++ni){
      int row = wn * 64 + ni * 16 + c15;
#pragma unroll
      for (int ks = 0; ks < 4; ++ks)
        bfr[ni][ks] = *(const bf16x8*)(Bs[cur] + (size_t)row * 128 + ((ks * 32 + g * 8) ^ ((row & 7) << 3)));
    }
    PRIO1;
#pragma unroll
    for (int mi = 0; mi < 2; ++mi)
#pragma unroll
      for (int ni = 0; ni < 4; ++ni)
#pragma unroll
        for (int ks = 0; ks < 4; ++ks)
          acc[mi][ni] = __builtin_amdgcn_mfma_f32_16x16x32_bf16(af[mi][ks], bfr[ni][ks],
                                                                acc[mi][ni], 0, 0, 0);
    PRIO0;
    BARRAW;
    cur ^= 1;
  }
#undef STG_O
#pragma unroll
  for (int mi = 0; mi < 2; ++mi)
#pragma unroll
    for (int ni = 0; ni < 4; ++ni)
#pragma unroll
      for (int r = 0; r < 4; ++r){
        int row = brow + wm * 32 + mi * 16 + g * 4 + r;
        int col = bcol + wn * 64 + ni * 16 + c15;
        C[(size_t)row * 2048 + col] = acc[mi][ni][r];
      }
}

// ---------------- pass 1a: rowsum of exp2 (causal), Q-in-registers ----------------
// grid (40, 16), 256 thr; K triple-buffered LDS stream, 1 barrier/iter.
__global__ __launch_bounds__(256)
void k_pass1a(const u16* __restrict__ Q, const u16* __restrict__ K, float* __restrict__ rowsum){
  __shared__ __align__(16) u16 Ks[3][64 * 128];
  const int tid = threadIdx.x;
  const int wv = tid >> 6, lane = tid & 63;
  const int g = lane >> 4, c15 = lane & 15;
  const int h = blockIdx.y;
  int qb = 0, c = 0;
  { int rem = blockIdx.x; int q = 0;
    while (rem >= ((2 * q + 9) >> 3)){ rem -= (2 * q + 9) >> 3; q++; }
    qb = q; c = rem; }
  const int i0 = qb * 128;
  const int ktend = 2 * qb + 2;
  const int kt0 = c * 8;
  const int kt1 = (ktend < kt0 + 8) ? ktend : (kt0 + 8);
  const u16* Qh = Q + h * HDIM;
  const u16* Kh = K + h * HDIM;
  const int wb = wv * 32;

  bf16x8 qfr[2][4];
#pragma unroll
  for (int m = 0; m < 2; m++)
#pragma unroll
    for (int ks = 0; ks < 4; ks++)
      qfr[m][ks] = *(const bf16x8*)(Qh + (size_t)(i0 + wb + m * 16 + c15) * 2048 + ks * 32 + g * 8);

  stage_tile(Kh, 2048, kt0 * 64, Ks[0], tid);
  if (kt0 + 1 < kt1) stage_tile(Kh, 2048, (kt0 + 1) * 64, Ks[1], tid);

  float rs[2][4] = {{0.f,0.f,0.f,0.f},{0.f,0.f,0.f,0.f}};
  for (int kt = kt0; kt < kt1; ++kt){
    const int bi = (kt - kt0) % 3;
    if (kt + 1 < kt1){ WAITVM(4); } else { WAITVM(0); }
    BARRAW;
    if (kt + 2 < kt1) stage_tile(Kh, 2048, (kt + 2) * 64, Ks[(kt - kt0 + 2) % 3], tid);
    const int k0 = kt * 64;
    f32x4 sacc[2][4];
#pragma unroll
    for (int m = 0; m < 2; m++)
#pragma unroll
      for (int n = 0; n < 4; n++) sacc[m][n] = (f32x4){0.f, 0.f, 0.f, 0.f};
#pragma unroll
    for (int ks = 0; ks < 4; ++ks){
#pragma unroll
      for (int n = 0; n < 4; n++){
        int brw = n * 16 + c15;
        bf16x8 b = *(const bf16x8*)(Ks[bi] + brw * 128 + ((ks * 32 + g * 8) ^ ((brw & 7) << 3)));
#pragma unroll
        for (int m = 0; m < 2; m++)
          sacc[m][n] = __builtin_amdgcn_mfma_f32_16x16x32_bf16(qfr[m][ks], b, sacc[m][n], 0, 0, 0);
      }
    }
    if (kt < 2 * qb){            // fully causal tile: no mask compare
#pragma unroll
      for (int m = 0; m < 2; m++)
#pragma unroll
        for (int n = 0; n < 4; n++)
#pragma unroll
          for (int r = 0; r < 4; r++)
            rs[m][r] += exp2g(sacc[m][n][r]);
    } else {
#pragma unroll
      for (int n = 0; n < 4; n++){
        int col = k0 + n * 16 + c15;
#pragma unroll
        for (int m = 0; m < 2; m++)
#pragma unroll
          for (int r = 0; r < 4; r++){
            int rowg = i0 + wb + m * 16 + g * 4 + r;
            rs[m][r] += (col <= rowg) ? exp2g(sacc[m][n][r]) : 0.f;
          }
      }
    }
  }
#pragma unroll
  for (int m = 0; m < 2; m++)
#pragma unroll
    for (int r = 0; r < 4; r++){
      float v = rs[m][r];
      v += __shfl_xor(v, 1); v += __shfl_xor(v, 2);
      v += __shfl_xor(v, 4); v += __shfl_xor(v, 8);
      if (c15 == 0)
        atomicAdd(&rowsum[h * 2048 + i0 + wb + m * 16 + g * 4 + r], v);
    }
}

// ---------------- pass 1b: colsum of normalized exp2, K-in-registers ----------------
// grid (40, 16), 256 thr; Q triple-buffered LDS stream, 1 barrier/iter.
__global__ __launch_bounds__(256)
void k_pass1b(const u16* __restrict__ Q, const u16* __restrict__ K,
              const float* __restrict__ rowsum, float* __restrict__ colsum){
  __shared__ __align__(16) u16 Qs[3][64 * 128];
  const int tid = threadIdx.x;
  const int wv = tid >> 6, lane = tid & 63;
  const int g = lane >> 4, c15 = lane & 15;
  const int h = blockIdx.y;
  int kb = 0, c = 0;
  { int rem = blockIdx.x; int q = 0;
    while (rem >= ((39 - 2 * q) >> 3)){ rem -= (39 - 2 * q) >> 3; q++; }
    kb = q; c = rem; }
  const int k0 = kb * 128;
  const int qt0 = 2 * kb + c * 8;
  const int qt1 = (2 * kb + c * 8 + 8 < 32) ? (2 * kb + c * 8 + 8) : 32;
  const u16* Qh = Q + h * HDIM;
  const u16* Kh = K + h * HDIM;
  const int wb = wv * 32;
  const float* rsrow = rowsum + h * 2048;

  bf16x8 kfr[2][4];
#pragma unroll
  for (int m = 0; m < 2; m++)
#pragma unroll
    for (int ks = 0; ks < 4; ks++)
      kfr[m][ks] = *(const bf16x8*)(Kh + (size_t)(k0 + wb + m * 16 + c15) * 2048 + ks * 32 + g * 8);

  stage_tile(Qh, 2048, qt0 * 64, Qs[0], tid);
  if (qt0 + 1 < qt1) stage_tile(Qh, 2048, (qt0 + 1) * 64, Qs[1], tid);

  float racc[2][4] = {{0.f,0.f,0.f,0.f},{0.f,0.f,0.f,0.f}};
  for (int qt = qt0; qt < qt1; ++qt){
    const int bi = (qt - qt0) % 3;
    if (qt + 1 < qt1){ WAITVM(4); } else { WAITVM(0); }
    BARRAW;
    if (qt + 2 < qt1) stage_tile(Qh, 2048, (qt + 2) * 64, Qs[(qt - qt0 + 2) % 3], tid);
    const int i0q = qt * 64;
    float rw[4];
#pragma unroll
    for (int n = 0; n < 4; n++)
      rw[n] = 1.0f / rsrow[i0q + n * 16 + c15];
    f32x4 sacc[2][4];
#pragma unroll
    for (int m = 0; m < 2; m++)
#pragma unroll
      for (int n = 0; n < 4; n++) sacc[m][n] = (f32x4){0.f, 0.f, 0.f, 0.f};
#pragma unroll
    for (int ks = 0; ks < 4; ++ks){
#pragma unroll
      for (int n = 0; n < 4; n++){
        int brw = n * 16 + c15;
        bf16x8 b = *(const bf16x8*)(Qs[bi] + brw * 128 + ((ks * 32 + g * 8) ^ ((brw & 7) << 3)));
#pragma unroll
        for (int m = 0; m < 2; m++)
          sacc[m][n] = __builtin_amdgcn_mfma_f32_16x16x32_bf16(kfr[m][ks], b, sacc[m][n], 0, 0, 0);
      }
    }
    if (qt >= 2 * kb + 2){       // fully causal: no mask compare
#pragma unroll
      for (int m = 0; m < 2; m++)
#pragma unroll
        for (int n = 0; n < 4; n++)
#pragma unroll
          for (int r = 0; r < 4; r++)
            racc[m][r] += exp2g(sacc[m][n][r]) * rw[n];
    } else {
#pragma unroll
      for (int n = 0; n < 4; n++){
        int colq = i0q + n * 16 + c15;
#pragma unroll
        for (int m = 0; m < 2; m++)
#pragma unroll
          for (int r = 0; r < 4; r++){
            int rowk = k0 + wb + m * 16 + g * 4 + r;
            racc[m][r] += (rowk <= colq) ? exp2g(sacc[m][n][r]) * rw[n] : 0.f;
          }
      }
    }
  }
#pragma unroll
  for (int m = 0; m < 2; m++)
#pragma unroll
    for (int r = 0; r < 4; r++){
      float v = racc[m][r];
      v += __shfl_xor(v, 1); v += __shfl_xor(v, 2);
      v += __shfl_xor(v, 4); v += __shfl_xor(v, 8);
      if (c15 == 0)
        atomicAdd(&colsum[h * 2048 + k0 + wb + m * 16 + g * 4 + r], v);
    }
}

// ---------------- top-k via exact radix-select (select only, 16 blocks) ----------------
__global__ __launch_bounds__(1024)
void k_topk(const float* __restrict__ colsum, short* __restrict__ cidx){
  __shared__ u32 keys[2048];
  __shared__ int hist[256];
  __shared__ int chunkCnt[32];
  __shared__ short cidL[256];
  __shared__ u32 Tacc_s;
  __shared__ int rem_s;
  const int tid = threadIdx.x;
  const int h = blockIdx.x;
  const int w = tid >> 6, lane = tid & 63;

  for (int i = tid; i < 2048; i += 1024) keys[i] = ((const u32*)colsum)[h * 2048 + i];
  if (tid == 0){ Tacc_s = 0; rem_s = HEAVY; }
  __syncthreads();

  for (int s = 24; s >= 0; s -= 8){
    if (tid < 256) hist[tid] = 0;
    __syncthreads();
    u32 T = Tacc_s;
    for (int i = tid; i < 2048; i += 1024){
      u32 k = keys[i];
      bool match = (s == 24) ? true : (((k ^ T) >> (s + 8)) == 0);
      if (match) atomicAdd(&hist[(k >> s) & 255], 1);
    }
    __syncthreads();
    if (tid == 0){
      int rem = rem_s, acc = 0, b = 255;
      for (; b > 0; --b){
        int c2 = hist[b];
        if (acc + c2 >= rem) break;
        acc += c2;
      }
      Tacc_s = T | ((u32)b << s);
      rem_s = rem - acc;
    }
    __syncthreads();
  }
  const u32 T = Tacc_s;
  const int need = rem_s;                 // smallest-index ties among == T
  const u32 kA = keys[tid], kB = keys[tid + 1024];
  const bool eqA = (kA == T), eqB = (kB == T);
  unsigned long long ebA = __ballot(eqA);
  unsigned long long ebB = __ballot(eqB);
  if (lane == 0){ chunkCnt[w] = __popcll(ebA); chunkCnt[16 + w] = __popcll(ebB); }
  __syncthreads();
  if (tid == 0){
    int s2 = 0;
    for (int i2 = 0; i2 < 32; ++i2){ int c2 = chunkCnt[i2]; chunkCnt[i2] = s2; s2 += c2; }
  }
  __syncthreads();
  const unsigned long long below = (1ull << lane) - 1ull;
  const int eqrA = chunkCnt[w] + __popcll(ebA & below);
  const int eqrB = chunkCnt[16 + w] + __popcll(ebB & below);
  const bool hvA = (kA > T) || (eqA && eqrA < need);
  const bool hvB = (kB > T) || (eqB && eqrB < need);
  __syncthreads();                        // before reusing chunkCnt
  unsigned long long hbA = __ballot(hvA);
  unsigned long long hbB = __ballot(hvB);
  if (lane == 0){ chunkCnt[w] = __popcll(hbA); chunkCnt[16 + w] = __popcll(hbB); }
  if (tid >= HEAVY && tid < 256) cidL[tid] = 32767;
  __syncthreads();
  if (tid == 0){
    int s2 = 0;
    for (int i2 = 0; i2 < 32; ++i2){ int c2 = chunkCnt[i2]; chunkCnt[i2] = s2; s2 += c2; }
  }
  __syncthreads();
  if (hvA) cidL[chunkCnt[w] + __popcll(hbA & below)] = (short)tid;
  if (hvB) cidL[chunkCnt[16 + w] + __popcll(hbB & below)] = (short)(tid + 1024);
  __syncthreads();
  if (tid < 256) cidx[h * 256 + tid] = cidL[tid];
}

// ---------------- gather heavy K rows + V cols (full-grid, 384 blocks) ----------------
__global__ void k_gath(const u16* __restrict__ Kb, const u16* __restrict__ Vb,
                       const short* __restrict__ cidx,
                       u16* __restrict__ Kg, u16* __restrict__ Vg){
  __shared__ __align__(16) u16 t[32][136];
  int b = blockIdx.x, tid = threadIdx.x;
  if (b < 256){
    int gid = b * 256 + tid;                   // 16h * 256slot * 16chunk = 65536
    int h = gid >> 12, rem = gid & 4095;
    int slot = rem >> 4, cp = rem & 15;
    int cid = cidx[h * 256 + slot];
    bf16x8 z = (bf16x8){0,0,0,0,0,0,0,0};
    bf16x8 val = (cid < 2048) ? *(const bf16x8*)(Kb + (size_t)cid * 2048 + h * 128 + cp * 8) : z;
    *(bf16x8*)(Kg + ((size_t)h * 256 + slot) * 128 + cp * 8) = val;
  } else {
    int b2 = b - 256;
    int h = b2 >> 3, s0 = (b2 & 7) * 32;
#pragma unroll
    for (int it = 0; it < 2; ++it){
      int m = it * 256 + tid;                  // 512 chunks = 32 slots x 16 chunks
      int s = m >> 4, cp = m & 15;
      int cid = cidx[h * 256 + s0 + s];
      bf16x8 z = (bf16x8){0,0,0,0,0,0,0,0};
      bf16x8 val = (cid < 2048) ? *(const bf16x8*)(Vb + (size_t)cid * 2048 + h * 128 + cp * 8) : z;
      *(bf16x8*)(&t[s][cp * 8]) = val;
    }
    __syncthreads();
#pragma unroll
    for (int i = 0; i < 16; ++i){
      int idx = i * 256 + tid;                 // 4096 = 128 d x 32 s
      int d = idx >> 5, s = idx & 31;
      Vg[((size_t)h * 128 + d) * 256 + s0 + s] = t[s][d];
    }
  }
}

// ---------------- pass 2: QBLK=128, Q-in-reg, K+V LDS dbuf, 2 barriers/iter ----------------
// grid (16, 16) = 256 blocks, 512 thr (8 waves: 2 q-halves x 4 strips)
__global__ __launch_bounds__(512)
void k_pass2(const u16* __restrict__ Q, const u16* __restrict__ K, const u16* __restrict__ Vt,
             const u16* __restrict__ Kg, const u16* __restrict__ Vg,
             const short* __restrict__ cidx, u16* __restrict__ attn){
  __shared__ __align__(16) u16 Ks[2][64 * 128];
  __shared__ __align__(16) u16 Vs[2][128 * 64];
  __shared__ __align__(16) u16 Ps[8][16 * 64];
  __shared__ short cids[256];
  __shared__ int lists[12];
  __shared__ int nact_s;
  const int tid = threadIdx.x;
  const int w = tid >> 6, lane = tid & 63;
  const int g = lane >> 4, c15 = lane & 15;
  const int qb = blockIdx.x, h = blockIdx.y;
  const int i0 = qb * 128;
  const int wq = w >> 2, w4 = w & 3;
  const int rowbase = i0 + wq * 64 + w4 * 16;
  const u16* Qh = Q + h * HDIM;
  const u16* Kh = K + h * HDIM;
  const u16* Kgh = Kg + (size_t)h * 256 * 128;
  const u16* Vth = Vt + (size_t)h * 128 * 2048;
  const u16* Vgh = Vg + (size_t)h * 128 * 256;

  if (tid < 256) cids[tid] = cidx[h * 256 + tid];
  // Q fragments in registers (rows rowbase + c15)
  bf16x8 qfr[4];
#pragma unroll
  for (int ks = 0; ks < 4; ks++)
    qfr[ks] = *(const bf16x8*)(Qh + (size_t)(rowbase + c15) * 2048 + ks * 32 + g * 8);
  __syncthreads();
  if (tid == 0){
    int n = 0;
    int ktb0 = (i0 > RECENT) ? ((i0 - RECENT) >> 6) : 0;
    int ktmax = (i0 + 127) >> 6;
    for (int kt = ktb0; kt <= ktmax; ++kt) lists[n++] = kt;
    for (int gt = 0; gt < 4; ++gt)
      if ((int)cids[gt * 64] <= i0 + 127 - RECENT - 1) lists[n++] = 100 + gt;
    nact_s = n;
  }
  __syncthreads();
  const int nact = nact_s;

  // prologue: stage K0 (2) + V0 (2) only
  { int e = lists[0];
    if (e < 100){ stageK512(Kh, 2048, e * 64, Ks[0], tid);
                  stageV512(Vth, 2048, e * 64, Vs[0], tid); }
    else        { stageK512(Kgh, 128, (e - 100) * 64, Ks[0], tid);
                  stageV512(Vgh, 256, (e - 100) * 64, Vs[0], tid); } }

  f32x4 oacc[8];
#pragma unroll
  for (int f = 0; f < 8; f++) oacc[f] = (f32x4){0.f, 0.f, 0.f, 0.f};
  float lsum[4] = {0.f, 0.f, 0.f, 0.f};

  int cur = 0;
  for (int i = 0; i < nact; ++i){
    const int e = lists[i];
    const bool isg = (e >= 100);
    const bool nxt = (i + 1 < nact);
    WAITVM(2);                 // retire K(i); keep V(i)
    BARRAW;
    if (nxt){                  // stage K/V(i+1) AFTER barrier (no race vs iter i-1 reads)
      int e2 = lists[i + 1];
      if (e2 < 100){ stageK512(Kh, 2048, e2 * 64, Ks[cur ^ 1], tid);
                     stageV512(Vth, 2048, e2 * 64, Vs[cur ^ 1], tid); }
      else         { stageK512(Kgh, 128, (e2 - 100) * 64, Ks[cur ^ 1], tid);
                     stageV512(Vgh, 256, (e2 - 100) * 64, Vs[cur ^ 1], tid); }
    }
    // QK^T
    f32x4 sacc[4];
#pragma unroll
    for (int n = 0; n < 4; n++) sacc[n] = (f32x4){0.f, 0.f, 0.f, 0.f};
#pragma unroll
    for (int ks = 0; ks < 4; ++ks){
#pragma unroll
      for (int n = 0; n < 4; n++){
        int brw = n * 16 + c15;
        bf16x8 b = *(const bf16x8*)(Ks[cur] + brw * 128 + ((ks * 32 + g * 8) ^ ((brw & 7) << 3)));
        sacc[n] = __builtin_amdgcn_mfma_f32_16x16x32_bf16(qfr[ks], b, sacc[n], 0, 0, 0);
      }
    }
    // masked exp2 -> P (LDS, wave-private), row sums
#pragma unroll
    for (int n = 0; n < 4; n++){
      int cid = isg ? (int)cids[(e - 100) * 64 + n * 16 + c15] : (e * 64 + n * 16 + c15);
#pragma unroll
      for (int r = 0; r < 4; r++){
        int rowg = rowbase + g * 4 + r;
        int dist = rowg - cid;
        bool valid = (cid <= rowg) && (isg ? (dist > RECENT) : (dist <= RECENT));
        float ev = valid ? exp2g(sacc[n][r]) : 0.f;
        lsum[r] += ev;
        int prow = g * 4 + r;
        Ps[w][prow * 64 + ((n * 16 + c15) ^ ((prow & 7) << 3))] = f2bf(ev);
      }
    }
    // retire V(i) (keep K/V(i+1)), then PV from LDS
    if (nxt) WAITVM(4); else WAITVM(0);
    BARRAW;
    PRIO1;
#pragma unroll
    for (int ks2 = 0; ks2 < 2; ++ks2){
      bf16x8 pa = *(const bf16x8*)(&Ps[w][c15 * 64 + ((ks2 * 32 + g * 8) ^ ((c15 & 7) << 3))]);
#pragma unroll
      for (int f = 0; f < 8; ++f){
        int vrow = f * 16 + c15;
        bf16x8 vb = *(const bf16x8*)(Vs[cur] + vrow * 64 + ((ks2 * 32 + g * 8) ^ ((vrow & 7) << 3)));
        oacc[f] = __builtin_amdgcn_mfma_f32_16x16x32_bf16(pa, vb, oacc[f], 0, 0, 0);
      }
    }
    PRIO0;
    cur ^= 1;
  }
  float rinv[4];
#pragma unroll
  for (int r = 0; r < 4; r++){
    float v = lsum[r];
    v += __shfl_xor(v, 1); v += __shfl_xor(v, 2);
    v += __shfl_xor(v, 4); v += __shfl_xor(v, 8);
    rinv[r] = 1.0f / v;
  }
#pragma unroll
  for (int f = 0; f < 8; f++)
#pragma unroll
    for (int r = 0; r < 4; r++){
      int rowg = rowbase + g * 4 + r;
      attn[(size_t)rowg * 2048 + h * HDIM + f * 16 + c15] = f2bf(oacc[f][r] * rinv[r]);
    }
}

// ---------------- host launcher ----------------
extern "C" void kernel_launch(void* const* d_in, const int* in_sizes, int n_in,
                              void* d_out, int out_size, void* d_ws, size_t ws_size,
                              hipStream_t stream){
  const float* X  = (const float*)d_in[0];
  const float* Wq = (const float*)d_in[1];
  const float* Wk = (const float*)d_in[2];
  const float* Wv = (const float*)d_in[3];
  const float* Wo = (const float*)d_in[4];

  char* w = (char*)d_ws;
  const size_t MB8 = (size_t)2048 * 2048 * 2;   // one bf16 matrix = 8 MiB
  u16* Xb  = (u16*)(w);
  u16* Wqb = (u16*)(w + 1 * MB8);
  u16* Wkb = (u16*)(w + 2 * MB8);
  u16* Wvb = (u16*)(w + 3 * MB8);
  u16* Wob = (u16*)(w + 4 * MB8);
  u16* Qb  = (u16*)(w + 5 * MB8);
  u16* Kb  = (u16*)(w + 6 * MB8);
  u16* Vb  = (u16*)(w + 7 * MB8);
  u16* Vtb   = Wqb;   // Wq dead after projections
  u16* attnb = Xb;    // X dead after projections
  char* p = w + 8 * MB8;
  float* cosT = (float*)p;              p += 524288;
  float* sinT = (float*)p;              p += 524288;
  float* colsum = (float*)p;            p += 131072;   // zeroed in k_prep (with rowsum)
  float* rowsum = (float*)p;            p += 131072;
  short* cidx  = (short*)p;             p += 16 * 256 * 2;
  u16*   Kg    = (u16*)p;               p += (size_t)16 * 256 * 128 * 2;
  u16*   Vg    = (u16*)p;

  dim3 b256(256);

  k_prep<<<21056, b256, 0, stream>>>(X, Wq, Wk, Wv, Wo, Xb, cosT, sinT, colsum);

  k_g256<<<dim3(32, 8), dim3(512), 0, stream>>>(Xb, Wqb, Wkb, Wvb, Qb, Kb, Vb);
  k_post<<<8192, b256, 0, stream>>>(Qb, Kb, cosT, sinT, Vb, Vtb);

  k_pass1a<<<dim3(40, 16), b256, 0, stream>>>(Qb, Kb, rowsum);
  k_pass1b<<<dim3(40, 16), b256, 0, stream>>>(Qb, Kb, rowsum, colsum);
  k_topk<<<16, dim3(1024), 0, stream>>>(colsum, cidx);
  k_gath<<<384, b256, 0, stream>>>(Kb, Vb, cidx, Kg, Vg);
  k_pass2<<<dim3(16, 16), dim3(512), 0, stream>>>(Qb, Kb, Vtb, Kg, Vg, cidx, attnb);

  k_gemm_out<<<dim3(16, 16), dim3(512), 0, stream>>>(attnb, Wob, (float*)d_out);
}

// Round 16
// 226.566 us; speedup vs baseline: 1.1140x; 1.0016x over previous
//
#include <hip/hip_runtime.h>
#include <hip/hip_bf16.h>
#include <stdint.h>

// Problem constants: b=1, s=2048, hidden=2048, H=16, d=128
#define SEQ   2048
#define HIDN  2048
#define NHEAD 16
#define HDIM  128
#define HEAVY 204   // int(0.1*2048)
#define RECENT 204
// Q is pre-scaled by (1/sqrt(128)) * log2(e) in k_post, so softmax uses exp2 directly.
#define QPRESCALE 0.12751743342f

typedef __attribute__((ext_vector_type(4))) float f32x4;
typedef __attribute__((ext_vector_type(8))) short bf16x8;
typedef unsigned short u16;
typedef unsigned int   u32;

static __device__ __forceinline__ u16 f2bf(float f){
  union { float f; u32 u; } v; v.f = f;
  u32 r = (v.u + 0x7FFFu + ((v.u >> 16) & 1u)) >> 16;
  return (u16)r;
}
static __device__ __forceinline__ float bf2f(u16 u){
  union { u32 u; float f; } v; v.u = ((u32)u) << 16;
  return v.f;
}
static __device__ __forceinline__ float exp2g(float x){
  return __builtin_amdgcn_exp2f(x);
}

// global -> LDS direct 16B load (dest is wave-uniform base + lane*16)
static __device__ __forceinline__ void gload16(const void* g, void* l){
  __builtin_amdgcn_global_load_lds((const __attribute__((address_space(1))) u32*)g,
                                   (__attribute__((address_space(3))) u32*)l, 16, 0, 0);
}

#define WAITVM(N) asm volatile("s_waitcnt vmcnt(" #N ")" ::: "memory")
#define BARRAW    __builtin_amdgcn_s_barrier()
#define PRIO1     __builtin_amdgcn_s_setprio(1)
#define PRIO0     __builtin_amdgcn_s_setprio(0)

// stage a 64x128 bf16 tile with 256 threads, runtime row stride (XOR-swizzled source)
static __device__ __forceinline__ void stage_tile(const u16* __restrict__ base, size_t stride,
                                                  int row0, u16* __restrict__ lds, int tid){
  const int wbase = tid & ~63;
#pragma unroll
  for (int it = 0; it < 4; ++it){
    int m = it * 256 + tid;
    int row = m >> 4, cp = m & 15;
    gload16(base + (size_t)(row0 + row) * stride + ((cp ^ (row & 7)) * 8),
            lds + (it * 256 + wbase) * 8);
  }
}

// stage 64x128 tile with 512 threads, runtime stride
static __device__ __forceinline__ void stageK512(const u16* __restrict__ base, size_t stride,
                                                 int row0, u16* __restrict__ lds, int tid){
#pragma unroll
  for (int it = 0; it < 2; ++it){
    int m = it * 512 + tid;
    int row = m >> 4, cp = m & 15;
    gload16(base + (size_t)(row0 + row) * stride + ((cp ^ (row & 7)) * 8),
            lds + (it * 512 + (tid & ~63)) * 8);
  }
}
// stage 128-row x 64-col tile (col offset c0) with 512 threads, runtime stride
static __device__ __forceinline__ void stageV512(const u16* __restrict__ base, size_t stride,
                                                 int c0, u16* __restrict__ lds, int tid){
#pragma unroll
  for (int it = 0; it < 2; ++it){
    int m = it * 512 + tid;
    int row = m >> 3, cp = m & 7;
    gload16(base + (size_t)row * stride + c0 + ((cp ^ (row & 7)) * 8),
            lds + (it * 512 + (tid & ~63)) * 8);
  }
}

// ---------------- prep: cvt5 + rope tables + zero colsum/rowsum (fused) ----------------
__global__ void k_prep(const float* __restrict__ A0, const float* __restrict__ A1,
                       const float* __restrict__ A2, const float* __restrict__ A3,
                       const float* __restrict__ A4, u16* __restrict__ out,
                       float* __restrict__ cosT, float* __restrict__ sinT,
                       float* __restrict__ colsum){
  int b = blockIdx.x, tid = threadIdx.x;
  if (b < 20480){
    int id = b * 256 + tid;
    int sel = id >> 20, off = (id & 1048575) * 4;
    const float* src = sel == 0 ? A0 : sel == 1 ? A1 : sel == 2 ? A2 : sel == 3 ? A3 : A4;
    float4 v = *(const float4*)(src + off);
    ushort4 o;
    o.x = f2bf(v.x); o.y = f2bf(v.y); o.z = f2bf(v.z); o.w = f2bf(v.w);
    *(ushort4*)(out + (size_t)sel * 4194304 + off) = o;
  } else if (b < 20992){
    int i = (b - 20480) * 256 + tid;           // 2048*64
    int pos = i >> 6, j = i & 63;
    float invf = powf(10000.0f, -(float)j * (1.0f / 64.0f));
    float a = (float)pos * invf;
    cosT[i] = cosf(a);
    sinT[i] = sinf(a);
  } else {
    int i = (b - 20992) * 256 + tid;           // 16384 float4 = colsum+rowsum (contiguous)
    if (i < 16384) ((float4*)colsum)[i] = (float4){0.f, 0.f, 0.f, 0.f};
  }
}

// ---------------- post: rope on Q,K (Q pre-scaled) + transpose V (fused) ----------------
__global__ void k_post(u16* __restrict__ Qm, u16* __restrict__ Km,
                       const float* __restrict__ cosT, const float* __restrict__ sinT,
                       const u16* __restrict__ V, u16* __restrict__ Vt){
  __shared__ u16 t[32][33];
  int b = blockIdx.x, tid = threadIdx.x;
  if (b < 4096){
    int gid = b * 256 + tid;                   // 2 * 524288
    bool isQ = (gid < 524288);
    u16* M = isQ ? Qm : Km;
    const float ps = isQ ? QPRESCALE : 1.0f;
    int id = gid & 524287;
    int pos = id >> 8, rem = id & 255;
    int h = rem >> 4, j4 = (rem & 15) * 4;
    u16* p = M + (size_t)pos * HIDN + h * HDIM + j4;
    ushort4 lo = *(ushort4*)p;
    ushort4 hi = *(ushort4*)(p + 64);
    float4 c = *(const float4*)(cosT + pos * 64 + j4);
    float4 s = *(const float4*)(sinT + pos * 64 + j4);
    float l0 = bf2f(lo.x), l1 = bf2f(lo.y), l2 = bf2f(lo.z), l3 = bf2f(lo.w);
    float h0 = bf2f(hi.x), h1 = bf2f(hi.y), h2 = bf2f(hi.z), h3 = bf2f(hi.w);
    ushort4 nlo, nhi;
    nlo.x = f2bf((l0 * c.x - h0 * s.x) * ps);  nhi.x = f2bf((h0 * c.x + l0 * s.x) * ps);
    nlo.y = f2bf((l1 * c.y - h1 * s.y) * ps);  nhi.y = f2bf((h1 * c.y + l1 * s.y) * ps);
    nlo.z = f2bf((l2 * c.z - h2 * s.z) * ps);  nhi.z = f2bf((h2 * c.z + l2 * s.z) * ps);
    nlo.w = f2bf((l3 * c.w - h3 * s.w) * ps);  nhi.w = f2bf((h3 * c.w + l3 * s.w) * ps);
    *(ushort4*)p = nlo;
    *(ushort4*)(p + 64) = nhi;
  } else {
    int b2 = b - 4096;
    int s0 = (b2 & 63) * 32, c0 = (b2 >> 6) * 32;
    int r = tid >> 3, cc = (tid & 7) * 4;
    ushort4 v = *(const ushort4*)(V + (size_t)(s0 + r) * 2048 + c0 + cc);
    t[r][cc] = v.x; t[r][cc + 1] = v.y; t[r][cc + 2] = v.z; t[r][cc + 3] = v.w;
    __syncthreads();
    int co = tid >> 3, ro = (tid & 7) * 4;
    ushort4 o;
    o.x = t[ro][co]; o.y = t[ro + 1][co]; o.z = t[ro + 2][co]; o.w = t[ro + 3][co];
    *(ushort4*)(Vt + (size_t)(c0 + co) * 2048 + s0 + ro) = o;
  }
}

// ---------------- fused projection GEMM: C[2048][6144] = X @ [Wq;Wk;Wv]^T ----------------
// 256x192 tile, BK=64, 8 waves, 2 barriers/tile, counted vmcnt. grid (32,8) = 256 blocks.
__global__ __launch_bounds__(512, 1)
void k_g256(const u16* __restrict__ X, const u16* __restrict__ Wq, const u16* __restrict__ Wk,
            const u16* __restrict__ Wv, u16* __restrict__ C0, u16* __restrict__ C1,
            u16* __restrict__ C2){
  __shared__ __align__(16) u16 LA[2][256 * 64];
  __shared__ __align__(16) u16 LB[2][192 * 64];
  const int tid = threadIdx.x;
  const int lane = tid & 63, wvi = tid >> 6;
  const int wm = wvi >> 2, wn = wvi & 3;
  const int g = lane >> 4, c15 = lane & 15;
  const int brow = blockIdx.y * 256;       // [0,2048)
  const int bcol = blockIdx.x * 192;       // [0,6144)
  const int NT = 32;

  f32x4 acc[8][3];
#pragma unroll
  for (int m = 0; m < 8; m++)
#pragma unroll
    for (int n = 0; n < 3; n++) acc[m][n] = (f32x4){0.f, 0.f, 0.f, 0.f};

  const int cc0 = ((g ^ (c15 & 7)) * 8);
  bf16x8 af[4][2], af2[4][2], bf[3][2];

#define BPTR(rB_) (rB_ < 2048 ? Wq + (size_t)(rB_) * 2048 \
                 : rB_ < 4096 ? Wk + (size_t)((rB_) - 2048) * 2048 \
                              : Wv + (size_t)((rB_) - 4096) * 2048)
#define STGA(grow0, gcol0, ldsb) do { \
  _Pragma("unroll") for (int it = 0; it < 2; ++it){ \
    int m_ = it * 512 + tid; \
    int row_ = m_ >> 3, cp_ = m_ & 7; \
    gload16(X + (size_t)((grow0) + row_) * 2048 + (gcol0) + ((cp_ ^ (row_ & 7)) * 8), \
            (ldsb) + (it * 512 + (tid & ~63)) * 8); \
  } } while(0)
#define STGB128(gcol0, ldsb) do { \
  _Pragma("unroll") for (int it = 0; it < 2; ++it){ \
    int m_ = it * 512 + tid; \
    int row_ = m_ >> 3, cp_ = m_ & 7; \
    int rB_ = bcol + row_; \
    const u16* bp_ = BPTR(rB_); \
    gload16(bp_ + (gcol0) + ((cp_ ^ (row_ & 7)) * 8), \
            (ldsb) + (it * 512 + (tid & ~63)) * 8); \
  } } while(0)
#define STGB64(gcol0, ldsb) do { \
    int row_ = 128 + (tid >> 3), cp_ = tid & 7; \
    int rB_ = bcol + row_; \
    const u16* bp_ = BPTR(rB_); \
    gload16(bp_ + (gcol0) + ((cp_ ^ (row_ & 7)) * 8), \
            (ldsb) + (tid & ~63) * 8); \
  } while(0)
#define RDA(buf) \
  _Pragma("unroll") for (int mi2 = 0; mi2 < 4; ++mi2){ \
    const u16* pr = &LA[buf][0] + (size_t)(wm * 128 + mi2 * 16 + c15) * 64; \
    af[mi2][0] = *(const bf16x8*)(pr + cc0); \
    af[mi2][1] = *(const bf16x8*)(pr + (cc0 ^ 32)); \
  }
#define RDA2(buf) \
  _Pragma("unroll") for (int mi2 = 0; mi2 < 4; ++mi2){ \
    const u16* pr = &LA[buf][0] + (size_t)(wm * 128 + (4 + mi2) * 16 + c15) * 64; \
    af2[mi2][0] = *(const bf16x8*)(pr + cc0); \
    af2[mi2][1] = *(const bf16x8*)(pr + (cc0 ^ 32)); \
  }
#define RDB2(buf) \
  _Pragma("unroll") for (int ni2 = 0; ni2 < 2; ++ni2){ \
    const u16* pr = &LB[buf][0] + (size_t)(wn * 48 + ni2 * 16 + c15) * 64; \
    bf[ni2][0] = *(const bf16x8*)(pr + cc0); \
    bf[ni2][1] = *(const bf16x8*)(pr + (cc0 ^ 32)); \
  }
#define RDB1(buf) do { \
    const u16* pr = &LB[buf][0] + (size_t)(wn * 48 + 32 + c15) * 64; \
    bf[2][0] = *(const bf16x8*)(pr + cc0); \
    bf[2][1] = *(const bf16x8*)(pr + (cc0 ^ 32)); \
  } while(0)
#define MM2A \
  _Pragma("unroll") for (int mi2 = 0; mi2 < 4; ++mi2) \
  _Pragma("unroll") for (int ni2 = 0; ni2 < 2; ++ni2) \
  _Pragma("unroll") for (int kk = 0; kk < 2; ++kk) \
    acc[mi2][ni2] = __builtin_amdgcn_mfma_f32_16x16x32_bf16( \
        af[mi2][kk], bf[ni2][kk], acc[mi2][ni2], 0, 0, 0);
#define MM1AB \
  _Pragma("unroll") for (int mi2 = 0; mi2 < 4; ++mi2) \
  _Pragma("unroll") for (int kk = 0; kk < 2; ++kk){ \
    acc[mi2][2] = __builtin_amdgcn_mfma_f32_16x16x32_bf16( \
        af[mi2][kk], bf[2][kk], acc[mi2][2], 0, 0, 0); \
    acc[4 + mi2][2] = __builtin_amdgcn_mfma_f32_16x16x32_bf16( \
        af2[mi2][kk], bf[2][kk], acc[4 + mi2][2], 0, 0, 0); \
  }
#define MM2B \
  _Pragma("unroll") for (int mi2 = 0; mi2 < 4; ++mi2) \
  _Pragma("unroll") for (int ni2 = 0; ni2 < 2; ++ni2) \
  _Pragma("unroll") for (int kk = 0; kk < 2; ++kk) \
    acc[4 + mi2][ni2] = __builtin_amdgcn_mfma_f32_16x16x32_bf16( \
        af2[mi2][kk], bf[ni2][kk], acc[4 + mi2][ni2], 0, 0, 0);

#define TILE(t, buf) do { \
    const int kn1 = ((t) + 1) * 64; \
    const int kn2 = ((t) + 2) * 64; \
    RDA(buf); RDB2(buf); RDA2(buf); RDB1(buf); \
    if ((t) + 1 < NT){ STGA(brow, kn1, &LA[buf ^ 1][0]); \
                       STGA(brow + 128, kn1, &LA[buf ^ 1][0] + 128 * 64); } \
    PRIO1; MM2A; MM1AB; PRIO0; \
    BARRAW; \
    if ((t) + 2 < NT){ STGB128(kn2, &LB[buf][0]); STGB64(kn2, &LB[buf][0] + 128 * 64); } \
    PRIO1; MM2B; PRIO0; \
    if ((t) + 2 < NT){ WAITVM(3); } \
    else if ((t) + 1 < NT){ WAITVM(0); } \
    BARRAW; \
  } while(0)

  STGA(brow,       0, &LA[0][0]);
  STGA(brow + 128, 0, &LA[0][0] + 128 * 64);
  STGB128(0,  &LB[0][0]);
  STGB64(0,   &LB[0][0] + 128 * 64);
  STGB128(64, &LB[1][0]);
  STGB64(64,  &LB[1][0] + 128 * 64);
  WAITVM(3);
  BARRAW;

  for (int t = 0; t < NT; t += 2){
    TILE(t, 0);
    TILE(t + 1, 1);
  }
#undef TILE
#undef BPTR
#undef STGA
#undef STGB128
#undef STGB64
#undef RDA
#undef RDA2
#undef RDB2
#undef RDB1
#undef MM2A
#undef MM1AB
#undef MM2B

#pragma unroll
  for (int mi = 0; mi < 8; ++mi)
#pragma unroll
    for (int ni = 0; ni < 3; ++ni){
      int colbase = bcol + wn * 48 + ni * 16;      // 2048-boundary is 16-aligned
      int proj = colbase >> 11;
      u16* Cb = proj == 0 ? C0 : proj == 1 ? C1 : C2;
      int lc = (colbase & 2047) + c15;
#pragma unroll
      for (int r = 0; r < 4; ++r){
        int row = brow + wm * 128 + mi * 16 + g * 4 + r;
        Cb[(size_t)row * 2048 + lc] = f2bf(acc[mi][ni][r]);
      }
    }
}

// ---------------- output GEMM: 128x128 tile, BK=128, 8 waves, counted vmcnt ----------------
// grid (16,16) = 256 blocks, 512 thr; 32 MFMA per barrier-pair.
__global__ __launch_bounds__(512)
void k_gemm_out(const u16* __restrict__ A, const u16* __restrict__ B, float* __restrict__ C){
  __shared__ __align__(16) u16 As[2][128 * 128];
  __shared__ __align__(16) u16 Bs[2][128 * 128];
  const int tid = threadIdx.x;
  const int w = tid >> 6, lane = tid & 63;
  const int wm = w >> 1, wn = w & 1;
  const int g = lane >> 4, c15 = lane & 15;
  const int brow = blockIdx.y * 128, bcol = blockIdx.x * 128;

  f32x4 acc[2][4];
#pragma unroll
  for (int m = 0; m < 2; m++)
#pragma unroll
    for (int n = 0; n < 4; n++) acc[m][n] = (f32x4){0.f, 0.f, 0.f, 0.f};

#define STG_O(k0, buf) do { \
  _Pragma("unroll") for (int it = 0; it < 4; ++it){ \
    int m_ = it * 512 + tid; \
    int row_ = m_ >> 4, cp_ = m_ & 15; \
    gload16(A + (size_t)(brow + row_) * 2048 + (k0) + ((cp_ ^ (row_ & 7)) * 8), \
            As[buf] + (it * 512 + (tid & ~63)) * 8); \
    gload16(B + (size_t)(bcol + row_) * 2048 + (k0) + ((cp_ ^ (row_ & 7)) * 8), \
            Bs[buf] + (it * 512 + (tid & ~63)) * 8); \
  } } while(0)

  STG_O(0, 0);
  int cur = 0;
  for (int kt = 0; kt < 16; ++kt){
    if (kt + 1 < 16){ STG_O((kt + 1) * 128, cur ^ 1); WAITVM(8); }
    else            { WAITVM(0); }
    BARRAW;
    bf16x8 af[2][4], bfr[4][4];
#pragma unroll
    for (int mi = 0; mi < 2; ++mi){
      int row = wm * 32 + mi * 16 + c15;
#pragma unroll
      for (int ks = 0; ks < 4; ++ks)
        af[mi][ks] = *(const bf16x8*)(As[cur] + (size_t)row * 128 + ((ks * 32 + g * 8) ^ ((row & 7) << 3)));
    }
#pragma unroll
    for (int ni = 0; ni < 4; ++ni){
      int row = wn * 64 + ni * 16 + c15;
#pragma unroll
      for (int ks = 0; ks < 4; ++ks)
        bfr[ni][ks] = *(const bf16x8*)(Bs[cur] + (size_t)row * 128 + ((ks * 32 + g * 8) ^ ((row & 7) << 3)));
    }
    PRIO1;
#pragma unroll
    for (int mi = 0; mi < 2; ++mi)
#pragma unroll
      for (int ni = 0; ni < 4; ++ni)
#pragma unroll
        for (int ks = 0; ks < 4; ++ks)
          acc[mi][ni] = __builtin_amdgcn_mfma_f32_16x16x32_bf16(af[mi][ks], bfr[ni][ks],
                                                                acc[mi][ni], 0, 0, 0);
    PRIO0;
    BARRAW;
    cur ^= 1;
  }
#undef STG_O
#pragma unroll
  for (int mi = 0; mi < 2; ++mi)
#pragma unroll
    for (int ni = 0; ni < 4; ++ni)
#pragma unroll
      for (int r = 0; r < 4; ++r){
        int row = brow + wm * 32 + mi * 16 + g * 4 + r;
        int col = bcol + wn * 64 + ni * 16 + c15;
        C[(size_t)row * 2048 + col] = acc[mi][ni][r];
      }
}

// ---------------- pass 1a: rowsum of exp2 (causal), Q-in-registers ----------------
// grid (40, 16), 256 thr; K triple-buffered LDS stream, 1 barrier/iter.
__global__ __launch_bounds__(256)
void k_pass1a(const u16* __restrict__ Q, const u16* __restrict__ K, float* __restrict__ rowsum){
  __shared__ __align__(16) u16 Ks[3][64 * 128];
  const int tid = threadIdx.x;
  const int wv = tid >> 6, lane = tid & 63;
  const int g = lane >> 4, c15 = lane & 15;
  const int h = blockIdx.y;
  int qb = 0, c = 0;
  { int rem = blockIdx.x; int q = 0;
    while (rem >= ((2 * q + 9) >> 3)){ rem -= (2 * q + 9) >> 3; q++; }
    qb = q; c = rem; }
  const int i0 = qb * 128;
  const int ktend = 2 * qb + 2;
  const int kt0 = c * 8;
  const int kt1 = (ktend < kt0 + 8) ? ktend : (kt0 + 8);
  const u16* Qh = Q + h * HDIM;
  const u16* Kh = K + h * HDIM;
  const int wb = wv * 32;

  bf16x8 qfr[2][4];
#pragma unroll
  for (int m = 0; m < 2; m++)
#pragma unroll
    for (int ks = 0; ks < 4; ks++)
      qfr[m][ks] = *(const bf16x8*)(Qh + (size_t)(i0 + wb + m * 16 + c15) * 2048 + ks * 32 + g * 8);

  stage_tile(Kh, 2048, kt0 * 64, Ks[0], tid);
  if (kt0 + 1 < kt1) stage_tile(Kh, 2048, (kt0 + 1) * 64, Ks[1], tid);

  float rs[2][4] = {{0.f,0.f,0.f,0.f},{0.f,0.f,0.f,0.f}};
  for (int kt = kt0; kt < kt1; ++kt){
    const int bi = (kt - kt0) % 3;
    if (kt + 1 < kt1){ WAITVM(4); } else { WAITVM(0); }
    BARRAW;
    if (kt + 2 < kt1) stage_tile(Kh, 2048, (kt + 2) * 64, Ks[(kt - kt0 + 2) % 3], tid);
    const int k0 = kt * 64;
    f32x4 sacc[2][4];
#pragma unroll
    for (int m = 0; m < 2; m++)
#pragma unroll
      for (int n = 0; n < 4; n++) sacc[m][n] = (f32x4){0.f, 0.f, 0.f, 0.f};
#pragma unroll
    for (int ks = 0; ks < 4; ++ks){
#pragma unroll
      for (int n = 0; n < 4; n++){
        int brw = n * 16 + c15;
        bf16x8 b = *(const bf16x8*)(Ks[bi] + brw * 128 + ((ks * 32 + g * 8) ^ ((brw & 7) << 3)));
#pragma unroll
        for (int m = 0; m < 2; m++)
          sacc[m][n] = __builtin_amdgcn_mfma_f32_16x16x32_bf16(qfr[m][ks], b, sacc[m][n], 0, 0, 0);
      }
    }
    if (kt < 2 * qb){            // fully causal tile: no mask compare
#pragma unroll
      for (int m = 0; m < 2; m++)
#pragma unroll
        for (int n = 0; n < 4; n++)
#pragma unroll
          for (int r = 0; r < 4; r++)
            rs[m][r] += exp2g(sacc[m][n][r]);
    } else {
#pragma unroll
      for (int n = 0; n < 4; n++){
        int col = k0 + n * 16 + c15;
#pragma unroll
        for (int m = 0; m < 2; m++)
#pragma unroll
          for (int r = 0; r < 4; r++){
            int rowg = i0 + wb + m * 16 + g * 4 + r;
            rs[m][r] += (col <= rowg) ? exp2g(sacc[m][n][r]) : 0.f;
          }
      }
    }
  }
#pragma unroll
  for (int m = 0; m < 2; m++)
#pragma unroll
    for (int r = 0; r < 4; r++){
      float v = rs[m][r];
      v += __shfl_xor(v, 1); v += __shfl_xor(v, 2);
      v += __shfl_xor(v, 4); v += __shfl_xor(v, 8);
      if (c15 == 0)
        atomicAdd(&rowsum[h * 2048 + i0 + wb + m * 16 + g * 4 + r], v);
    }
}

// ---------------- pass 1b: colsum of normalized exp2, K-in-registers ----------------
// grid (40, 16), 256 thr; Q triple-buffered LDS stream, 1 barrier/iter.
__global__ __launch_bounds__(256)
void k_pass1b(const u16* __restrict__ Q, const u16* __restrict__ K,
              const float* __restrict__ rowsum, float* __restrict__ colsum){
  __shared__ __align__(16) u16 Qs[3][64 * 128];
  const int tid = threadIdx.x;
  const int wv = tid >> 6, lane = tid & 63;
  const int g = lane >> 4, c15 = lane & 15;
  const int h = blockIdx.y;
  int kb = 0, c = 0;
  { int rem = blockIdx.x; int q = 0;
    while (rem >= ((39 - 2 * q) >> 3)){ rem -= (39 - 2 * q) >> 3; q++; }
    kb = q; c = rem; }
  const int k0 = kb * 128;
  const int qt0 = 2 * kb + c * 8;
  const int qt1 = (2 * kb + c * 8 + 8 < 32) ? (2 * kb + c * 8 + 8) : 32;
  const u16* Qh = Q + h * HDIM;
  const u16* Kh = K + h * HDIM;
  const int wb = wv * 32;
  const float* rsrow = rowsum + h * 2048;

  bf16x8 kfr[2][4];
#pragma unroll
  for (int m = 0; m < 2; m++)
#pragma unroll
    for (int ks = 0; ks < 4; ks++)
      kfr[m][ks] = *(const bf16x8*)(Kh + (size_t)(k0 + wb + m * 16 + c15) * 2048 + ks * 32 + g * 8);

  stage_tile(Qh, 2048, qt0 * 64, Qs[0], tid);
  if (qt0 + 1 < qt1) stage_tile(Qh, 2048, (qt0 + 1) * 64, Qs[1], tid);

  float racc[2][4] = {{0.f,0.f,0.f,0.f},{0.f,0.f,0.f,0.f}};
  for (int qt = qt0; qt < qt1; ++qt){
    const int bi = (qt - qt0) % 3;
    if (qt + 1 < qt1){ WAITVM(4); } else { WAITVM(0); }
    BARRAW;
    if (qt + 2 < qt1) stage_tile(Qh, 2048, (qt + 2) * 64, Qs[(qt - qt0 + 2) % 3], tid);
    const int i0q = qt * 64;
    float rw[4];
#pragma unroll
    for (int n = 0; n < 4; n++)
      rw[n] = 1.0f / rsrow[i0q + n * 16 + c15];
    f32x4 sacc[2][4];
#pragma unroll
    for (int m = 0; m < 2; m++)
#pragma unroll
      for (int n = 0; n < 4; n++) sacc[m][n] = (f32x4){0.f, 0.f, 0.f, 0.f};
#pragma unroll
    for (int ks = 0; ks < 4; ++ks){
#pragma unroll
      for (int n = 0; n < 4; n++){
        int brw = n * 16 + c15;
        bf16x8 b = *(const bf16x8*)(Qs[bi] + brw * 128 + ((ks * 32 + g * 8) ^ ((brw & 7) << 3)));
#pragma unroll
        for (int m = 0; m < 2; m++)
          sacc[m][n] = __builtin_amdgcn_mfma_f32_16x16x32_bf16(kfr[m][ks], b, sacc[m][n], 0, 0, 0);
      }
    }
    if (qt >= 2 * kb + 2){       // fully causal: no mask compare
#pragma unroll
      for (int m = 0; m < 2; m++)
#pragma unroll
        for (int n = 0; n < 4; n++)
#pragma unroll
          for (int r = 0; r < 4; r++)
            racc[m][r] += exp2g(sacc[m][n][r]) * rw[n];
    } else {
#pragma unroll
      for (int n = 0; n < 4; n++){
        int colq = i0q + n * 16 + c15;
#pragma unroll
        for (int m = 0; m < 2; m++)
#pragma unroll
          for (int r = 0; r < 4; r++){
            int rowk = k0 + wb + m * 16 + g * 4 + r;
            racc[m][r] += (rowk <= colq) ? exp2g(sacc[m][n][r]) * rw[n] : 0.f;
          }
      }
    }
  }
#pragma unroll
  for (int m = 0; m < 2; m++)
#pragma unroll
    for (int r = 0; r < 4; r++){
      float v = racc[m][r];
      v += __shfl_xor(v, 1); v += __shfl_xor(v, 2);
      v += __shfl_xor(v, 4); v += __shfl_xor(v, 8);
      if (c15 == 0)
        atomicAdd(&colsum[h * 2048 + k0 + wb + m * 16 + g * 4 + r], v);
    }
}

// ---------------- top-k via exact radix-select (select only, 16 blocks) ----------------
__global__ __launch_bounds__(1024)
void k_topk(const float* __restrict__ colsum, short* __restrict__ cidx){
  __shared__ u32 keys[2048];
  __shared__ int hist[256];
  __shared__ int chunkCnt[32];
  __shared__ short cidL[256];
  __shared__ u32 Tacc_s;
  __shared__ int rem_s;
  const int tid = threadIdx.x;
  const int h = blockIdx.x;
  const int w = tid >> 6, lane = tid & 63;

  for (int i = tid; i < 2048; i += 1024) keys[i] = ((const u32*)colsum)[h * 2048 + i];
  if (tid == 0){ Tacc_s = 0; rem_s = HEAVY; }
  __syncthreads();

  for (int s = 24; s >= 0; s -= 8){
    if (tid < 256) hist[tid] = 0;
    __syncthreads();
    u32 T = Tacc_s;
    for (int i = tid; i < 2048; i += 1024){
      u32 k = keys[i];
      bool match = (s == 24) ? true : (((k ^ T) >> (s + 8)) == 0);
      if (match) atomicAdd(&hist[(k >> s) & 255], 1);
    }
    __syncthreads();
    if (tid == 0){
      int rem = rem_s, acc = 0, b = 255;
      for (; b > 0; --b){
        int c2 = hist[b];
        if (acc + c2 >= rem) break;
        acc += c2;
      }
      Tacc_s = T | ((u32)b << s);
      rem_s = rem - acc;
    }
    __syncthreads();
  }
  const u32 T = Tacc_s;
  const int need = rem_s;                 // smallest-index ties among == T
  const u32 kA = keys[tid], kB = keys[tid + 1024];
  const bool eqA = (kA == T), eqB = (kB == T);
  unsigned long long ebA = __ballot(eqA);
  unsigned long long ebB = __ballot(eqB);
  if (lane == 0){ chunkCnt[w] = __popcll(ebA); chunkCnt[16 + w] = __popcll(ebB); }
  __syncthreads();
  if (tid == 0){
    int s2 = 0;
    for (int i2 = 0; i2 < 32; ++i2){ int c2 = chunkCnt[i2]; chunkCnt[i2] = s2; s2 += c2; }
  }
  __syncthreads();
  const unsigned long long below = (1ull << lane) - 1ull;
  const int eqrA = chunkCnt[w] + __popcll(ebA & below);
  const int eqrB = chunkCnt[16 + w] + __popcll(ebB & below);
  const bool hvA = (kA > T) || (eqA && eqrA < need);
  const bool hvB = (kB > T) || (eqB && eqrB < need);
  __syncthreads();                        // before reusing chunkCnt
  unsigned long long hbA = __ballot(hvA);
  unsigned long long hbB = __ballot(hvB);
  if (lane == 0){ chunkCnt[w] = __popcll(hbA); chunkCnt[16 + w] = __popcll(hbB); }
  if (tid >= HEAVY && tid < 256) cidL[tid] = 32767;
  __syncthreads();
  if (tid == 0){
    int s2 = 0;
    for (int i2 = 0; i2 < 32; ++i2){ int c2 = chunkCnt[i2]; chunkCnt[i2] = s2; s2 += c2; }
  }
  __syncthreads();
  if (hvA) cidL[chunkCnt[w] + __popcll(hbA & below)] = (short)tid;
  if (hvB) cidL[chunkCnt[16 + w] + __popcll(hbB & below)] = (short)(tid + 1024);
  __syncthreads();
  if (tid < 256) cidx[h * 256 + tid] = cidL[tid];
}

// ---------------- gather heavy K rows + V cols (full-grid, 384 blocks) ----------------
__global__ void k_gath(const u16* __restrict__ Kb, const u16* __restrict__ Vb,
                       const short* __restrict__ cidx,
                       u16* __restrict__ Kg, u16* __restrict__ Vg){
  __shared__ __align__(16) u16 t[32][136];
  int b = blockIdx.x, tid = threadIdx.x;
  if (b < 256){
    int gid = b * 256 + tid;                   // 16h * 256slot * 16chunk = 65536
    int h = gid >> 12, rem = gid & 4095;
    int slot = rem >> 4, cp = rem & 15;
    int cid = cidx[h * 256 + slot];
    bf16x8 z = (bf16x8){0,0,0,0,0,0,0,0};
    bf16x8 val = (cid < 2048) ? *(const bf16x8*)(Kb + (size_t)cid * 2048 + h * 128 + cp * 8) : z;
    *(bf16x8*)(Kg + ((size_t)h * 256 + slot) * 128 + cp * 8) = val;
  } else {
    int b2 = b - 256;
    int h = b2 >> 3, s0 = (b2 & 7) * 32;
#pragma unroll
    for (int it = 0; it < 2; ++it){
      int m = it * 256 + tid;                  // 512 chunks = 32 slots x 16 chunks
      int s = m >> 4, cp = m & 15;
      int cid = cidx[h * 256 + s0 + s];
      bf16x8 z = (bf16x8){0,0,0,0,0,0,0,0};
      bf16x8 val = (cid < 2048) ? *(const bf16x8*)(Vb + (size_t)cid * 2048 + h * 128 + cp * 8) : z;
      *(bf16x8*)(&t[s][cp * 8]) = val;
    }
    __syncthreads();
#pragma unroll
    for (int i = 0; i < 16; ++i){
      int idx = i * 256 + tid;                 // 4096 = 128 d x 32 s
      int d = idx >> 5, s = idx & 31;
      Vg[((size_t)h * 128 + d) * 256 + s0 + s] = t[s][d];
    }
  }
}

// ---------------- pass 2: QBLK=128, Q-in-reg, K+V LDS dbuf, ONE barrier/iter ----------------
// grid (16, 16) = 256 blocks, 512 thr (8 waves: 2 q-halves x 4 strips)
// Hazard proof: at iter top, outstanding loads = K(i),V(i) (staged one full compute-phase
// ago); WAITVM(0) retires both, barrier makes them visible; K/V(i+1) staged into buf^1
// (fully read before this barrier in iter i-1); Ps is wave-private -> PV needs no sync.
__global__ __launch_bounds__(512)
void k_pass2(const u16* __restrict__ Q, const u16* __restrict__ K, const u16* __restrict__ Vt,
             const u16* __restrict__ Kg, const u16* __restrict__ Vg,
             const short* __restrict__ cidx, u16* __restrict__ attn){
  __shared__ __align__(16) u16 Ks[2][64 * 128];
  __shared__ __align__(16) u16 Vs[2][128 * 64];
  __shared__ __align__(16) u16 Ps[8][16 * 64];
  __shared__ short cids[256];
  __shared__ int lists[12];
  __shared__ int nact_s;
  const int tid = threadIdx.x;
  const int w = tid >> 6, lane = tid & 63;
  const int g = lane >> 4, c15 = lane & 15;
  const int qb = blockIdx.x, h = blockIdx.y;
  const int i0 = qb * 128;
  const int wq = w >> 2, w4 = w & 3;
  const int rowbase = i0 + wq * 64 + w4 * 16;
  const u16* Qh = Q + h * HDIM;
  const u16* Kh = K + h * HDIM;
  const u16* Kgh = Kg + (size_t)h * 256 * 128;
  const u16* Vth = Vt + (size_t)h * 128 * 2048;
  const u16* Vgh = Vg + (size_t)h * 128 * 256;

  if (tid < 256) cids[tid] = cidx[h * 256 + tid];
  // Q fragments in registers (rows rowbase + c15)
  bf16x8 qfr[4];
#pragma unroll
  for (int ks = 0; ks < 4; ks++)
    qfr[ks] = *(const bf16x8*)(Qh + (size_t)(rowbase + c15) * 2048 + ks * 32 + g * 8);
  __syncthreads();
  if (tid == 0){
    int n = 0;
    int ktb0 = (i0 > RECENT) ? ((i0 - RECENT) >> 6) : 0;
    int ktmax = (i0 + 127) >> 6;
    for (int kt = ktb0; kt <= ktmax; ++kt) lists[n++] = kt;
    for (int gt = 0; gt < 4; ++gt)
      if ((int)cids[gt * 64] <= i0 + 127 - RECENT - 1) lists[n++] = 100 + gt;
    nact_s = n;
  }
  __syncthreads();
  const int nact = nact_s;

  // prologue: stage K0 (2) + V0 (2) only
  { int e = lists[0];
    if (e < 100){ stageK512(Kh, 2048, e * 64, Ks[0], tid);
                  stageV512(Vth, 2048, e * 64, Vs[0], tid); }
    else        { stageK512(Kgh, 128, (e - 100) * 64, Ks[0], tid);
                  stageV512(Vgh, 256, (e - 100) * 64, Vs[0], tid); } }

  f32x4 oacc[8];
#pragma unroll
  for (int f = 0; f < 8; f++) oacc[f] = (f32x4){0.f, 0.f, 0.f, 0.f};
  float lsum[4] = {0.f, 0.f, 0.f, 0.f};

  int cur = 0;
  for (int i = 0; i < nact; ++i){
    const int e = lists[i];
    const bool isg = (e >= 100);
    const bool nxt = (i + 1 < nact);
    WAITVM(0);                 // retire K(i) and V(i) (issued one compute-phase ago)
    BARRAW;                    // single barrier: K/V(i) visible; buf^1 free for restage
    if (nxt){
      int e2 = lists[i + 1];
      if (e2 < 100){ stageK512(Kh, 2048, e2 * 64, Ks[cur ^ 1], tid);
                     stageV512(Vth, 2048, e2 * 64, Vs[cur ^ 1], tid); }
      else         { stageK512(Kgh, 128, (e2 - 100) * 64, Ks[cur ^ 1], tid);
                     stageV512(Vgh, 256, (e2 - 100) * 64, Vs[cur ^ 1], tid); }
    }
    // QK^T
    f32x4 sacc[4];
#pragma unroll
    for (int n = 0; n < 4; n++) sacc[n] = (f32x4){0.f, 0.f, 0.f, 0.f};
#pragma unroll
    for (int ks = 0; ks < 4; ++ks){
#pragma unroll
      for (int n = 0; n < 4; n++){
        int brw = n * 16 + c15;
        bf16x8 b = *(const bf16x8*)(Ks[cur] + brw * 128 + ((ks * 32 + g * 8) ^ ((brw & 7) << 3)));
        sacc[n] = __builtin_amdgcn_mfma_f32_16x16x32_bf16(qfr[ks], b, sacc[n], 0, 0, 0);
      }
    }
    // masked exp2 -> P (LDS, wave-private), row sums
#pragma unroll
    for (int n = 0; n < 4; n++){
      int cid = isg ? (int)cids[(e - 100) * 64 + n * 16 + c15] : (e * 64 + n * 16 + c15);
#pragma unroll
      for (int r = 0; r < 4; r++){
        int rowg = rowbase + g * 4 + r;
        int dist = rowg - cid;
        bool valid = (cid <= rowg) && (isg ? (dist > RECENT) : (dist <= RECENT));
        float ev = valid ? exp2g(sacc[n][r]) : 0.f;
        lsum[r] += ev;
        int prow = g * 4 + r;
        Ps[w][prow * 64 + ((n * 16 + c15) ^ ((prow & 7) << 3))] = f2bf(ev);
      }
    }
    // PV from LDS (V(i) visibility guaranteed by the top barrier; Ps wave-private)
    PRIO1;
#pragma unroll
    for (int ks2 = 0; ks2 < 2; ++ks2){
      bf16x8 pa = *(const bf16x8*)(&Ps[w][c15 * 64 + ((ks2 * 32 + g * 8) ^ ((c15 & 7) << 3))]);
#pragma unroll
      for (int f = 0; f < 8; ++f){
        int vrow = f * 16 + c15;
        bf16x8 vb = *(const bf16x8*)(Vs[cur] + vrow * 64 + ((ks2 * 32 + g * 8) ^ ((vrow & 7) << 3)));
        oacc[f] = __builtin_amdgcn_mfma_f32_16x16x32_bf16(pa, vb, oacc[f], 0, 0, 0);
      }
    }
    PRIO0;
    cur ^= 1;
  }
  float rinv[4];
#pragma unroll
  for (int r = 0; r < 4; r++){
    float v = lsum[r];
    v += __shfl_xor(v, 1); v += __shfl_xor(v, 2);
    v += __shfl_xor(v, 4); v += __shfl_xor(v, 8);
    rinv[r] = 1.0f / v;
  }
#pragma unroll
  for (int f = 0; f < 8; f++)
#pragma unroll
    for (int r = 0; r < 4; r++){
      int rowg = rowbase + g * 4 + r;
      attn[(size_t)rowg * 2048 + h * HDIM + f * 16 + c15] = f2bf(oacc[f][r] * rinv[r]);
    }
}

// ---------------- host launcher ----------------
extern "C" void kernel_launch(void* const* d_in, const int* in_sizes, int n_in,
                              void* d_out, int out_size, void* d_ws, size_t ws_size,
                              hipStream_t stream){
  const float* X  = (const float*)d_in[0];
  const float* Wq = (const float*)d_in[1];
  const float* Wk = (const float*)d_in[2];
  const float* Wv = (const float*)d_in[3];
  const float* Wo = (const float*)d_in[4];

  char* w = (char*)d_ws;
  const size_t MB8 = (size_t)2048 * 2048 * 2;   // one bf16 matrix = 8 MiB
  u16* Xb  = (u16*)(w);
  u16* Wqb = (u16*)(w + 1 * MB8);
  u16* Wkb = (u16*)(w + 2 * MB8);
  u16* Wvb = (u16*)(w + 3 * MB8);
  u16* Wob = (u16*)(w + 4 * MB8);
  u16* Qb  = (u16*)(w + 5 * MB8);
  u16* Kb  = (u16*)(w + 6 * MB8);
  u16* Vb  = (u16*)(w + 7 * MB8);
  u16* Vtb   = Wqb;   // Wq dead after projections
  u16* attnb = Xb;    // X dead after projections
  char* p = w + 8 * MB8;
  float* cosT = (float*)p;              p += 524288;
  float* sinT = (float*)p;              p += 524288;
  float* colsum = (float*)p;            p += 131072;   // zeroed in k_prep (with rowsum)
  float* rowsum = (float*)p;            p += 131072;
  short* cidx  = (short*)p;             p += 16 * 256 * 2;
  u16*   Kg    = (u16*)p;               p += (size_t)16 * 256 * 128 * 2;
  u16*   Vg    = (u16*)p;

  dim3 b256(256);

  k_prep<<<21056, b256, 0, stream>>>(X, Wq, Wk, Wv, Wo, Xb, cosT, sinT, colsum);

  k_g256<<<dim3(32, 8), dim3(512), 0, stream>>>(Xb, Wqb, Wkb, Wvb, Qb, Kb, Vb);
  k_post<<<8192, b256, 0, stream>>>(Qb, Kb, cosT, sinT, Vb, Vtb);

  k_pass1a<<<dim3(40, 16), b256, 0, stream>>>(Qb, Kb, rowsum);
  k_pass1b<<<dim3(40, 16), b256, 0, stream>>>(Qb, Kb, rowsum, colsum);
  k_topk<<<16, dim3(1024), 0, stream>>>(colsum, cidx);
  k_gath<<<384, b256, 0, stream>>>(Kb, Vb, cidx, Kg, Vg);
  k_pass2<<<dim3(16, 16), dim3(512), 0, stream>>>(Qb, Kb, Vtb, Kg, Vg, cidx, attnb);

  k_gemm_out<<<dim3(16, 16), dim3(512), 0, stream>>>(attnb, Wob, (float*)d_out);
}